// Round 1
// baseline (926.688 us; speedup 1.0000x reference)
//
#include <hip/hip_runtime.h>
#include <math.h>

// ---------------- problem constants ----------------
constexpr int B_    = 2;
constexpr int L_    = 2048;
constexpr int NROW  = B_ * L_;     // 4096
constexpr int HALF_ = 256;
constexpr int DS_   = 128;         // D_STATE
// DT_RANK = 32, D_INNER = 512

// ---------------- ws layout (floats) ----------------
constexpr size_t OFF_A1   = 0;
constexpr size_t OFF_A2   = OFF_A1 + (size_t)HALF_ * DS_;       // 32768
constexpr size_t OFF_THR  = OFF_A2 + (size_t)HALF_ * DS_;       // 4 (thrB1,thrC1,thrB2,thrC2)
constexpr size_t OFF_PART = OFF_THR + 4;                        // 256 partial maxes
constexpr size_t OFF_XIN  = OFF_PART + 256;                     // 4096x512 (shared transient)
constexpr size_t OFF_XZ   = OFF_XIN + (size_t)NROW * 512;       // 4096x512 (shared transient)
constexpr size_t OFF_XDBL = OFF_XZ  + (size_t)NROW * 512;       // 4096x288 (shared transient)
constexpr size_t OFF_XS   = OFF_XDBL + (size_t)NROW * 288;      // 2 x 4096x256
constexpr size_t OFF_DLT  = OFF_XS  + (size_t)2 * NROW * 256;   // 2 x 4096x256
constexpr size_t OFF_BS   = OFF_DLT + (size_t)2 * NROW * 256;   // 2 x 4096x128
constexpr size_t OFF_CS   = OFF_BS  + (size_t)2 * NROW * 128;   // 2 x 4096x128
constexpr size_t OFF_YZ   = OFF_CS  + (size_t)2 * NROW * 128;   // 2 x 4096x512
constexpr size_t WS_FLOATS = OFF_YZ + (size_t)2 * NROW * 512;   // ~16M floats = 64 MB

// ---------------- device helpers ----------------
__device__ __forceinline__ float shrinkf(float v, float thr) {
    float a = fabsf(v) - thr;
    a = fmaxf(a, 0.0f);
    float r = copysignf(a, v);
    return (v == 0.0f) ? 0.0f : r;   // sign(0)*anything == 0 in the reference
}

__device__ __forceinline__ float siluf(float v) {
    return v / (1.0f + __expf(-v));
}

__device__ __forceinline__ float softplusf(float v) {
    // stable: max(x,0) + log1p(exp(-|x|))
    return fmaxf(v, 0.0f) + log1pf(__expf(-fabsf(v)));
}

__device__ __forceinline__ float blockMaxAll(float v, float* sbuf) {
    __syncthreads();   // safe back-to-back use of sbuf
    #pragma unroll
    for (int off = 32; off > 0; off >>= 1) v = fmaxf(v, __shfl_xor(v, off));
    int w = threadIdx.x >> 6;
    if ((threadIdx.x & 63) == 0) sbuf[w] = v;
    __syncthreads();
    int nw = blockDim.x >> 6;
    float r = (threadIdx.x < nw) ? sbuf[threadIdx.x] : -INFINITY;
    #pragma unroll
    for (int off = 32; off > 0; off >>= 1) r = fmaxf(r, __shfl_xor(r, off));
    if (threadIdx.x == 0) sbuf[0] = r;
    __syncthreads();
    return sbuf[0];
}

// ---------------- A1/A2 precompute (one block) ----------------
__global__ __launch_bounds__(256) void computeA_kernel(const float* __restrict__ A_log,
                                                       const float* __restrict__ eps,
                                                       float* __restrict__ ws) {
    __shared__ float sbuf[8];
    float* A1 = ws + OFF_A1;
    float* A2 = ws + OFF_A2;
    const int N = HALF_ * DS_;   // 32768
    float e = 1.0f + eps[0];
    float mx = -INFINITY;
    for (int i = threadIdx.x; i < N; i += 256) {
        float base = -e * __expf(A_log[i]);
        A1[i] = base;
        mx = fmaxf(mx, base);
    }
    float thr1 = 0.1f * blockMaxAll(mx, sbuf);
    float mx2 = -INFINITY;
    for (int i = threadIdx.x; i < N; i += 256) {
        float v = shrinkf(A1[i], thr1);
        A1[i] = v;
        mx2 = fmaxf(mx2, v);
    }
    float thr2 = 0.1f * blockMaxAll(mx2, sbuf);
    for (int i = threadIdx.x; i < N; i += 256) {
        A2[i] = shrinkf(A1[i], thr2);
    }
}

// ---------------- input transpose: (B, 1024, L) slice -> (B*L, 512) ----------------
__global__ __launch_bounds__(256) void transpose_in_kernel(const float* __restrict__ inp,
                                                           float* __restrict__ xin, int coff) {
    __shared__ float tile[32][33];
    int b  = blockIdx.z;
    int t0 = blockIdx.x * 32;
    int m0 = blockIdx.y * 32;
    int tx = threadIdx.x;        // 32
    int ty = threadIdx.y;        // 8
    #pragma unroll
    for (int k = 0; k < 4; k++) {
        tile[ty + 8 * k][tx] =
            inp[((size_t)b * 1024 + coff + m0 + ty + 8 * k) * L_ + t0 + tx];
    }
    __syncthreads();
    #pragma unroll
    for (int k = 0; k < 4; k++) {
        xin[((size_t)b * L_ + t0 + ty + 8 * k) * 512 + m0 + tx] = tile[tx][ty + 8 * k];
    }
}

// ---------------- generic fp32 GEMM: C[M,N] = A[M,K] * W[N,K]^T ----------------
// EPI 0: none, 1: softplus(x + bias[n])
template <int EPI>
__global__ __launch_bounds__(256) void gemm_nt(const float* __restrict__ A, int lda,
                                               const float* __restrict__ W,
                                               const float* __restrict__ bias,
                                               float* __restrict__ C, int ldc,
                                               int M, int N, int K) {
    __shared__ float As[16][68];
    __shared__ float Ws[16][68];
    int tid = threadIdx.x;
    int kk = tid & 15;
    int rr = tid >> 4;
    int mblk = blockIdx.y * 64;
    int nblk = blockIdx.x * 64;
    float acc[4][4] = {};
    for (int k0 = 0; k0 < K; k0 += 16) {
        #pragma unroll
        for (int j = 0; j < 4; j++) {
            As[kk][rr + 16 * j] = A[(size_t)(mblk + rr + 16 * j) * lda + k0 + kk];
        }
        #pragma unroll
        for (int j = 0; j < 4; j++) {
            int n = nblk + rr + 16 * j;
            Ws[kk][rr + 16 * j] = (n < N) ? W[(size_t)n * K + k0 + kk] : 0.0f;
        }
        __syncthreads();
        int ty = tid >> 4;
        int tx = tid & 15;
        #pragma unroll
        for (int kq = 0; kq < 16; kq++) {
            float a0 = As[kq][ty * 4 + 0];
            float a1 = As[kq][ty * 4 + 1];
            float a2 = As[kq][ty * 4 + 2];
            float a3 = As[kq][ty * 4 + 3];
            float b0 = Ws[kq][tx * 4 + 0];
            float b1 = Ws[kq][tx * 4 + 1];
            float b2 = Ws[kq][tx * 4 + 2];
            float b3 = Ws[kq][tx * 4 + 3];
            acc[0][0] = fmaf(a0, b0, acc[0][0]); acc[0][1] = fmaf(a0, b1, acc[0][1]);
            acc[0][2] = fmaf(a0, b2, acc[0][2]); acc[0][3] = fmaf(a0, b3, acc[0][3]);
            acc[1][0] = fmaf(a1, b0, acc[1][0]); acc[1][1] = fmaf(a1, b1, acc[1][1]);
            acc[1][2] = fmaf(a1, b2, acc[1][2]); acc[1][3] = fmaf(a1, b3, acc[1][3]);
            acc[2][0] = fmaf(a2, b0, acc[2][0]); acc[2][1] = fmaf(a2, b1, acc[2][1]);
            acc[2][2] = fmaf(a2, b2, acc[2][2]); acc[2][3] = fmaf(a2, b3, acc[2][3]);
            acc[3][0] = fmaf(a3, b0, acc[3][0]); acc[3][1] = fmaf(a3, b1, acc[3][1]);
            acc[3][2] = fmaf(a3, b2, acc[3][2]); acc[3][3] = fmaf(a3, b3, acc[3][3]);
        }
        __syncthreads();
    }
    int ty = tid >> 4;
    int tx = tid & 15;
    #pragma unroll
    for (int i = 0; i < 4; i++) {
        int m = mblk + ty * 4 + i;
        #pragma unroll
        for (int j = 0; j < 4; j++) {
            int n = nblk + tx * 4 + j;
            if (n < N) {
                float v = acc[i][j];
                if (EPI == 1) v = softplusf(v + bias[n]);
                C[(size_t)m * ldc + n] = v;
            }
        }
    }
}

// ---------------- depthwise conv (k=4, pad 1/2) + SiLU ----------------
__global__ __launch_bounds__(256) void conv_silu_kernel(const float* __restrict__ xz,
                                                        float* __restrict__ xs,
                                                        float* __restrict__ yz,
                                                        const float* __restrict__ wx,
                                                        const float* __restrict__ wz) {
    int idx = blockIdx.x * 256 + threadIdx.x;   // over NROW*HALF
    if (idx >= NROW * HALF_) return;
    int c   = idx & 255;
    int row = idx >> 8;
    int t   = row & (L_ - 1);
    float ax = 0.0f, az = 0.0f;
    #pragma unroll
    for (int j = 0; j < 4; j++) {
        int tt = t + j - 1;
        if (tt >= 0 && tt < L_) {
            const float* p = xz + (size_t)(row + j - 1) * 512;
            ax = fmaf(p[c], wx[c * 4 + j], ax);
            az = fmaf(p[c + 256], wz[c * 4 + j], az);
        }
    }
    xs[(size_t)row * 256 + c] = siluf(ax);
    yz[(size_t)row * 512 + 256 + c] = siluf(az);
}

// ---------------- global signed-max over Bc/Cc slices ----------------
__global__ __launch_bounds__(256) void redmax_kernel(const float* __restrict__ xdbl,
                                                     float* __restrict__ part) {
    __shared__ float sbuf[8];
    float mb = -INFINITY, mc = -INFINITY;
    const size_t total = (size_t)NROW * 128;
    for (size_t i = (size_t)blockIdx.x * 256 + threadIdx.x; i < total;
         i += (size_t)gridDim.x * 256) {
        size_t row = i >> 7;
        int n = (int)(i & 127);
        const float* p = xdbl + row * 288;
        mb = fmaxf(mb, p[32 + n]);
        mc = fmaxf(mc, p[160 + n]);
    }
    mb = blockMaxAll(mb, sbuf);
    mc = blockMaxAll(mc, sbuf);
    if (threadIdx.x == 0) {
        part[blockIdx.x] = mb;
        part[128 + blockIdx.x] = mc;
    }
}

__global__ __launch_bounds__(64) void finmax_kernel(const float* __restrict__ part,
                                                    float* __restrict__ thr) {
    int l = threadIdx.x;
    float vb = fmaxf(part[l], part[l + 64]);
    float vc = fmaxf(part[128 + l], part[192 + l]);
    #pragma unroll
    for (int off = 32; off > 0; off >>= 1) {
        vb = fmaxf(vb, __shfl_xor(vb, off));
        vc = fmaxf(vc, __shfl_xor(vc, off));
    }
    if (l == 0) {
        thr[0] = 0.1f * vb;
        thr[1] = 0.1f * vc;
    }
}

// ---------------- shrink + pack Bc/Cc into contiguous (row,128) ----------------
__global__ __launch_bounds__(256) void shrinkpack_kernel(const float* __restrict__ xdbl,
                                                         const float* __restrict__ thr,
                                                         float* __restrict__ Bs,
                                                         float* __restrict__ Cs) {
    int idx = blockIdx.x * 256 + threadIdx.x;
    if (idx >= NROW * 128) return;
    int row = idx >> 7;
    int n = idx & 127;
    float tB = thr[0], tC = thr[1];
    const float* p = xdbl + (size_t)row * 288;
    Bs[idx] = shrinkf(p[32 + n], tB);
    Cs[idx] = shrinkf(p[160 + n], tC);
}

// ---------------- selective scan: one wave per (b, d, branch) ----------------
__global__ __launch_bounds__(64) void scan_kernel(float* __restrict__ ws,
                                                  const float* __restrict__ Dvec) {
    int d    = blockIdx.x;   // 0..255
    int b    = blockIdx.y;   // 0..1
    int br   = blockIdx.z;   // 0..1
    int lane = threadIdx.x;  // 0..63

    const float* A   = ws + (br == 0 ? OFF_A1 : OFF_A2);
    const float* xs  = ws + OFF_XS  + (size_t)br * NROW * 256;
    const float* dlt = ws + OFF_DLT + (size_t)br * NROW * 256;
    const float* Bs  = ws + OFF_BS  + (size_t)br * NROW * 128;
    const float* Cs  = ws + OFF_CS  + (size_t)br * NROW * 128;
    float*       yz  = ws + OFF_YZ  + (size_t)br * NROW * 512;

    float a0 = A[d * 128 + 2 * lane];
    float a1 = A[d * 128 + 2 * lane + 1];
    float Dd = Dvec[d];
    float h0 = 0.0f, h1 = 0.0f;

    size_t rowbase = (size_t)b * L_;
    const float*  pD = dlt + rowbase * 256 + d;
    const float*  pU = xs  + rowbase * 256 + d;
    const float2* pB = (const float2*)(Bs + rowbase * 128) + lane;
    const float2* pC = (const float2*)(Cs + rowbase * 128) + lane;
    float*        pY = yz + rowbase * 512 + d;

    for (int t0 = 0; t0 < L_; t0 += 8) {
        float py[8], ud[8];
        #pragma unroll
        for (int j = 0; j < 8; j++) {
            int t = t0 + j;
            float dt = pD[t * 256];
            float u  = pU[t * 256];
            float2 Bv = pB[t * 64];
            float2 Cv = pC[t * 64];
            float e0 = __expf(dt * a0);
            float e1 = __expf(dt * a1);
            float du = dt * u;
            h0 = fmaf(e0, h0, du * Bv.x);
            h1 = fmaf(e1, h1, du * Bv.y);
            py[j] = fmaf(h0, Cv.x, h1 * Cv.y);
            ud[j] = u * Dd;
        }
        // 8 independent 64-lane reductions (hide ds_swizzle latency with ILP)
        #pragma unroll
        for (int off = 32; off > 0; off >>= 1) {
            #pragma unroll
            for (int j = 0; j < 8; j++) py[j] += __shfl_xor(py[j], off);
        }
        if (lane == 0) {
            #pragma unroll
            for (int j = 0; j < 8; j++) pY[(t0 + j) * 512] = py[j] + ud[j];
        }
    }
}

// ---------------- host-side launch ----------------
extern "C" void kernel_launch(void* const* d_in, const int* in_sizes, int n_in,
                              void* d_out, int out_size, void* d_ws, size_t ws_size,
                              hipStream_t stream) {
    const float* inp   = (const float*)d_in[0];
    const float* in_w[2]  = {(const float*)d_in[1],  (const float*)d_in[8]};
    const float* cxw[2]   = {(const float*)d_in[2],  (const float*)d_in[9]};
    const float* czw[2]   = {(const float*)d_in[3],  (const float*)d_in[10]};
    const float* xw[2]    = {(const float*)d_in[4],  (const float*)d_in[11]};
    const float* dtw[2]   = {(const float*)d_in[5],  (const float*)d_in[12]};
    const float* dtb[2]   = {(const float*)d_in[6],  (const float*)d_in[13]};
    const float* outw[2]  = {(const float*)d_in[7],  (const float*)d_in[14]};
    const float* A_log = (const float*)d_in[15];
    const float* Dvec  = (const float*)d_in[16];
    const float* eps   = (const float*)d_in[17];
    float* out = (float*)d_out;
    float* ws  = (float*)d_ws;

    computeA_kernel<<<1, 256, 0, stream>>>(A_log, eps, ws);

    for (int br = 0; br < 2; br++) {
        float* xin  = ws + OFF_XIN;
        float* xz   = ws + OFF_XZ;
        float* xdbl = ws + OFF_XDBL;
        float* xs_b = ws + OFF_XS  + (size_t)br * NROW * 256;
        float* dl_b = ws + OFF_DLT + (size_t)br * NROW * 256;
        float* Bs_b = ws + OFF_BS  + (size_t)br * NROW * 128;
        float* Cs_b = ws + OFF_CS  + (size_t)br * NROW * 128;
        float* yz_b = ws + OFF_YZ  + (size_t)br * NROW * 512;
        float* thrb = ws + OFF_THR + 2 * br;

        transpose_in_kernel<<<dim3(L_ / 32, 512 / 32, B_), dim3(32, 8), 0, stream>>>(
            inp, xin, br * 512);

        gemm_nt<0><<<dim3(512 / 64, NROW / 64), 256, 0, stream>>>(
            xin, 512, in_w[br], nullptr, xz, 512, NROW, 512, 512);

        conv_silu_kernel<<<(NROW * HALF_) / 256, 256, 0, stream>>>(
            xz, xs_b, yz_b, cxw[br], czw[br]);

        gemm_nt<0><<<dim3((288 + 63) / 64, NROW / 64), 256, 0, stream>>>(
            xs_b, 256, xw[br], nullptr, xdbl, 288, NROW, 288, 256);

        gemm_nt<1><<<dim3(256 / 64, NROW / 64), 256, 0, stream>>>(
            xdbl, 288, dtw[br], dtb[br], dl_b, 256, NROW, 256, 32);

        redmax_kernel<<<128, 256, 0, stream>>>(xdbl, ws + OFF_PART);
        finmax_kernel<<<1, 64, 0, stream>>>(ws + OFF_PART, thrb);

        shrinkpack_kernel<<<(NROW * 128) / 256, 256, 0, stream>>>(
            xdbl, thrb, Bs_b, Cs_b);
    }

    // both branches' scans in one launch: 1024 waves total
    scan_kernel<<<dim3(HALF_, B_, 2), 64, 0, stream>>>(ws, Dvec);

    for (int br = 0; br < 2; br++) {
        float* yz_b = ws + OFF_YZ + (size_t)br * NROW * 512;
        gemm_nt<0><<<dim3(512 / 64, NROW / 64), 256, 0, stream>>>(
            yz_b, 512, outw[br], nullptr, out + (size_t)br * NROW * 512, 512,
            NROW, 512, 512);
    }
}

// Round 2
// 751.708 us; speedup vs baseline: 1.2328x; 1.2328x over previous
//
#include <hip/hip_runtime.h>
#include <math.h>

// ---------------- problem constants ----------------
constexpr int B_    = 2;
constexpr int L_    = 2048;
constexpr int NROW  = B_ * L_;     // 4096
constexpr int HALF_ = 256;
constexpr int DS_   = 128;         // D_STATE

// ---------------- ws layout (floats) ----------------
constexpr size_t OFF_A1   = 0;
constexpr size_t OFF_A2   = OFF_A1 + (size_t)HALF_ * DS_;       // 32768
constexpr size_t OFF_THR  = OFF_A2 + (size_t)HALF_ * DS_;       // 4
constexpr size_t OFF_PART = OFF_THR + 4;                        // 256
constexpr size_t OFF_XIN  = OFF_PART + 256;                     // 4096x512 transient; ALIASED as YT after branch loop
constexpr size_t OFF_XZ   = OFF_XIN + (size_t)NROW * 512;       // 4096x512 transient
constexpr size_t OFF_XDBL = OFF_XZ  + (size_t)NROW * 512;       // 4096x288 transient
constexpr size_t OFF_XS   = OFF_XDBL + (size_t)NROW * 288;      // 4096x256 transient (per-branch reuse)
constexpr size_t OFF_DLT  = OFF_XS  + (size_t)NROW * 256;       // 4096x256 transient (per-branch reuse)
constexpr size_t OFF_BS   = OFF_DLT + (size_t)NROW * 256;       // 2 x 4096x128
constexpr size_t OFF_CS   = OFF_BS  + (size_t)2 * NROW * 128;   // 2 x 4096x128
constexpr size_t OFF_YZ   = OFF_CS  + (size_t)2 * NROW * 128;   // 2 x 4096x512
constexpr size_t OFF_DTT  = OFF_YZ  + (size_t)2 * NROW * 512;   // 2 x 256x4096 (d-major delta)
constexpr size_t OFF_UT   = OFF_DTT + (size_t)2 * 256 * 4096;   // 2 x 256x4096 (d-major u)
constexpr size_t OFF_YT   = OFF_XIN;                            // alias: 2 x 256x4096 (d-major y)

// ---------------- device helpers ----------------
__device__ __forceinline__ float shrinkf(float v, float thr) {
    float a = fabsf(v) - thr;
    a = fmaxf(a, 0.0f);
    float r = copysignf(a, v);
    return (v == 0.0f) ? 0.0f : r;
}

__device__ __forceinline__ float siluf(float v) {
    return v / (1.0f + __expf(-v));
}

__device__ __forceinline__ float softplusf(float v) {
    return fmaxf(v, 0.0f) + log1pf(__expf(-fabsf(v)));
}

__device__ __forceinline__ float blockMaxAll(float v, float* sbuf) {
    __syncthreads();
    #pragma unroll
    for (int off = 32; off > 0; off >>= 1) v = fmaxf(v, __shfl_xor(v, off));
    int w = threadIdx.x >> 6;
    if ((threadIdx.x & 63) == 0) sbuf[w] = v;
    __syncthreads();
    int nw = blockDim.x >> 6;
    float r = (threadIdx.x < nw) ? sbuf[threadIdx.x] : -INFINITY;
    #pragma unroll
    for (int off = 32; off > 0; off >>= 1) r = fmaxf(r, __shfl_xor(r, off));
    if (threadIdx.x == 0) sbuf[0] = r;
    __syncthreads();
    return sbuf[0];
}

// ---------------- A1/A2 precompute (one block) ----------------
__global__ __launch_bounds__(256) void computeA_kernel(const float* __restrict__ A_log,
                                                       const float* __restrict__ eps,
                                                       float* __restrict__ ws) {
    __shared__ float sbuf[8];
    float* A1 = ws + OFF_A1;
    float* A2 = ws + OFF_A2;
    const int N = HALF_ * DS_;
    float e = 1.0f + eps[0];
    float mx = -INFINITY;
    for (int i = threadIdx.x; i < N; i += 256) {
        float base = -e * __expf(A_log[i]);
        A1[i] = base;
        mx = fmaxf(mx, base);
    }
    float thr1 = 0.1f * blockMaxAll(mx, sbuf);
    float mx2 = -INFINITY;
    for (int i = threadIdx.x; i < N; i += 256) {
        float v = shrinkf(A1[i], thr1);
        A1[i] = v;
        mx2 = fmaxf(mx2, v);
    }
    float thr2 = 0.1f * blockMaxAll(mx2, sbuf);
    for (int i = threadIdx.x; i < N; i += 256) {
        A2[i] = shrinkf(A1[i], thr2);
    }
}

// ---------------- input transpose: (B, 1024, L) slice -> (B*L, 512) ----------------
__global__ __launch_bounds__(256) void transpose_in_kernel(const float* __restrict__ inp,
                                                           float* __restrict__ xin, int coff) {
    __shared__ float tile[32][33];
    int b  = blockIdx.z;
    int t0 = blockIdx.x * 32;
    int m0 = blockIdx.y * 32;
    int tx = threadIdx.x;
    int ty = threadIdx.y;
    #pragma unroll
    for (int k = 0; k < 4; k++) {
        tile[ty + 8 * k][tx] =
            inp[((size_t)b * 1024 + coff + m0 + ty + 8 * k) * L_ + t0 + tx];
    }
    __syncthreads();
    #pragma unroll
    for (int k = 0; k < 4; k++) {
        xin[((size_t)b * L_ + t0 + ty + 8 * k) * 512 + m0 + tx] = tile[tx][ty + 8 * k];
    }
}

// ---------------- generic 2D transpose: dst[n*ld + m] = src[m*ls + n] ----------------
// M, N multiples of 32. grid (M/32, N/32), block (32, 8)
__global__ __launch_bounds__(256) void transpose2d_kernel(const float* __restrict__ src,
                                                          float* __restrict__ dst,
                                                          int ls, int ld) {
    __shared__ float tile[32][33];
    int m0 = blockIdx.x * 32;
    int n0 = blockIdx.y * 32;
    int tx = threadIdx.x;
    int ty = threadIdx.y;
    #pragma unroll
    for (int k = 0; k < 4; k++) {
        tile[ty + 8 * k][tx] = src[(size_t)(m0 + ty + 8 * k) * ls + n0 + tx];
    }
    __syncthreads();
    #pragma unroll
    for (int k = 0; k < 4; k++) {
        dst[(size_t)(n0 + ty + 8 * k) * ld + m0 + tx] = tile[tx][ty + 8 * k];
    }
}

// ---------------- generic fp32 GEMM: C[M,N] = A[M,K] * W[N,K]^T ----------------
template <int EPI>
__global__ __launch_bounds__(256) void gemm_nt(const float* __restrict__ A, int lda,
                                               const float* __restrict__ W,
                                               const float* __restrict__ bias,
                                               float* __restrict__ C, int ldc,
                                               int M, int N, int K) {
    __shared__ float As[16][68];
    __shared__ float Ws[16][68];
    int tid = threadIdx.x;
    int kk = tid & 15;
    int rr = tid >> 4;
    int mblk = blockIdx.y * 64;
    int nblk = blockIdx.x * 64;
    float acc[4][4] = {};
    for (int k0 = 0; k0 < K; k0 += 16) {
        #pragma unroll
        for (int j = 0; j < 4; j++) {
            As[kk][rr + 16 * j] = A[(size_t)(mblk + rr + 16 * j) * lda + k0 + kk];
        }
        #pragma unroll
        for (int j = 0; j < 4; j++) {
            int n = nblk + rr + 16 * j;
            Ws[kk][rr + 16 * j] = (n < N) ? W[(size_t)n * K + k0 + kk] : 0.0f;
        }
        __syncthreads();
        int ty = tid >> 4;
        int tx = tid & 15;
        #pragma unroll
        for (int kq = 0; kq < 16; kq++) {
            float a0 = As[kq][ty * 4 + 0];
            float a1 = As[kq][ty * 4 + 1];
            float a2 = As[kq][ty * 4 + 2];
            float a3 = As[kq][ty * 4 + 3];
            float b0 = Ws[kq][tx * 4 + 0];
            float b1 = Ws[kq][tx * 4 + 1];
            float b2 = Ws[kq][tx * 4 + 2];
            float b3 = Ws[kq][tx * 4 + 3];
            acc[0][0] = fmaf(a0, b0, acc[0][0]); acc[0][1] = fmaf(a0, b1, acc[0][1]);
            acc[0][2] = fmaf(a0, b2, acc[0][2]); acc[0][3] = fmaf(a0, b3, acc[0][3]);
            acc[1][0] = fmaf(a1, b0, acc[1][0]); acc[1][1] = fmaf(a1, b1, acc[1][1]);
            acc[1][2] = fmaf(a1, b2, acc[1][2]); acc[1][3] = fmaf(a1, b3, acc[1][3]);
            acc[2][0] = fmaf(a2, b0, acc[2][0]); acc[2][1] = fmaf(a2, b1, acc[2][1]);
            acc[2][2] = fmaf(a2, b2, acc[2][2]); acc[2][3] = fmaf(a2, b3, acc[2][3]);
            acc[3][0] = fmaf(a3, b0, acc[3][0]); acc[3][1] = fmaf(a3, b1, acc[3][1]);
            acc[3][2] = fmaf(a3, b2, acc[3][2]); acc[3][3] = fmaf(a3, b3, acc[3][3]);
        }
        __syncthreads();
    }
    int ty = tid >> 4;
    int tx = tid & 15;
    #pragma unroll
    for (int i = 0; i < 4; i++) {
        int m = mblk + ty * 4 + i;
        #pragma unroll
        for (int j = 0; j < 4; j++) {
            int n = nblk + tx * 4 + j;
            if (n < N) {
                float v = acc[i][j];
                if (EPI == 1) v = softplusf(v + bias[n]);
                C[(size_t)m * ldc + n] = v;
            }
        }
    }
}

// ---------------- depthwise conv (k=4, pad 1/2) + SiLU ----------------
__global__ __launch_bounds__(256) void conv_silu_kernel(const float* __restrict__ xz,
                                                        float* __restrict__ xs,
                                                        float* __restrict__ yz,
                                                        const float* __restrict__ wx,
                                                        const float* __restrict__ wz) {
    int idx = blockIdx.x * 256 + threadIdx.x;
    if (idx >= NROW * HALF_) return;
    int c   = idx & 255;
    int row = idx >> 8;
    int t   = row & (L_ - 1);
    float ax = 0.0f, az = 0.0f;
    #pragma unroll
    for (int j = 0; j < 4; j++) {
        int tt = t + j - 1;
        if (tt >= 0 && tt < L_) {
            const float* p = xz + (size_t)(row + j - 1) * 512;
            ax = fmaf(p[c], wx[c * 4 + j], ax);
            az = fmaf(p[c + 256], wz[c * 4 + j], az);
        }
    }
    xs[(size_t)row * 256 + c] = siluf(ax);
    yz[(size_t)row * 512 + 256 + c] = siluf(az);
}

// ---------------- global signed-max over Bc/Cc slices ----------------
__global__ __launch_bounds__(256) void redmax_kernel(const float* __restrict__ xdbl,
                                                     float* __restrict__ part) {
    __shared__ float sbuf[8];
    float mb = -INFINITY, mc = -INFINITY;
    const size_t total = (size_t)NROW * 128;
    for (size_t i = (size_t)blockIdx.x * 256 + threadIdx.x; i < total;
         i += (size_t)gridDim.x * 256) {
        size_t row = i >> 7;
        int n = (int)(i & 127);
        const float* p = xdbl + row * 288;
        mb = fmaxf(mb, p[32 + n]);
        mc = fmaxf(mc, p[160 + n]);
    }
    mb = blockMaxAll(mb, sbuf);
    mc = blockMaxAll(mc, sbuf);
    if (threadIdx.x == 0) {
        part[blockIdx.x] = mb;
        part[128 + blockIdx.x] = mc;
    }
}

__global__ __launch_bounds__(64) void finmax_kernel(const float* __restrict__ part,
                                                    float* __restrict__ thr) {
    int l = threadIdx.x;
    float vb = fmaxf(part[l], part[l + 64]);
    float vc = fmaxf(part[128 + l], part[192 + l]);
    #pragma unroll
    for (int off = 32; off > 0; off >>= 1) {
        vb = fmaxf(vb, __shfl_xor(vb, off));
        vc = fmaxf(vc, __shfl_xor(vc, off));
    }
    if (l == 0) {
        thr[0] = 0.1f * vb;
        thr[1] = 0.1f * vc;
    }
}

// ---------------- shrink + pack Bc/Cc into contiguous (row,128) ----------------
__global__ __launch_bounds__(256) void shrinkpack_kernel(const float* __restrict__ xdbl,
                                                         const float* __restrict__ thr,
                                                         float* __restrict__ Bs,
                                                         float* __restrict__ Cs) {
    int idx = blockIdx.x * 256 + threadIdx.x;
    if (idx >= NROW * 128) return;
    int row = idx >> 7;
    int n = idx & 127;
    float tB = thr[0], tC = thr[1];
    const float* p = xdbl + (size_t)row * 288;
    Bs[idx] = shrinkf(p[32 + n], tB);
    Cs[idx] = shrinkf(p[160 + n], tC);
}

// ---------------- selective scan v2 ----------------
// One wave per (br,b,d) chain. d-major dt/u (coalesced chunk loads + readlane
// broadcast), register-double-buffered B/C prefetch, LDS transpose-reduce per
// 64-t chunk (replaces per-8t butterfly), coalesced yT stores, XCD-aware remap.
__global__ __launch_bounds__(64) void scan2_kernel(float* __restrict__ ws,
                                                   const float* __restrict__ Dvec) {
    // blockIdx.x in [0,1024): xcd = blk%8. Chains of one (br,b) combo land on
    // an XCD pair -> B/C stream fetched once per XCD pair, write lines local.
    int blk  = blockIdx.x;
    int xcd  = blk & 7;
    int slot = blk >> 3;            // 0..127
    int combo = xcd >> 1;           // 0..3
    int d  = (xcd & 1) * 128 + slot;
    int br = combo >> 1;
    int b  = combo & 1;
    int lane = threadIdx.x;

    const float* A = ws + (br ? OFF_A2 : OFF_A1);
    const float*  dtT = ws + OFF_DTT + ((size_t)br * 256 + d) * 4096 + (size_t)b * L_;
    const float*  uT  = ws + OFF_UT  + ((size_t)br * 256 + d) * 4096 + (size_t)b * L_;
    const float2* Bp  = (const float2*)(ws + OFF_BS + ((size_t)br * NROW + (size_t)b * L_) * 128) + lane;
    const float2* Cp  = (const float2*)(ws + OFF_CS + ((size_t)br * NROW + (size_t)b * L_) * 128) + lane;
    float*        yTp = ws + OFF_YT  + ((size_t)br * 256 + d) * 4096 + (size_t)b * L_ + lane;

    __shared__ float red[64 * 65];   // [t_in_chunk][lane], +1 pad: conflict-free

    float a0 = A[d * 128 + 2 * lane];
    float a1 = A[d * 128 + 2 * lane + 1];
    float Dd = Dvec[d];
    float h0 = 0.0f, h1 = 0.0f;

    // pipeline state
    float2 Bb[2][8], Cb[2][8];
    float dt_c = dtT[lane];
    float u_c  = uT[lane];
    float dt_n = 0.0f, u_n = 0.0f;
    #pragma unroll
    for (int j = 0; j < 8; j++) { Bb[0][j] = Bp[(size_t)j * 64];       Cb[0][j] = Cp[(size_t)j * 64]; }
    #pragma unroll
    for (int j = 0; j < 8; j++) { Bb[1][j] = Bp[(size_t)(8 + j) * 64]; Cb[1][j] = Cp[(size_t)(8 + j) * 64]; }

    for (int c = 0; c < 32; c++) {
        if (c < 31) {
            dt_n = dtT[(c + 1) * 64 + lane];
            u_n  = uT[(c + 1) * 64 + lane];
        }
        #pragma unroll
        for (int m = 0; m < 8; m++) {
            const int cur = m & 1;
            #pragma unroll
            for (int j = 0; j < 8; j++) {
                const int tl = m * 8 + j;              // compile-time lane idx
                float dt = __shfl(dt_c, tl, 64);
                float u  = __shfl(u_c,  tl, 64);
                float2 Bv = Bb[cur][j];
                float2 Cv = Cb[cur][j];
                float e0 = __expf(dt * a0);
                float e1 = __expf(dt * a1);
                float du = dt * u;
                h0 = fmaf(e0, h0, du * Bv.x);
                h1 = fmaf(e1, h1, du * Bv.y);
                red[tl * 65 + lane] = fmaf(h0, Cv.x, h1 * Cv.y);
            }
            // refill freed buffer with batch (global batch index + 2)
            int nb = c * 8 + m + 2;
            if (nb < 256) {
                #pragma unroll
                for (int j = 0; j < 8; j++) {
                    Bb[cur][j] = Bp[((size_t)nb * 8 + j) * 64];
                    Cb[cur][j] = Cp[((size_t)nb * 8 + j) * 64];
                }
            }
        }
        __syncthreads();   // single-wave block: cheap lgkm drain + barrier
        // lane l sums row l -> y for t = c*64 + l  (banks (l+i)%32: conflict-free)
        float s0 = 0.f, s1 = 0.f, s2 = 0.f, s3 = 0.f;
        const float* rp = &red[lane * 65];
        #pragma unroll
        for (int i = 0; i < 64; i += 4) {
            s0 += rp[i]; s1 += rp[i + 1]; s2 += rp[i + 2]; s3 += rp[i + 3];
        }
        float y = (s0 + s1) + (s2 + s3) + u_c * Dd;
        yTp[c * 64] = y;
        __syncthreads();   // WAR: protect red before next chunk's writes
        dt_c = dt_n;
        u_c  = u_n;
    }
}

// ---------------- host-side launch ----------------
extern "C" void kernel_launch(void* const* d_in, const int* in_sizes, int n_in,
                              void* d_out, int out_size, void* d_ws, size_t ws_size,
                              hipStream_t stream) {
    const float* inp   = (const float*)d_in[0];
    const float* in_w[2]  = {(const float*)d_in[1],  (const float*)d_in[8]};
    const float* cxw[2]   = {(const float*)d_in[2],  (const float*)d_in[9]};
    const float* czw[2]   = {(const float*)d_in[3],  (const float*)d_in[10]};
    const float* xw[2]    = {(const float*)d_in[4],  (const float*)d_in[11]};
    const float* dtw[2]   = {(const float*)d_in[5],  (const float*)d_in[12]};
    const float* dtb[2]   = {(const float*)d_in[6],  (const float*)d_in[13]};
    const float* outw[2]  = {(const float*)d_in[7],  (const float*)d_in[14]};
    const float* A_log = (const float*)d_in[15];
    const float* Dvec  = (const float*)d_in[16];
    const float* eps   = (const float*)d_in[17];
    float* out = (float*)d_out;
    float* ws  = (float*)d_ws;

    computeA_kernel<<<1, 256, 0, stream>>>(A_log, eps, ws);

    for (int br = 0; br < 2; br++) {
        float* xin  = ws + OFF_XIN;
        float* xz   = ws + OFF_XZ;
        float* xdbl = ws + OFF_XDBL;
        float* xs_b = ws + OFF_XS;                              // per-branch transient
        float* dl_b = ws + OFF_DLT;                             // per-branch transient
        float* Bs_b = ws + OFF_BS  + (size_t)br * NROW * 128;
        float* Cs_b = ws + OFF_CS  + (size_t)br * NROW * 128;
        float* yz_b = ws + OFF_YZ  + (size_t)br * NROW * 512;
        float* dtT  = ws + OFF_DTT + (size_t)br * 256 * 4096;
        float* uT   = ws + OFF_UT  + (size_t)br * 256 * 4096;
        float* thrb = ws + OFF_THR + 2 * br;

        transpose_in_kernel<<<dim3(L_ / 32, 512 / 32, B_), dim3(32, 8), 0, stream>>>(
            inp, xin, br * 512);

        gemm_nt<0><<<dim3(512 / 64, NROW / 64), 256, 0, stream>>>(
            xin, 512, in_w[br], nullptr, xz, 512, NROW, 512, 512);

        conv_silu_kernel<<<(NROW * HALF_) / 256, 256, 0, stream>>>(
            xz, xs_b, yz_b, cxw[br], czw[br]);

        gemm_nt<0><<<dim3((288 + 63) / 64, NROW / 64), 256, 0, stream>>>(
            xs_b, 256, xw[br], nullptr, xdbl, 288, NROW, 288, 256);

        gemm_nt<1><<<dim3(256 / 64, NROW / 64), 256, 0, stream>>>(
            xdbl, 288, dtw[br], dtb[br], dl_b, 256, NROW, 256, 32);

        // d-major transposes for the scan: (4096 x 256) -> (256 x 4096)
        transpose2d_kernel<<<dim3(NROW / 32, 256 / 32), dim3(32, 8), 0, stream>>>(
            dl_b, dtT, 256, 4096);
        transpose2d_kernel<<<dim3(NROW / 32, 256 / 32), dim3(32, 8), 0, stream>>>(
            xs_b, uT, 256, 4096);

        redmax_kernel<<<128, 256, 0, stream>>>(xdbl, ws + OFF_PART);
        finmax_kernel<<<1, 64, 0, stream>>>(ws + OFF_PART, thrb);

        shrinkpack_kernel<<<(NROW * 128) / 256, 256, 0, stream>>>(
            xdbl, thrb, Bs_b, Cs_b);
    }

    // both branches' scans in one launch: 1024 waves, XCD-swizzled
    scan2_kernel<<<dim3(1024), 64, 0, stream>>>(ws, Dvec);

    // yT (256 x 4096, d-major) -> yz first half (row-major, ld 512)
    for (int br = 0; br < 2; br++) {
        const float* yT = ws + OFF_YT + (size_t)br * 256 * 4096;
        float* yz_b = ws + OFF_YZ + (size_t)br * NROW * 512;
        transpose2d_kernel<<<dim3(256 / 32, NROW / 32), dim3(32, 8), 0, stream>>>(
            yT, yz_b, 4096, 512);
    }

    for (int br = 0; br < 2; br++) {
        float* yz_b = ws + OFF_YZ + (size_t)br * NROW * 512;
        gemm_nt<0><<<dim3(512 / 64, NROW / 64), 256, 0, stream>>>(
            yz_b, 512, outw[br], nullptr, out + (size_t)br * NROW * 512, 512,
            NROW, 512, 512);
    }
}

// Round 4
// 683.946 us; speedup vs baseline: 1.3549x; 1.0991x over previous
//
#include <hip/hip_runtime.h>
#include <math.h>

// ---------------- problem constants ----------------
constexpr int B_    = 2;
constexpr int L_    = 2048;
constexpr int NROW  = B_ * L_;     // 4096
constexpr int HALF_ = 256;
constexpr int DS_   = 128;         // D_STATE

constexpr float LOG2E = 1.4426950408889634f;

// ---------------- ws layout (floats) ----------------
constexpr size_t OFF_A1   = 0;
constexpr size_t OFF_A2   = OFF_A1 + (size_t)HALF_ * DS_;       // 32768
constexpr size_t OFF_THR  = OFF_A2 + (size_t)HALF_ * DS_;       // 4
constexpr size_t OFF_PART = OFF_THR + 4;                        // 256
constexpr size_t OFF_XIN  = OFF_PART + 256;                     // 4096x512 transient; ALIASED as YT after branch loop
constexpr size_t OFF_XZ   = OFF_XIN + (size_t)NROW * 512;       // 4096x512 transient
constexpr size_t OFF_XDBL = OFF_XZ  + (size_t)NROW * 512;       // 4096x288 transient
constexpr size_t OFF_XS   = OFF_XDBL + (size_t)NROW * 288;      // 4096x256 transient (per-branch reuse)
constexpr size_t OFF_DLT  = OFF_XS  + (size_t)NROW * 256;       // 4096x256 transient (per-branch reuse)
constexpr size_t OFF_BS   = OFF_DLT + (size_t)NROW * 256;       // 2 x 4096x128
constexpr size_t OFF_CS   = OFF_BS  + (size_t)2 * NROW * 128;   // 2 x 4096x128
constexpr size_t OFF_YZ   = OFF_CS  + (size_t)2 * NROW * 128;   // 2 x 4096x512
constexpr size_t OFF_DTT  = OFF_YZ  + (size_t)2 * NROW * 512;   // 2 x 256x4096  dt*log2e (d-major)
constexpr size_t OFF_DUT  = OFF_DTT + (size_t)2 * 256 * 4096;   // 2 x 256x4096  dt*u     (d-major)
constexpr size_t OFF_UDT  = OFF_DUT + (size_t)2 * 256 * 4096;   // 2 x 256x4096  u*D      (d-major)
constexpr size_t OFF_YT   = OFF_XIN;                            // alias: 2 x 256x4096 (d-major y)

// ---------------- device helpers ----------------
__device__ __forceinline__ float shrinkf(float v, float thr) {
    float a = fabsf(v) - thr;
    a = fmaxf(a, 0.0f);
    float r = copysignf(a, v);
    return (v == 0.0f) ? 0.0f : r;
}

__device__ __forceinline__ float siluf(float v) {
    return v / (1.0f + __expf(-v));
}

__device__ __forceinline__ float softplusf(float v) {
    return fmaxf(v, 0.0f) + log1pf(__expf(-fabsf(v)));
}

__device__ __forceinline__ float rlanef(float v, int l) {
    return __int_as_float(__builtin_amdgcn_readlane(__float_as_int(v), l));
}

__device__ __forceinline__ float blockMaxAll(float v, float* sbuf) {
    __syncthreads();
    #pragma unroll
    for (int off = 32; off > 0; off >>= 1) v = fmaxf(v, __shfl_xor(v, off));
    int w = threadIdx.x >> 6;
    if ((threadIdx.x & 63) == 0) sbuf[w] = v;
    __syncthreads();
    int nw = blockDim.x >> 6;
    float r = (threadIdx.x < nw) ? sbuf[threadIdx.x] : -INFINITY;
    #pragma unroll
    for (int off = 32; off > 0; off >>= 1) r = fmaxf(r, __shfl_xor(r, off));
    if (threadIdx.x == 0) sbuf[0] = r;
    __syncthreads();
    return sbuf[0];
}

// ---------------- A1/A2 precompute (one block) ----------------
__global__ __launch_bounds__(256) void computeA_kernel(const float* __restrict__ A_log,
                                                       const float* __restrict__ eps,
                                                       float* __restrict__ ws) {
    __shared__ float sbuf[8];
    float* A1 = ws + OFF_A1;
    float* A2 = ws + OFF_A2;
    const int N = HALF_ * DS_;
    float e = 1.0f + eps[0];
    float mx = -INFINITY;
    for (int i = threadIdx.x; i < N; i += 256) {
        float base = -e * __expf(A_log[i]);
        A1[i] = base;
        mx = fmaxf(mx, base);
    }
    float thr1 = 0.1f * blockMaxAll(mx, sbuf);
    float mx2 = -INFINITY;
    for (int i = threadIdx.x; i < N; i += 256) {
        float v = shrinkf(A1[i], thr1);
        A1[i] = v;
        mx2 = fmaxf(mx2, v);
    }
    float thr2 = 0.1f * blockMaxAll(mx2, sbuf);
    for (int i = threadIdx.x; i < N; i += 256) {
        A2[i] = shrinkf(A1[i], thr2);
    }
}

// ---------------- input transpose: (B, 1024, L) slice -> (B*L, 512) ----------------
__global__ __launch_bounds__(256) void transpose_in_kernel(const float* __restrict__ inp,
                                                           float* __restrict__ xin, int coff) {
    __shared__ float tile[32][33];
    int b  = blockIdx.z;
    int t0 = blockIdx.x * 32;
    int m0 = blockIdx.y * 32;
    int tx = threadIdx.x;
    int ty = threadIdx.y;
    #pragma unroll
    for (int k = 0; k < 4; k++) {
        tile[ty + 8 * k][tx] =
            inp[((size_t)b * 1024 + coff + m0 + ty + 8 * k) * L_ + t0 + tx];
    }
    __syncthreads();
    #pragma unroll
    for (int k = 0; k < 4; k++) {
        xin[((size_t)b * L_ + t0 + ty + 8 * k) * 512 + m0 + tx] = tile[tx][ty + 8 * k];
    }
}

// ---------------- generic 2D transpose: dst[n*ld + m] = src[m*ls + n] ----------------
__global__ __launch_bounds__(256) void transpose2d_kernel(const float* __restrict__ src,
                                                          float* __restrict__ dst,
                                                          int ls, int ld) {
    __shared__ float tile[32][33];
    int m0 = blockIdx.x * 32;
    int n0 = blockIdx.y * 32;
    int tx = threadIdx.x;
    int ty = threadIdx.y;
    #pragma unroll
    for (int k = 0; k < 4; k++) {
        tile[ty + 8 * k][tx] = src[(size_t)(m0 + ty + 8 * k) * ls + n0 + tx];
    }
    __syncthreads();
    #pragma unroll
    for (int k = 0; k < 4; k++) {
        dst[(size_t)(n0 + ty + 8 * k) * ld + m0 + tx] = tile[tx][ty + 8 * k];
    }
}

// ---------------- fused scan-input prep ----------------
// dl (4096x256 delta), xs (4096x256 u)  ->  d-major 256x4096:
//   dtT = delta*log2e,  duT = delta*u,  udT = u*D[d]
__global__ __launch_bounds__(256) void prep_kernel(const float* __restrict__ dl,
                                                   const float* __restrict__ xs,
                                                   const float* __restrict__ Dvec,
                                                   float* __restrict__ dtT,
                                                   float* __restrict__ duT,
                                                   float* __restrict__ udT) {
    __shared__ float tD[32][33];
    __shared__ float tU[32][33];
    int m0 = blockIdx.x * 32;   // t rows
    int n0 = blockIdx.y * 32;   // d cols
    int tx = threadIdx.x;
    int ty = threadIdx.y;
    #pragma unroll
    for (int k = 0; k < 4; k++) {
        size_t src = (size_t)(m0 + ty + 8 * k) * 256 + n0 + tx;
        tD[ty + 8 * k][tx] = dl[src];
        tU[ty + 8 * k][tx] = xs[src];
    }
    __syncthreads();
    #pragma unroll
    for (int k = 0; k < 4; k++) {
        int d = n0 + ty + 8 * k;
        size_t dst = (size_t)d * 4096 + m0 + tx;
        float dv = tD[tx][ty + 8 * k];
        float uv = tU[tx][ty + 8 * k];
        dtT[dst] = dv * LOG2E;
        duT[dst] = dv * uv;
        udT[dst] = uv * Dvec[d];
    }
}

// ---------------- generic fp32 GEMM: C[M,N] = A[M,K] * W[N,K]^T ----------------
template <int EPI>
__global__ __launch_bounds__(256) void gemm_nt(const float* __restrict__ A, int lda,
                                               const float* __restrict__ W,
                                               const float* __restrict__ bias,
                                               float* __restrict__ C, int ldc,
                                               int M, int N, int K) {
    __shared__ float As[16][68];
    __shared__ float Ws[16][68];
    int tid = threadIdx.x;
    int kk = tid & 15;
    int rr = tid >> 4;
    int mblk = blockIdx.y * 64;
    int nblk = blockIdx.x * 64;
    float acc[4][4] = {};
    for (int k0 = 0; k0 < K; k0 += 16) {
        #pragma unroll
        for (int j = 0; j < 4; j++) {
            As[kk][rr + 16 * j] = A[(size_t)(mblk + rr + 16 * j) * lda + k0 + kk];
        }
        #pragma unroll
        for (int j = 0; j < 4; j++) {
            int n = nblk + rr + 16 * j;
            Ws[kk][rr + 16 * j] = (n < N) ? W[(size_t)n * K + k0 + kk] : 0.0f;
        }
        __syncthreads();
        int ty = tid >> 4;
        int tx = tid & 15;
        #pragma unroll
        for (int kq = 0; kq < 16; kq++) {
            float a0 = As[kq][ty * 4 + 0];
            float a1 = As[kq][ty * 4 + 1];
            float a2 = As[kq][ty * 4 + 2];
            float a3 = As[kq][ty * 4 + 3];
            float b0 = Ws[kq][tx * 4 + 0];
            float b1 = Ws[kq][tx * 4 + 1];
            float b2 = Ws[kq][tx * 4 + 2];
            float b3 = Ws[kq][tx * 4 + 3];
            acc[0][0] = fmaf(a0, b0, acc[0][0]); acc[0][1] = fmaf(a0, b1, acc[0][1]);
            acc[0][2] = fmaf(a0, b2, acc[0][2]); acc[0][3] = fmaf(a0, b3, acc[0][3]);
            acc[1][0] = fmaf(a1, b0, acc[1][0]); acc[1][1] = fmaf(a1, b1, acc[1][1]);
            acc[1][2] = fmaf(a1, b2, acc[1][2]); acc[1][3] = fmaf(a1, b3, acc[1][3]);
            acc[2][0] = fmaf(a2, b0, acc[2][0]); acc[2][1] = fmaf(a2, b1, acc[2][1]);
            acc[2][2] = fmaf(a2, b2, acc[2][2]); acc[2][3] = fmaf(a2, b3, acc[2][3]);
            acc[3][0] = fmaf(a3, b0, acc[3][0]); acc[3][1] = fmaf(a3, b1, acc[3][1]);
            acc[3][2] = fmaf(a3, b2, acc[3][2]); acc[3][3] = fmaf(a3, b3, acc[3][3]);
        }
        __syncthreads();
    }
    int ty = tid >> 4;
    int tx = tid & 15;
    #pragma unroll
    for (int i = 0; i < 4; i++) {
        int m = mblk + ty * 4 + i;
        #pragma unroll
        for (int j = 0; j < 4; j++) {
            int n = nblk + tx * 4 + j;
            if (n < N) {
                float v = acc[i][j];
                if (EPI == 1) v = softplusf(v + bias[n]);
                C[(size_t)m * ldc + n] = v;
            }
        }
    }
}

// ---------------- depthwise conv (k=4, pad 1/2) + SiLU ----------------
__global__ __launch_bounds__(256) void conv_silu_kernel(const float* __restrict__ xz,
                                                        float* __restrict__ xs,
                                                        float* __restrict__ yz,
                                                        const float* __restrict__ wx,
                                                        const float* __restrict__ wz) {
    int idx = blockIdx.x * 256 + threadIdx.x;
    if (idx >= NROW * HALF_) return;
    int c   = idx & 255;
    int row = idx >> 8;
    int t   = row & (L_ - 1);
    float ax = 0.0f, az = 0.0f;
    #pragma unroll
    for (int j = 0; j < 4; j++) {
        int tt = t + j - 1;
        if (tt >= 0 && tt < L_) {
            const float* p = xz + (size_t)(row + j - 1) * 512;
            ax = fmaf(p[c], wx[c * 4 + j], ax);
            az = fmaf(p[c + 256], wz[c * 4 + j], az);
        }
    }
    xs[(size_t)row * 256 + c] = siluf(ax);
    yz[(size_t)row * 512 + 256 + c] = siluf(az);
}

// ---------------- global signed-max over Bc/Cc slices ----------------
__global__ __launch_bounds__(256) void redmax_kernel(const float* __restrict__ xdbl,
                                                     float* __restrict__ part) {
    __shared__ float sbuf[8];
    float mb = -INFINITY, mc = -INFINITY;
    const size_t total = (size_t)NROW * 128;
    for (size_t i = (size_t)blockIdx.x * 256 + threadIdx.x; i < total;
         i += (size_t)gridDim.x * 256) {
        size_t row = i >> 7;
        int n = (int)(i & 127);
        const float* p = xdbl + row * 288;
        mb = fmaxf(mb, p[32 + n]);
        mc = fmaxf(mc, p[160 + n]);
    }
    mb = blockMaxAll(mb, sbuf);
    mc = blockMaxAll(mc, sbuf);
    if (threadIdx.x == 0) {
        part[blockIdx.x] = mb;
        part[128 + blockIdx.x] = mc;
    }
}

__global__ __launch_bounds__(64) void finmax_kernel(const float* __restrict__ part,
                                                    float* __restrict__ thr) {
    int l = threadIdx.x;
    float vb = fmaxf(part[l], part[l + 64]);
    float vc = fmaxf(part[128 + l], part[192 + l]);
    #pragma unroll
    for (int off = 32; off > 0; off >>= 1) {
        vb = fmaxf(vb, __shfl_xor(vb, off));
        vc = fmaxf(vc, __shfl_xor(vc, off));
    }
    if (l == 0) {
        thr[0] = 0.1f * vb;
        thr[1] = 0.1f * vc;
    }
}

// ---------------- shrink + pack Bc/Cc into contiguous (row,128) ----------------
__global__ __launch_bounds__(256) void shrinkpack_kernel(const float* __restrict__ xdbl,
                                                         const float* __restrict__ thr,
                                                         float* __restrict__ Bs,
                                                         float* __restrict__ Cs) {
    int idx = blockIdx.x * 256 + threadIdx.x;
    if (idx >= NROW * 128) return;
    int row = idx >> 7;
    int n = idx & 127;
    float tB = thr[0], tC = thr[1];
    const float* p = xdbl + (size_t)row * 288;
    Bs[idx] = shrinkf(p[32 + n], tB);
    Cs[idx] = shrinkf(p[160 + n], tC);
}

// ---------------- selective scan v3 ----------------
// 2 waves (128 threads) per (br,b,d) chain, 1 state/lane. Prescaled inputs
// (dt*log2e, dt*u, u*D) -> per-t work is mul+exp2+mul+fma+mul+ds_write.
// readlane broadcast (SALU path), register double-buffered B/C prefetch,
// LDS transpose-reduce per 64-t chunk, coalesced yT stores, XCD-aware remap.
__global__ __launch_bounds__(128) void scan3_kernel(float* __restrict__ ws) {
    int blk  = blockIdx.x;          // 0..1023
    int xcd  = blk & 7;
    int slot = blk >> 3;            // 0..127
    int combo = xcd >> 1;           // 0..3
    int d  = (xcd & 1) * 128 + slot;
    int br = combo >> 1;
    int b  = combo & 1;
    int tid = threadIdx.x;          // 0..127
    int lt  = tid & 63;

    const float* A   = ws + (br ? OFF_A2 : OFF_A1);
    size_t dchain = ((size_t)br * 256 + d) * 4096 + (size_t)b * L_;
    const float* dtT = ws + OFF_DTT + dchain;
    const float* duT = ws + OFF_DUT + dchain;
    const float* udT = ws + OFF_UDT + dchain;
    const float* Bp  = ws + OFF_BS + ((size_t)br * NROW + (size_t)b * L_) * 128 + tid;
    const float* Cp  = ws + OFF_CS + ((size_t)br * NROW + (size_t)b * L_) * 128 + tid;
    float*       yTp = ws + OFF_YT + dchain;

    __shared__ float red[64 * 132];   // [t_in_chunk][state], stride 132: aligned b128, uniform banks
    __shared__ float comb[64];

    float a = A[d * 128 + tid];
    float h = 0.0f;

    float Bb[2][8], Cb[2][8];
    float dt_c = dtT[lt];
    float du_c = duT[lt];
    float ud_c = udT[lt];
    float dt_n = 0.f, du_n = 0.f, ud_n = 0.f;
    #pragma unroll
    for (int j = 0; j < 8; j++) { Bb[0][j] = Bp[(size_t)j * 128];       Cb[0][j] = Cp[(size_t)j * 128]; }
    #pragma unroll
    for (int j = 0; j < 8; j++) { Bb[1][j] = Bp[(size_t)(8 + j) * 128]; Cb[1][j] = Cp[(size_t)(8 + j) * 128]; }

    for (int c = 0; c < 32; c++) {
        if (c < 31) {
            dt_n = dtT[(c + 1) * 64 + lt];
            du_n = duT[(c + 1) * 64 + lt];
            ud_n = udT[(c + 1) * 64 + lt];
        }
        #pragma unroll
        for (int m = 0; m < 8; m++) {
            const int cur = m & 1;
            #pragma unroll
            for (int j = 0; j < 8; j++) {
                const int tl = m * 8 + j;          // compile-time lane idx
                float dt2 = rlanef(dt_c, tl);
                float du  = rlanef(du_c, tl);
                float e = __builtin_amdgcn_exp2f(dt2 * a);
                h = fmaf(e, h, du * Bb[cur][j]);
                red[tl * 132 + tid] = h * Cb[cur][j];
            }
            int nb = c * 8 + m + 2;
            if (nb < 256) {
                #pragma unroll
                for (int j = 0; j < 8; j++) {
                    Bb[cur][j] = Bp[((size_t)nb * 8 + j) * 128];
                    Cb[cur][j] = Cp[((size_t)nb * 8 + j) * 128];
                }
            }
        }
        __syncthreads();
        // epilogue: thread handles row r=tid&63, half=tid>>6 (64 floats, 16x b128)
        {
            const float* rp = &red[(tid & 63) * 132 + (tid >> 6) * 64];
            float s0 = 0.f, s1 = 0.f, s2 = 0.f, s3 = 0.f;
            #pragma unroll
            for (int i = 0; i < 64; i += 4) {
                float4 v = *(const float4*)(rp + i);
                s0 += v.x; s1 += v.y; s2 += v.z; s3 += v.w;
            }
            float part = (s0 + s1) + (s2 + s3);
            if (tid >= 64) comb[tid - 64] = part;
            __syncthreads();
            if (tid < 64) yTp[c * 64 + tid] = part + comb[tid] + ud_c;
        }
        __syncthreads();   // WAR: red & comb reused next chunk
        dt_c = dt_n;
        du_c = du_n;
        ud_c = ud_n;
    }
}

// ---------------- host-side launch ----------------
extern "C" void kernel_launch(void* const* d_in, const int* in_sizes, int n_in,
                              void* d_out, int out_size, void* d_ws, size_t ws_size,
                              hipStream_t stream) {
    const float* inp   = (const float*)d_in[0];
    const float* in_w[2]  = {(const float*)d_in[1],  (const float*)d_in[8]};
    const float* cxw[2]   = {(const float*)d_in[2],  (const float*)d_in[9]};
    const float* czw[2]   = {(const float*)d_in[3],  (const float*)d_in[10]};
    const float* xw[2]    = {(const float*)d_in[4],  (const float*)d_in[11]};
    const float* dtw[2]   = {(const float*)d_in[5],  (const float*)d_in[12]};
    const float* dtb[2]   = {(const float*)d_in[6],  (const float*)d_in[13]};
    const float* outw[2]  = {(const float*)d_in[7],  (const float*)d_in[14]};
    const float* A_log = (const float*)d_in[15];
    const float* Dvec  = (const float*)d_in[16];
    const float* eps   = (const float*)d_in[17];
    float* out = (float*)d_out;
    float* ws  = (float*)d_ws;

    computeA_kernel<<<1, 256, 0, stream>>>(A_log, eps, ws);

    for (int br = 0; br < 2; br++) {
        float* xin  = ws + OFF_XIN;
        float* xz   = ws + OFF_XZ;
        float* xdbl = ws + OFF_XDBL;
        float* xs_b = ws + OFF_XS;                              // per-branch transient
        float* dl_b = ws + OFF_DLT;                             // per-branch transient
        float* Bs_b = ws + OFF_BS  + (size_t)br * NROW * 128;
        float* Cs_b = ws + OFF_CS  + (size_t)br * NROW * 128;
        float* yz_b = ws + OFF_YZ  + (size_t)br * NROW * 512;
        float* dtT  = ws + OFF_DTT + (size_t)br * 256 * 4096;
        float* duT  = ws + OFF_DUT + (size_t)br * 256 * 4096;
        float* udT  = ws + OFF_UDT + (size_t)br * 256 * 4096;
        float* thrb = ws + OFF_THR + 2 * br;

        transpose_in_kernel<<<dim3(L_ / 32, 512 / 32, B_), dim3(32, 8), 0, stream>>>(
            inp, xin, br * 512);

        gemm_nt<0><<<dim3(512 / 64, NROW / 64), 256, 0, stream>>>(
            xin, 512, in_w[br], nullptr, xz, 512, NROW, 512, 512);

        conv_silu_kernel<<<(NROW * HALF_) / 256, 256, 0, stream>>>(
            xz, xs_b, yz_b, cxw[br], czw[br]);

        gemm_nt<0><<<dim3((288 + 63) / 64, NROW / 64), 256, 0, stream>>>(
            xs_b, 256, xw[br], nullptr, xdbl, 288, NROW, 288, 256);

        gemm_nt<1><<<dim3(256 / 64, NROW / 64), 256, 0, stream>>>(
            xdbl, 288, dtw[br], dtb[br], dl_b, 256, NROW, 256, 32);

        // fused prep: (4096x256) delta,u -> d-major dt*log2e, dt*u, u*D
        prep_kernel<<<dim3(NROW / 32, 256 / 32), dim3(32, 8), 0, stream>>>(
            dl_b, xs_b, Dvec, dtT, duT, udT);

        redmax_kernel<<<128, 256, 0, stream>>>(xdbl, ws + OFF_PART);
        finmax_kernel<<<1, 64, 0, stream>>>(ws + OFF_PART, thrb);

        shrinkpack_kernel<<<(NROW * 128) / 256, 256, 0, stream>>>(
            xdbl, thrb, Bs_b, Cs_b);
    }

    // both branches' scans: 1024 blocks x 2 waves, XCD-swizzled
    scan3_kernel<<<dim3(1024), 128, 0, stream>>>(ws);

    // yT (256 x 4096, d-major) -> yz first half (row-major, ld 512)
    for (int br = 0; br < 2; br++) {
        const float* yT = ws + OFF_YT + (size_t)br * 256 * 4096;
        float* yz_b = ws + OFF_YZ + (size_t)br * NROW * 512;
        transpose2d_kernel<<<dim3(256 / 32, NROW / 32), dim3(32, 8), 0, stream>>>(
            yT, yz_b, 4096, 512);
    }

    for (int br = 0; br < 2; br++) {
        float* yz_b = ws + OFF_YZ + (size_t)br * NROW * 512;
        gemm_nt<0><<<dim3(512 / 64, NROW / 64), 256, 0, stream>>>(
            yz_b, 512, outw[br], nullptr, out + (size_t)br * NROW * 512, 512,
            NROW, 512, 512);
    }
}

// Round 5
// 509.474 us; speedup vs baseline: 1.8189x; 1.3425x over previous
//
#include <hip/hip_runtime.h>
#include <math.h>

// ---------------- problem constants ----------------
constexpr int B_    = 2;
constexpr int L_    = 2048;
constexpr int NROW  = B_ * L_;     // 4096
constexpr int HALF_ = 256;
constexpr int DS_   = 128;         // D_STATE

constexpr float LOG2E = 1.4426950408889634f;

// ---------------- ws layout ----------------
// fp32 region (element offsets)
constexpr size_t OFF_A1   = 0;                                   // 32768
constexpr size_t OFF_A2   = OFF_A1 + 32768;                      // 32768
constexpr size_t OFF_THR  = OFF_A2 + 32768;                      // 4
constexpr size_t OFF_PART = OFF_THR + 4;                         // 256
constexpr size_t OFF_XZ   = OFF_PART + 256;                      // 4096x512 transient; ALIASED as YT after branch loop
constexpr size_t OFF_XDBL = OFF_XZ  + (size_t)NROW * 512;        // 4096x288 transient
constexpr size_t OFF_XS   = OFF_XDBL + (size_t)NROW * 288;       // 4096x256 transient
constexpr size_t OFF_DLT  = OFF_XS  + (size_t)NROW * 256;        // 4096x256 transient
constexpr size_t OFF_BS   = OFF_DLT + (size_t)NROW * 256;        // 2 x 4096x128
constexpr size_t OFF_CS   = OFF_BS  + (size_t)2 * NROW * 128;    // 2 x 4096x128
constexpr size_t OFF_DTT  = OFF_CS  + (size_t)2 * NROW * 128;    // 2 x 256x4096
constexpr size_t OFF_DUT  = OFF_DTT + (size_t)2 * 256 * 4096;
constexpr size_t OFF_UDT  = OFF_DUT + (size_t)2 * 256 * 4096;
constexpr size_t FLOAT_END = OFF_UDT + (size_t)2 * 256 * 4096;
constexpr size_t OFF_YT   = OFF_XZ;   // alias: scan output, after XZ's last use

// bf16 region (ushort element offsets, based at ws + FLOAT_END floats)
constexpr size_t HOFF_XINH = 0;                                   // 4096x512
constexpr size_t HOFF_XINL = HOFF_XINH + (size_t)NROW * 512;
constexpr size_t HOFF_XSH  = HOFF_XINL + (size_t)NROW * 512;      // 4096x256
constexpr size_t HOFF_XSL  = HOFF_XSH  + (size_t)NROW * 256;
constexpr size_t HOFF_YZH  = HOFF_XSL  + (size_t)NROW * 256;      // 2 x 4096x512
constexpr size_t HOFF_YZL  = HOFF_YZH  + (size_t)2 * NROW * 512;
constexpr size_t HOFF_INWH = HOFF_YZL  + (size_t)2 * NROW * 512;  // 512x512 (per-branch reuse)
constexpr size_t HOFF_INWL = HOFF_INWH + 262144;
constexpr size_t HOFF_XWH  = HOFF_INWL + 262144;                  // 288x256 (per-branch reuse)
constexpr size_t HOFF_XWL  = HOFF_XWH  + 73728;
constexpr size_t HOFF_OUTWH= HOFF_XWL  + 73728;                   // 2 x 512x512
constexpr size_t HOFF_OUTWL= HOFF_OUTWH+ 524288;

// ---------------- types / helpers ----------------
typedef __bf16 bf16x8 __attribute__((ext_vector_type(8)));
typedef float  f32x4  __attribute__((ext_vector_type(4)));

__device__ __forceinline__ unsigned short bf16rn(float x) {
    unsigned u = __float_as_uint(x);
    unsigned r = (u + 0x7FFFu + ((u >> 16) & 1u)) >> 16;
    return (unsigned short)r;
}
__device__ __forceinline__ void split2(float x, unsigned short& h, unsigned short& l) {
    h = bf16rn(x);
    float hf = __uint_as_float(((unsigned)h) << 16);
    l = bf16rn(x - hf);
}

__device__ __forceinline__ float shrinkf(float v, float thr) {
    float a = fabsf(v) - thr;
    a = fmaxf(a, 0.0f);
    float r = copysignf(a, v);
    return (v == 0.0f) ? 0.0f : r;
}
__device__ __forceinline__ float siluf(float v) { return v / (1.0f + __expf(-v)); }
__device__ __forceinline__ float softplusf(float v) {
    return fmaxf(v, 0.0f) + log1pf(__expf(-fabsf(v)));
}
__device__ __forceinline__ float rlanef(float v, int l) {
    return __int_as_float(__builtin_amdgcn_readlane(__float_as_int(v), l));
}

__device__ __forceinline__ float blockMaxAll(float v, float* sbuf) {
    __syncthreads();
    #pragma unroll
    for (int off = 32; off > 0; off >>= 1) v = fmaxf(v, __shfl_xor(v, off));
    int w = threadIdx.x >> 6;
    if ((threadIdx.x & 63) == 0) sbuf[w] = v;
    __syncthreads();
    int nw = blockDim.x >> 6;
    float r = (threadIdx.x < nw) ? sbuf[threadIdx.x] : -INFINITY;
    #pragma unroll
    for (int off = 32; off > 0; off >>= 1) r = fmaxf(r, __shfl_xor(r, off));
    if (threadIdx.x == 0) sbuf[0] = r;
    __syncthreads();
    return sbuf[0];
}

// ---------------- A1/A2 precompute (one block) ----------------
__global__ __launch_bounds__(256) void computeA_kernel(const float* __restrict__ A_log,
                                                       const float* __restrict__ eps,
                                                       float* __restrict__ ws) {
    __shared__ float sbuf[8];
    float* A1 = ws + OFF_A1;
    float* A2 = ws + OFF_A2;
    const int N = HALF_ * DS_;
    float e = 1.0f + eps[0];
    float mx = -INFINITY;
    for (int i = threadIdx.x; i < N; i += 256) {
        float base = -e * __expf(A_log[i]);
        A1[i] = base;
        mx = fmaxf(mx, base);
    }
    float thr1 = 0.1f * blockMaxAll(mx, sbuf);
    float mx2 = -INFINITY;
    for (int i = threadIdx.x; i < N; i += 256) {
        float v = shrinkf(A1[i], thr1);
        A1[i] = v;
        mx2 = fmaxf(mx2, v);
    }
    float thr2 = 0.1f * blockMaxAll(mx2, sbuf);
    for (int i = threadIdx.x; i < N; i += 256) {
        A2[i] = shrinkf(A1[i], thr2);
    }
}

// ---------------- weight split: fp32 -> bf16 hi/lo ----------------
__global__ __launch_bounds__(256) void wsplit_kernel(const float* __restrict__ src,
                                                     unsigned short* __restrict__ dh,
                                                     unsigned short* __restrict__ dl,
                                                     int n) {
    int i = blockIdx.x * 256 + threadIdx.x;
    if (i >= n) return;
    unsigned short h, l;
    split2(src[i], h, l);
    dh[i] = h; dl[i] = l;
}

// ---------------- input transpose + split: (B,1024,L) slice -> bf16 hi/lo (B*L,512) ----------------
__global__ __launch_bounds__(256) void transpose_in_kernel(const float* __restrict__ inp,
                                                           unsigned short* __restrict__ xh,
                                                           unsigned short* __restrict__ xl,
                                                           int coff) {
    __shared__ float tile[32][33];
    int b  = blockIdx.z;
    int t0 = blockIdx.x * 32;
    int m0 = blockIdx.y * 32;
    int tx = threadIdx.x;
    int ty = threadIdx.y;
    #pragma unroll
    for (int k = 0; k < 4; k++) {
        tile[ty + 8 * k][tx] =
            inp[((size_t)b * 1024 + coff + m0 + ty + 8 * k) * L_ + t0 + tx];
    }
    __syncthreads();
    #pragma unroll
    for (int k = 0; k < 4; k++) {
        size_t dst = ((size_t)b * L_ + t0 + ty + 8 * k) * 512 + m0 + tx;
        unsigned short h, l;
        split2(tile[tx][ty + 8 * k], h, l);
        xh[dst] = h; xl[dst] = l;
    }
}

// ---------------- MFMA GEMM (bf16x3 split): C[M,N] = A[M,K] * W[N,K]^T, fp32 out ----------------
// A,W pre-split bf16 hi/lo, K-contiguous rows. Tile 64x64, BK=32, 256 thr.
// Wave w: rows [w*16,w*16+16), all 64 cols (4 n-tiles). 3 MFMA/tile (hh, hl, lh).
template <int NGUARD>
__global__ __launch_bounds__(256) void gemm_mfma(const unsigned short* __restrict__ Ah,
                                                 const unsigned short* __restrict__ Al, int lda,
                                                 const unsigned short* __restrict__ Wh,
                                                 const unsigned short* __restrict__ Wl,
                                                 float* __restrict__ C, int ldc,
                                                 int N, int K) {
    __shared__ __align__(16) unsigned short sAh[64 * 40];
    __shared__ __align__(16) unsigned short sAl[64 * 40];
    __shared__ __align__(16) unsigned short sBh[64 * 40];
    __shared__ __align__(16) unsigned short sBl[64 * 40];
    int tid  = threadIdx.x;
    int wid  = tid >> 6;
    int lane = tid & 63;
    int fr   = lane & 15;
    int kg   = lane >> 4;
    int mblk = blockIdx.y * 64;
    int nblk = blockIdx.x * 64;
    int srow = tid >> 2;            // 0..63
    int skp  = (tid & 3) * 8;       // 0,8,16,24 halves

    f32x4 acc[4] = {};

    for (int k0 = 0; k0 < K; k0 += 32) {
        uint4 vah = *(const uint4*)(Ah + (size_t)(mblk + srow) * lda + k0 + skp);
        uint4 val = *(const uint4*)(Al + (size_t)(mblk + srow) * lda + k0 + skp);
        uint4 vbh = {0, 0, 0, 0}, vbl = {0, 0, 0, 0};
        if (!NGUARD || (nblk + srow) < N) {
            vbh = *(const uint4*)(Wh + (size_t)(nblk + srow) * K + k0 + skp);
            vbl = *(const uint4*)(Wl + (size_t)(nblk + srow) * K + k0 + skp);
        }
        __syncthreads();   // WAR: previous iter's ds_reads done
        *(uint4*)(sAh + srow * 40 + skp) = vah;
        *(uint4*)(sAl + srow * 40 + skp) = val;
        *(uint4*)(sBh + srow * 40 + skp) = vbh;
        *(uint4*)(sBl + srow * 40 + skp) = vbl;
        __syncthreads();

        bf16x8 a_h = *(const bf16x8*)(sAh + (wid * 16 + fr) * 40 + kg * 8);
        bf16x8 a_l = *(const bf16x8*)(sAl + (wid * 16 + fr) * 40 + kg * 8);
        #pragma unroll
        for (int nt = 0; nt < 4; nt++) {
            bf16x8 b_h = *(const bf16x8*)(sBh + (nt * 16 + fr) * 40 + kg * 8);
            bf16x8 b_l = *(const bf16x8*)(sBl + (nt * 16 + fr) * 40 + kg * 8);
            acc[nt] = __builtin_amdgcn_mfma_f32_16x16x32_bf16(a_h, b_h, acc[nt], 0, 0, 0);
            acc[nt] = __builtin_amdgcn_mfma_f32_16x16x32_bf16(a_h, b_l, acc[nt], 0, 0, 0);
            acc[nt] = __builtin_amdgcn_mfma_f32_16x16x32_bf16(a_l, b_h, acc[nt], 0, 0, 0);
        }
    }
    // C/D layout: col = lane&15, row = (lane>>4)*4 + reg
    #pragma unroll
    for (int nt = 0; nt < 4; nt++) {
        int col = nblk + nt * 16 + fr;
        if (NGUARD && col >= N) continue;
        #pragma unroll
        for (int r = 0; r < 4; r++) {
            int row = mblk + wid * 16 + kg * 4 + r;
            C[(size_t)row * ldc + col] = acc[nt][r];
        }
    }
}

// ---------------- fused scan-input prep ----------------
__global__ __launch_bounds__(256) void prep_kernel(const float* __restrict__ dl,
                                                   const float* __restrict__ xs,
                                                   const float* __restrict__ Dvec,
                                                   float* __restrict__ dtT,
                                                   float* __restrict__ duT,
                                                   float* __restrict__ udT) {
    __shared__ float tD[32][33];
    __shared__ float tU[32][33];
    int m0 = blockIdx.x * 32;   // t rows
    int n0 = blockIdx.y * 32;   // d cols
    int tx = threadIdx.x;
    int ty = threadIdx.y;
    #pragma unroll
    for (int k = 0; k < 4; k++) {
        size_t src = (size_t)(m0 + ty + 8 * k) * 256 + n0 + tx;
        tD[ty + 8 * k][tx] = dl[src];
        tU[ty + 8 * k][tx] = xs[src];
    }
    __syncthreads();
    #pragma unroll
    for (int k = 0; k < 4; k++) {
        int d = n0 + ty + 8 * k;
        size_t dst = (size_t)d * 4096 + m0 + tx;
        float dv = tD[tx][ty + 8 * k];
        float uv = tU[tx][ty + 8 * k];
        dtT[dst] = dv * LOG2E;
        duT[dst] = dv * uv;
        udT[dst] = uv * Dvec[d];
    }
}

// ---------------- vector fp32 GEMM (kept for dt_proj, K=32) ----------------
template <int EPI>
__global__ __launch_bounds__(256) void gemm_nt(const float* __restrict__ A, int lda,
                                               const float* __restrict__ W,
                                               const float* __restrict__ bias,
                                               float* __restrict__ C, int ldc,
                                               int M, int N, int K) {
    __shared__ float As[16][68];
    __shared__ float Ws[16][68];
    int tid = threadIdx.x;
    int kk = tid & 15;
    int rr = tid >> 4;
    int mblk = blockIdx.y * 64;
    int nblk = blockIdx.x * 64;
    float acc[4][4] = {};
    for (int k0 = 0; k0 < K; k0 += 16) {
        #pragma unroll
        for (int j = 0; j < 4; j++) {
            As[kk][rr + 16 * j] = A[(size_t)(mblk + rr + 16 * j) * lda + k0 + kk];
        }
        #pragma unroll
        for (int j = 0; j < 4; j++) {
            int n = nblk + rr + 16 * j;
            Ws[kk][rr + 16 * j] = (n < N) ? W[(size_t)n * K + k0 + kk] : 0.0f;
        }
        __syncthreads();
        int ty = tid >> 4;
        int tx = tid & 15;
        #pragma unroll
        for (int kq = 0; kq < 16; kq++) {
            float a0 = As[kq][ty * 4 + 0];
            float a1 = As[kq][ty * 4 + 1];
            float a2 = As[kq][ty * 4 + 2];
            float a3 = As[kq][ty * 4 + 3];
            float b0 = Ws[kq][tx * 4 + 0];
            float b1 = Ws[kq][tx * 4 + 1];
            float b2 = Ws[kq][tx * 4 + 2];
            float b3 = Ws[kq][tx * 4 + 3];
            acc[0][0] = fmaf(a0, b0, acc[0][0]); acc[0][1] = fmaf(a0, b1, acc[0][1]);
            acc[0][2] = fmaf(a0, b2, acc[0][2]); acc[0][3] = fmaf(a0, b3, acc[0][3]);
            acc[1][0] = fmaf(a1, b0, acc[1][0]); acc[1][1] = fmaf(a1, b1, acc[1][1]);
            acc[1][2] = fmaf(a1, b2, acc[1][2]); acc[1][3] = fmaf(a1, b3, acc[1][3]);
            acc[2][0] = fmaf(a2, b0, acc[2][0]); acc[2][1] = fmaf(a2, b1, acc[2][1]);
            acc[2][2] = fmaf(a2, b2, acc[2][2]); acc[2][3] = fmaf(a2, b3, acc[2][3]);
            acc[3][0] = fmaf(a3, b0, acc[3][0]); acc[3][1] = fmaf(a3, b1, acc[3][1]);
            acc[3][2] = fmaf(a3, b2, acc[3][2]); acc[3][3] = fmaf(a3, b3, acc[3][3]);
        }
        __syncthreads();
    }
    int ty = tid >> 4;
    int tx = tid & 15;
    #pragma unroll
    for (int i = 0; i < 4; i++) {
        int m = mblk + ty * 4 + i;
        #pragma unroll
        for (int j = 0; j < 4; j++) {
            int n = nblk + tx * 4 + j;
            if (n < N) {
                float v = acc[i][j];
                if (EPI == 1) v = softplusf(v + bias[n]);
            C[(size_t)m * ldc + n] = v;
            }
        }
    }
}

// ---------------- depthwise conv (k=4) + SiLU, with split outputs ----------------
// xs: fp32 (scan/prep path); xsh/xsl: bf16 split (x_proj GEMM input);
// z half -> yzh/yzl cols 256..511 (out GEMM input).
__global__ __launch_bounds__(256) void conv_silu_kernel(const float* __restrict__ xz,
                                                        float* __restrict__ xs,
                                                        unsigned short* __restrict__ xsh,
                                                        unsigned short* __restrict__ xsl,
                                                        unsigned short* __restrict__ yzh,
                                                        unsigned short* __restrict__ yzl,
                                                        const float* __restrict__ wx,
                                                        const float* __restrict__ wz) {
    int idx = blockIdx.x * 256 + threadIdx.x;
    if (idx >= NROW * HALF_) return;
    int c   = idx & 255;
    int row = idx >> 8;
    int t   = row & (L_ - 1);
    float ax = 0.0f, az = 0.0f;
    #pragma unroll
    for (int j = 0; j < 4; j++) {
        int tt = t + j - 1;
        if (tt >= 0 && tt < L_) {
            const float* p = xz + (size_t)(row + j - 1) * 512;
            ax = fmaf(p[c], wx[c * 4 + j], ax);
            az = fmaf(p[c + 256], wz[c * 4 + j], az);
        }
    }
    float sx = siluf(ax);
    float sz = siluf(az);
    xs[(size_t)row * 256 + c] = sx;
    unsigned short h, l;
    split2(sx, h, l);
    xsh[(size_t)row * 256 + c] = h;
    xsl[(size_t)row * 256 + c] = l;
    split2(sz, h, l);
    yzh[(size_t)row * 512 + 256 + c] = h;
    yzl[(size_t)row * 512 + 256 + c] = l;
}

// ---------------- global signed-max over Bc/Cc slices ----------------
__global__ __launch_bounds__(256) void redmax_kernel(const float* __restrict__ xdbl,
                                                     float* __restrict__ part) {
    __shared__ float sbuf[8];
    float mb = -INFINITY, mc = -INFINITY;
    const size_t total = (size_t)NROW * 128;
    for (size_t i = (size_t)blockIdx.x * 256 + threadIdx.x; i < total;
         i += (size_t)gridDim.x * 256) {
        size_t row = i >> 7;
        int n = (int)(i & 127);
        const float* p = xdbl + row * 288;
        mb = fmaxf(mb, p[32 + n]);
        mc = fmaxf(mc, p[160 + n]);
    }
    mb = blockMaxAll(mb, sbuf);
    mc = blockMaxAll(mc, sbuf);
    if (threadIdx.x == 0) {
        part[blockIdx.x] = mb;
        part[128 + blockIdx.x] = mc;
    }
}

__global__ __launch_bounds__(64) void finmax_kernel(const float* __restrict__ part,
                                                    float* __restrict__ thr) {
    int l = threadIdx.x;
    float vb = fmaxf(part[l], part[l + 64]);
    float vc = fmaxf(part[128 + l], part[192 + l]);
    #pragma unroll
    for (int off = 32; off > 0; off >>= 1) {
        vb = fmaxf(vb, __shfl_xor(vb, off));
        vc = fmaxf(vc, __shfl_xor(vc, off));
    }
    if (l == 0) {
        thr[0] = 0.1f * vb;
        thr[1] = 0.1f * vc;
    }
}

// ---------------- shrink + pack Bc/Cc ----------------
__global__ __launch_bounds__(256) void shrinkpack_kernel(const float* __restrict__ xdbl,
                                                         const float* __restrict__ thr,
                                                         float* __restrict__ Bs,
                                                         float* __restrict__ Cs) {
    int idx = blockIdx.x * 256 + threadIdx.x;
    if (idx >= NROW * 128) return;
    int row = idx >> 7;
    int n = idx & 127;
    float tB = thr[0], tC = thr[1];
    const float* p = xdbl + (size_t)row * 288;
    Bs[idx] = shrinkf(p[32 + n], tB);
    Cs[idx] = shrinkf(p[160 + n], tC);
}

// ---------------- selective scan (v3, unchanged) ----------------
__global__ __launch_bounds__(128) void scan3_kernel(float* __restrict__ ws) {
    int blk  = blockIdx.x;
    int xcd  = blk & 7;
    int slot = blk >> 3;
    int combo = xcd >> 1;
    int d  = (xcd & 1) * 128 + slot;
    int br = combo >> 1;
    int b  = combo & 1;
    int tid = threadIdx.x;
    int lt  = tid & 63;

    const float* A   = ws + (br ? OFF_A2 : OFF_A1);
    size_t dchain = ((size_t)br * 256 + d) * 4096 + (size_t)b * L_;
    const float* dtT = ws + OFF_DTT + dchain;
    const float* duT = ws + OFF_DUT + dchain;
    const float* udT = ws + OFF_UDT + dchain;
    const float* Bp  = ws + OFF_BS + ((size_t)br * NROW + (size_t)b * L_) * 128 + tid;
    const float* Cp  = ws + OFF_CS + ((size_t)br * NROW + (size_t)b * L_) * 128 + tid;
    float*       yTp = ws + OFF_YT + dchain;

    __shared__ float red[64 * 132];
    __shared__ float comb[64];

    float a = A[d * 128 + tid];
    float h = 0.0f;

    float Bb[2][8], Cb[2][8];
    float dt_c = dtT[lt];
    float du_c = duT[lt];
    float ud_c = udT[lt];
    float dt_n = 0.f, du_n = 0.f, ud_n = 0.f;
    #pragma unroll
    for (int j = 0; j < 8; j++) { Bb[0][j] = Bp[(size_t)j * 128];       Cb[0][j] = Cp[(size_t)j * 128]; }
    #pragma unroll
    for (int j = 0; j < 8; j++) { Bb[1][j] = Bp[(size_t)(8 + j) * 128]; Cb[1][j] = Cp[(size_t)(8 + j) * 128]; }

    for (int c = 0; c < 32; c++) {
        if (c < 31) {
            dt_n = dtT[(c + 1) * 64 + lt];
            du_n = duT[(c + 1) * 64 + lt];
            ud_n = udT[(c + 1) * 64 + lt];
        }
        #pragma unroll
        for (int m = 0; m < 8; m++) {
            const int cur = m & 1;
            #pragma unroll
            for (int j = 0; j < 8; j++) {
                const int tl = m * 8 + j;
                float dt2 = rlanef(dt_c, tl);
                float du  = rlanef(du_c, tl);
                float e = __builtin_amdgcn_exp2f(dt2 * a);
                h = fmaf(e, h, du * Bb[cur][j]);
                red[tl * 132 + tid] = h * Cb[cur][j];
            }
            int nb = c * 8 + m + 2;
            if (nb < 256) {
                #pragma unroll
                for (int j = 0; j < 8; j++) {
                    Bb[cur][j] = Bp[((size_t)nb * 8 + j) * 128];
                    Cb[cur][j] = Cp[((size_t)nb * 8 + j) * 128];
                }
            }
        }
        __syncthreads();
        {
            const float* rp = &red[(tid & 63) * 132 + (tid >> 6) * 64];
            float s0 = 0.f, s1 = 0.f, s2 = 0.f, s3 = 0.f;
            #pragma unroll
            for (int i = 0; i < 64; i += 4) {
                float4 v = *(const float4*)(rp + i);
                s0 += v.x; s1 += v.y; s2 += v.z; s3 += v.w;
            }
            float part = (s0 + s1) + (s2 + s3);
            if (tid >= 64) comb[tid - 64] = part;
            __syncthreads();
            if (tid < 64) yTp[c * 64 + tid] = part + comb[tid] + ud_c;
        }
        __syncthreads();
        dt_c = dt_n;
        du_c = du_n;
        ud_c = ud_n;
    }
}

// ---------------- yT (256x4096 d-major) -> yz bf16 split (row-major, ld 512, cols 0..255) ----------------
__global__ __launch_bounds__(256) void transpose_yz_kernel(const float* __restrict__ yT,
                                                           unsigned short* __restrict__ yzh,
                                                           unsigned short* __restrict__ yzl) {
    __shared__ float tile[32][33];
    int m0 = blockIdx.x * 32;   // d rows
    int n0 = blockIdx.y * 32;   // t cols
    int tx = threadIdx.x;
    int ty = threadIdx.y;
    #pragma unroll
    for (int k = 0; k < 4; k++) {
        tile[ty + 8 * k][tx] = yT[(size_t)(m0 + ty + 8 * k) * 4096 + n0 + tx];
    }
    __syncthreads();
    #pragma unroll
    for (int k = 0; k < 4; k++) {
        size_t dst = (size_t)(n0 + ty + 8 * k) * 512 + m0 + tx;
        unsigned short h, l;
        split2(tile[tx][ty + 8 * k], h, l);
        yzh[dst] = h; yzl[dst] = l;
    }
}

// ---------------- host-side launch ----------------
extern "C" void kernel_launch(void* const* d_in, const int* in_sizes, int n_in,
                              void* d_out, int out_size, void* d_ws, size_t ws_size,
                              hipStream_t stream) {
    const float* inp   = (const float*)d_in[0];
    const float* in_w[2]  = {(const float*)d_in[1],  (const float*)d_in[8]};
    const float* cxw[2]   = {(const float*)d_in[2],  (const float*)d_in[9]};
    const float* czw[2]   = {(const float*)d_in[3],  (const float*)d_in[10]};
    const float* xw[2]    = {(const float*)d_in[4],  (const float*)d_in[11]};
    const float* dtw[2]   = {(const float*)d_in[5],  (const float*)d_in[12]};
    const float* dtb[2]   = {(const float*)d_in[6],  (const float*)d_in[13]};
    const float* outw[2]  = {(const float*)d_in[7],  (const float*)d_in[14]};
    const float* A_log = (const float*)d_in[15];
    const float* Dvec  = (const float*)d_in[16];
    const float* eps   = (const float*)d_in[17];
    float* out = (float*)d_out;
    float* ws  = (float*)d_ws;
    unsigned short* hb = (unsigned short*)(ws + FLOAT_END);

    computeA_kernel<<<1, 256, 0, stream>>>(A_log, eps, ws);

    for (int br = 0; br < 2; br++) {
        float* xz   = ws + OFF_XZ;
        float* xdbl = ws + OFF_XDBL;
        float* xs_b = ws + OFF_XS;
        float* dl_b = ws + OFF_DLT;
        float* Bs_b = ws + OFF_BS  + (size_t)br * NROW * 128;
        float* Cs_b = ws + OFF_CS  + (size_t)br * NROW * 128;
        float* dtT  = ws + OFF_DTT + (size_t)br * 256 * 4096;
        float* duT  = ws + OFF_DUT + (size_t)br * 256 * 4096;
        float* udT  = ws + OFF_UDT + (size_t)br * 256 * 4096;
        float* thrb = ws + OFF_THR + 2 * br;
        unsigned short* yzh_b = hb + HOFF_YZH + (size_t)br * NROW * 512;
        unsigned short* yzl_b = hb + HOFF_YZL + (size_t)br * NROW * 512;

        // input transpose + bf16 split
        transpose_in_kernel<<<dim3(L_ / 32, 512 / 32, B_), dim3(32, 8), 0, stream>>>(
            inp, hb + HOFF_XINH, hb + HOFF_XINL, br * 512);

        // weight splits for this branch
        wsplit_kernel<<<(262144 + 255) / 256, 256, 0, stream>>>(
            in_w[br], hb + HOFF_INWH, hb + HOFF_INWL, 262144);
        wsplit_kernel<<<(73728 + 255) / 256, 256, 0, stream>>>(
            xw[br], hb + HOFF_XWH, hb + HOFF_XWL, 73728);
        wsplit_kernel<<<(262144 + 255) / 256, 256, 0, stream>>>(
            outw[br], hb + HOFF_OUTWH + (size_t)br * 262144,
            hb + HOFF_OUTWL + (size_t)br * 262144, 262144);

        // in_proj: (4096x512) = xin * in_w^T   [MFMA bf16x3]
        gemm_mfma<0><<<dim3(512 / 64, NROW / 64), 256, 0, stream>>>(
            hb + HOFF_XINH, hb + HOFF_XINL, 512,
            hb + HOFF_INWH, hb + HOFF_INWL, xz, 512, 512, 512);

        conv_silu_kernel<<<(NROW * HALF_) / 256, 256, 0, stream>>>(
            xz, xs_b, hb + HOFF_XSH, hb + HOFF_XSL, yzh_b, yzl_b, cxw[br], czw[br]);

        // x_proj: (4096x288) = xs * xw^T   [MFMA bf16x3, N guard]
        gemm_mfma<1><<<dim3((288 + 63) / 64, NROW / 64), 256, 0, stream>>>(
            hb + HOFF_XSH, hb + HOFF_XSL, 256,
            hb + HOFF_XWH, hb + HOFF_XWL, xdbl, 288, 288, 256);

        // dt_proj (K=32, vector fp32) + softplus
        gemm_nt<1><<<dim3(256 / 64, NROW / 64), 256, 0, stream>>>(
            xdbl, 288, dtw[br], dtb[br], dl_b, 256, NROW, 256, 32);

        prep_kernel<<<dim3(NROW / 32, 256 / 32), dim3(32, 8), 0, stream>>>(
            dl_b, xs_b, Dvec, dtT, duT, udT);

        redmax_kernel<<<128, 256, 0, stream>>>(xdbl, ws + OFF_PART);
        finmax_kernel<<<1, 64, 0, stream>>>(ws + OFF_PART, thrb);

        shrinkpack_kernel<<<(NROW * 128) / 256, 256, 0, stream>>>(
            xdbl, thrb, Bs_b, Cs_b);
    }

    // both branches' scans: 1024 blocks x 2 waves, XCD-swizzled
    scan3_kernel<<<dim3(1024), 128, 0, stream>>>(ws);

    // yT -> yz bf16 split (y half), then out_proj MFMA
    for (int br = 0; br < 2; br++) {
        const float* yT = ws + OFF_YT + (size_t)br * 256 * 4096;
        unsigned short* yzh_b = hb + HOFF_YZH + (size_t)br * NROW * 512;
        unsigned short* yzl_b = hb + HOFF_YZL + (size_t)br * NROW * 512;
        transpose_yz_kernel<<<dim3(256 / 32, 4096 / 32), dim3(32, 8), 0, stream>>>(
            yT, yzh_b, yzl_b);

        gemm_mfma<0><<<dim3(512 / 64, NROW / 64), 256, 0, stream>>>(
            yzh_b, yzl_b, 512,
            hb + HOFF_OUTWH + (size_t)br * 262144,
            hb + HOFF_OUTWL + (size_t)br * 262144,
            out + (size_t)br * NROW * 512, 512, 512, 512);
    }
}

// Round 6
// 442.887 us; speedup vs baseline: 2.0924x; 1.1503x over previous
//
#include <hip/hip_runtime.h>
#include <math.h>

// ---------------- problem constants ----------------
constexpr int B_    = 2;
constexpr int L_    = 2048;
constexpr int NROW  = B_ * L_;     // 4096 rows per branch
constexpr int MROW  = 2 * NROW;    // 8192 merged rows (branch-major)
constexpr int HALF_ = 256;
constexpr int DS_   = 128;

constexpr float LOG2E = 1.4426950408889634f;

// ---------------- ws layout ----------------
// fp32 region (float element offsets)
constexpr size_t OFF_A1   = 0;                                    // 32768
constexpr size_t OFF_A2   = OFF_A1 + 32768;                       // 32768
constexpr size_t OFF_THR  = OFF_A2 + 32768;                       // 4
constexpr size_t OFF_PART = OFF_THR + 4;                          // 512
constexpr size_t OFF_XZ   = OFF_PART + 512;                       // 8192x512 (transient)
constexpr size_t OFF_DLT  = OFF_XZ;                               // alias: 8192x256 (after conv)
constexpr size_t OFF_YT   = OFF_XZ + (size_t)MROW * 256;          // alias: 2x256x4096 (after prep)
constexpr size_t OFF_XDBL = OFF_XZ + (size_t)MROW * 512;          // 8192x288
constexpr size_t OFF_XS   = OFF_XDBL + (size_t)MROW * 288;        // 8192x256
constexpr size_t OFF_BS   = OFF_XS  + (size_t)MROW * 256;         // 2 x 4096x128
constexpr size_t OFF_CS   = OFF_BS  + (size_t)2 * NROW * 128;     // 2 x 4096x128
constexpr size_t OFF_DTT  = OFF_CS  + (size_t)2 * NROW * 128;     // 2 x 256x4096
constexpr size_t OFF_DUT  = OFF_DTT + (size_t)2 * 256 * 4096;
constexpr size_t OFF_UDT  = OFF_DUT + (size_t)2 * 256 * 4096;
constexpr size_t FLOAT_END = OFF_UDT + (size_t)2 * 256 * 4096;

// bf16 region (ushort element offsets, based at ws + FLOAT_END floats)
constexpr size_t HOFF_XINH = 0;                                   // 8192x512
constexpr size_t HOFF_XINL = HOFF_XINH + (size_t)MROW * 512;
constexpr size_t HOFF_YZH  = HOFF_XINH;                           // alias (xin dead after in_proj)
constexpr size_t HOFF_YZL  = HOFF_XINL;
constexpr size_t HOFF_XSH  = HOFF_XINL + (size_t)MROW * 512;      // 8192x256
constexpr size_t HOFF_XSL  = HOFF_XSH  + (size_t)MROW * 256;
constexpr size_t HOFF_INWH = HOFF_XSL  + (size_t)MROW * 256;      // 2 x 512x512
constexpr size_t HOFF_INWL = HOFF_INWH + 524288;
constexpr size_t HOFF_XWH  = HOFF_INWL + 524288;                  // 2 x 288x256
constexpr size_t HOFF_XWL  = HOFF_XWH  + 147456;
constexpr size_t HOFF_OUTWH= HOFF_XWL  + 147456;                  // 2 x 512x512
constexpr size_t HOFF_OUTWL= HOFF_OUTWH+ 524288;

constexpr size_t WST_IN = 262144;   // per-branch in/out weight elems
constexpr size_t WST_X  = 73728;    // per-branch x_proj weight elems

// ---------------- types / helpers ----------------
typedef __bf16 bf16x8 __attribute__((ext_vector_type(8)));
typedef float  f32x4  __attribute__((ext_vector_type(4)));

__device__ __forceinline__ unsigned short bf16rn(float x) {
    unsigned u = __float_as_uint(x);
    unsigned r = (u + 0x7FFFu + ((u >> 16) & 1u)) >> 16;
    return (unsigned short)r;
}
__device__ __forceinline__ void split2(float x, unsigned short& h, unsigned short& l) {
    h = bf16rn(x);
    float hf = __uint_as_float(((unsigned)h) << 16);
    l = bf16rn(x - hf);
}

__device__ __forceinline__ float shrinkf(float v, float thr) {
    float a = fabsf(v) - thr;
    a = fmaxf(a, 0.0f);
    float r = copysignf(a, v);
    return (v == 0.0f) ? 0.0f : r;
}
__device__ __forceinline__ float siluf(float v) { return v / (1.0f + __expf(-v)); }
__device__ __forceinline__ float softplusf(float v) {
    return fmaxf(v, 0.0f) + log1pf(__expf(-fabsf(v)));
}
__device__ __forceinline__ float rlanef(float v, int l) {
    return __int_as_float(__builtin_amdgcn_readlane(__float_as_int(v), l));
}

__device__ __forceinline__ float blockMaxAll(float v, float* sbuf) {
    __syncthreads();
    #pragma unroll
    for (int off = 32; off > 0; off >>= 1) v = fmaxf(v, __shfl_xor(v, off));
    int w = threadIdx.x >> 6;
    if ((threadIdx.x & 63) == 0) sbuf[w] = v;
    __syncthreads();
    int nw = blockDim.x >> 6;
    float r = (threadIdx.x < nw) ? sbuf[threadIdx.x] : -INFINITY;
    #pragma unroll
    for (int off = 32; off > 0; off >>= 1) r = fmaxf(r, __shfl_xor(r, off));
    if (threadIdx.x == 0) sbuf[0] = r;
    __syncthreads();
    return sbuf[0];
}

// ---------------- A1/A2 precompute (one block) ----------------
__global__ __launch_bounds__(256) void computeA_kernel(const float* __restrict__ A_log,
                                                       const float* __restrict__ eps,
                                                       float* __restrict__ ws) {
    __shared__ float sbuf[8];
    float* A1 = ws + OFF_A1;
    float* A2 = ws + OFF_A2;
    const int N = HALF_ * DS_;
    float e = 1.0f + eps[0];
    float mx = -INFINITY;
    for (int i = threadIdx.x; i < N; i += 256) {
        float base = -e * __expf(A_log[i]);
        A1[i] = base;
        mx = fmaxf(mx, base);
    }
    float thr1 = 0.1f * blockMaxAll(mx, sbuf);
    float mx2 = -INFINITY;
    for (int i = threadIdx.x; i < N; i += 256) {
        float v = shrinkf(A1[i], thr1);
        A1[i] = v;
        mx2 = fmaxf(mx2, v);
    }
    float thr2 = 0.1f * blockMaxAll(mx2, sbuf);
    for (int i = threadIdx.x; i < N; i += 256) {
        A2[i] = shrinkf(A1[i], thr2);
    }
}

// ---------------- ALL weight splits in one dispatch ----------------
__global__ __launch_bounds__(256) void wsplit_all(const float* __restrict__ in_w0,
                                                  const float* __restrict__ in_w1,
                                                  const float* __restrict__ outw0,
                                                  const float* __restrict__ outw1,
                                                  const float* __restrict__ xw0,
                                                  const float* __restrict__ xw1,
                                                  unsigned short* __restrict__ hb) {
    int i = blockIdx.x * 256 + threadIdx.x;
    if (i >= 1196032) return;   // 4*262144 + 2*73728
    const float* src;
    size_t hbase, lbase;
    int off;
    if (i < 1048576) {
        int t = i >> 18;
        off = i & 262143;
        src = (t == 0) ? in_w0 : (t == 1) ? in_w1 : (t == 2) ? outw0 : outw1;
        if (t < 2) { hbase = HOFF_INWH + (size_t)t * WST_IN;  lbase = HOFF_INWL + (size_t)t * WST_IN; }
        else       { hbase = HOFF_OUTWH + (size_t)(t - 2) * WST_IN; lbase = HOFF_OUTWL + (size_t)(t - 2) * WST_IN; }
    } else {
        int j = i - 1048576;
        int t = (j < (int)WST_X) ? 0 : 1;
        off = j - t * (int)WST_X;
        src = t ? xw1 : xw0;
        hbase = HOFF_XWH + (size_t)t * WST_X;
        lbase = HOFF_XWL + (size_t)t * WST_X;
    }
    unsigned short h, l;
    split2(src[off], h, l);
    hb[hbase + off] = h;
    hb[lbase + off] = l;
}

// ---------------- input transpose + split (both branches, both b) ----------------
// grid (L/32, 512/32, 4): z = br*2 + b
__global__ __launch_bounds__(256) void transpose_in_kernel(const float* __restrict__ inp,
                                                           unsigned short* __restrict__ xh,
                                                           unsigned short* __restrict__ xl) {
    __shared__ float tile[32][33];
    int z  = blockIdx.z;
    int br = z >> 1;
    int b  = z & 1;
    int t0 = blockIdx.x * 32;
    int m0 = blockIdx.y * 32;
    int tx = threadIdx.x;
    int ty = threadIdx.y;
    #pragma unroll
    for (int k = 0; k < 4; k++) {
        tile[ty + 8 * k][tx] =
            inp[((size_t)b * 1024 + br * 512 + m0 + ty + 8 * k) * L_ + t0 + tx];
    }
    __syncthreads();
    #pragma unroll
    for (int k = 0; k < 4; k++) {
        size_t dst = ((size_t)br * NROW + (size_t)b * L_ + t0 + ty + 8 * k) * 512 + m0 + tx;
        unsigned short h, l;
        split2(tile[tx][ty + 8 * k], h, l);
        xh[dst] = h; xl[dst] = l;
    }
}

// ---------------- MFMA GEMM (bf16x3): C[M,N] = A * W_br^T, merged M=8192 ----------------
// 128x64 tile, BK=32, 256 thr (4 waves x 32 rows). Per-branch weight select.
template <int NGUARD>
__global__ __launch_bounds__(256) void gemm_mfma(const unsigned short* __restrict__ Ah,
                                                 const unsigned short* __restrict__ Al, int lda,
                                                 const unsigned short* __restrict__ WhB,
                                                 const unsigned short* __restrict__ WlB,
                                                 size_t wstride,
                                                 float* __restrict__ C, int ldc,
                                                 int N, int K) {
    __shared__ __align__(16) unsigned short sAh[128 * 40];
    __shared__ __align__(16) unsigned short sAl[128 * 40];
    __shared__ __align__(16) unsigned short sBh[64 * 40];
    __shared__ __align__(16) unsigned short sBl[64 * 40];
    int tid  = threadIdx.x;
    int wid  = tid >> 6;
    int lane = tid & 63;
    int fr   = lane & 15;
    int kg   = lane >> 4;
    int mblk = blockIdx.y * 128;
    int nblk = blockIdx.x * 64;
    int br   = (mblk >= NROW) ? 1 : 0;
    const unsigned short* Wh = WhB + (size_t)br * wstride;
    const unsigned short* Wl = WlB + (size_t)br * wstride;
    int srow = tid >> 2;            // 0..63
    int skp  = (tid & 3) * 8;       // k-chunk of 8

    f32x4 acc[2][4] = {};

    for (int k0 = 0; k0 < K; k0 += 32) {
        uint4 vah0 = *(const uint4*)(Ah + (size_t)(mblk + srow) * lda + k0 + skp);
        uint4 vah1 = *(const uint4*)(Ah + (size_t)(mblk + 64 + srow) * lda + k0 + skp);
        uint4 val0 = *(const uint4*)(Al + (size_t)(mblk + srow) * lda + k0 + skp);
        uint4 val1 = *(const uint4*)(Al + (size_t)(mblk + 64 + srow) * lda + k0 + skp);
        uint4 vbh = {0, 0, 0, 0}, vbl = {0, 0, 0, 0};
        if (!NGUARD || (nblk + srow) < N) {
            vbh = *(const uint4*)(Wh + (size_t)(nblk + srow) * K + k0 + skp);
            vbl = *(const uint4*)(Wl + (size_t)(nblk + srow) * K + k0 + skp);
        }
        __syncthreads();   // WAR vs previous iter's ds_reads
        *(uint4*)(sAh + srow * 40 + skp) = vah0;
        *(uint4*)(sAh + (64 + srow) * 40 + skp) = vah1;
        *(uint4*)(sAl + srow * 40 + skp) = val0;
        *(uint4*)(sAl + (64 + srow) * 40 + skp) = val1;
        *(uint4*)(sBh + srow * 40 + skp) = vbh;
        *(uint4*)(sBl + srow * 40 + skp) = vbl;
        __syncthreads();

        bf16x8 ah0 = *(const bf16x8*)(sAh + (wid * 32 + fr) * 40 + kg * 8);
        bf16x8 ah1 = *(const bf16x8*)(sAh + (wid * 32 + 16 + fr) * 40 + kg * 8);
        bf16x8 al0 = *(const bf16x8*)(sAl + (wid * 32 + fr) * 40 + kg * 8);
        bf16x8 al1 = *(const bf16x8*)(sAl + (wid * 32 + 16 + fr) * 40 + kg * 8);
        #pragma unroll
        for (int nt = 0; nt < 4; nt++) {
            bf16x8 bh = *(const bf16x8*)(sBh + (nt * 16 + fr) * 40 + kg * 8);
            bf16x8 bl = *(const bf16x8*)(sBl + (nt * 16 + fr) * 40 + kg * 8);
            acc[0][nt] = __builtin_amdgcn_mfma_f32_16x16x32_bf16(ah0, bh, acc[0][nt], 0, 0, 0);
            acc[0][nt] = __builtin_amdgcn_mfma_f32_16x16x32_bf16(ah0, bl, acc[0][nt], 0, 0, 0);
            acc[0][nt] = __builtin_amdgcn_mfma_f32_16x16x32_bf16(al0, bh, acc[0][nt], 0, 0, 0);
            acc[1][nt] = __builtin_amdgcn_mfma_f32_16x16x32_bf16(ah1, bh, acc[1][nt], 0, 0, 0);
            acc[1][nt] = __builtin_amdgcn_mfma_f32_16x16x32_bf16(ah1, bl, acc[1][nt], 0, 0, 0);
            acc[1][nt] = __builtin_amdgcn_mfma_f32_16x16x32_bf16(al1, bh, acc[1][nt], 0, 0, 0);
        }
    }
    // C/D layout: col = lane&15, row = (lane>>4)*4 + reg
    #pragma unroll
    for (int mt = 0; mt < 2; mt++) {
        #pragma unroll
        for (int nt = 0; nt < 4; nt++) {
            int col = nblk + nt * 16 + fr;
            if (NGUARD && col >= N) continue;
            #pragma unroll
            for (int r = 0; r < 4; r++) {
                int row = mblk + wid * 32 + mt * 16 + kg * 4 + r;
                C[(size_t)row * ldc + col] = acc[mt][nt][r];
            }
        }
    }
}

// ---------------- depthwise conv (k=4) + SiLU, merged branches ----------------
__global__ __launch_bounds__(256) void conv_silu_kernel(const float* __restrict__ xz,
                                                        float* __restrict__ xs,
                                                        unsigned short* __restrict__ xsh,
                                                        unsigned short* __restrict__ xsl,
                                                        unsigned short* __restrict__ yzh,
                                                        unsigned short* __restrict__ yzl,
                                                        const float* __restrict__ wx0,
                                                        const float* __restrict__ wx1,
                                                        const float* __restrict__ wz0,
                                                        const float* __restrict__ wz1) {
    int idx = blockIdx.x * 256 + threadIdx.x;   // over MROW*256
    int c   = idx & 255;
    int row = idx >> 8;          // global row 0..8191
    int br  = row >> 12;
    int t   = row & (L_ - 1);
    const float* wx = br ? wx1 : wx0;
    const float* wz = br ? wz1 : wz0;
    float ax = 0.0f, az = 0.0f;
    #pragma unroll
    for (int j = 0; j < 4; j++) {
        int tt = t + j - 1;
        if (tt >= 0 && tt < L_) {
            const float* p = xz + (size_t)(row + j - 1) * 512;
            ax = fmaf(p[c], wx[c * 4 + j], ax);
            az = fmaf(p[c + 256], wz[c * 4 + j], az);
        }
    }
    float sx = siluf(ax);
    float sz = siluf(az);
    xs[(size_t)row * 256 + c] = sx;
    unsigned short h, l;
    split2(sx, h, l);
    xsh[(size_t)row * 256 + c] = h;
    xsl[(size_t)row * 256 + c] = l;
    split2(sz, h, l);
    yzh[(size_t)row * 512 + 256 + c] = h;
    yzl[(size_t)row * 512 + 256 + c] = l;
}

// ---------------- vector fp32 GEMM for dt_proj (K=32), merged branches ----------------
__global__ __launch_bounds__(256) void gemm_dt(const float* __restrict__ A, int lda,
                                               const float* __restrict__ W0,
                                               const float* __restrict__ W1,
                                               const float* __restrict__ b0,
                                               const float* __restrict__ b1,
                                               float* __restrict__ C, int ldc,
                                               int N, int K) {
    __shared__ float As[16][68];
    __shared__ float Ws[16][68];
    int tid = threadIdx.x;
    int kk = tid & 15;
    int rr = tid >> 4;
    int mblk = blockIdx.y * 64;
    int nblk = blockIdx.x * 64;
    const float* W    = (mblk >= NROW) ? W1 : W0;
    const float* bias = (mblk >= NROW) ? b1 : b0;
    float acc[4][4] = {};
    for (int k0 = 0; k0 < K; k0 += 16) {
        #pragma unroll
        for (int j = 0; j < 4; j++) {
            As[kk][rr + 16 * j] = A[(size_t)(mblk + rr + 16 * j) * lda + k0 + kk];
        }
        #pragma unroll
        for (int j = 0; j < 4; j++) {
            int n = nblk + rr + 16 * j;
            Ws[kk][rr + 16 * j] = (n < N) ? W[(size_t)n * K + k0 + kk] : 0.0f;
        }
        __syncthreads();
        int ty = tid >> 4;
        int tx = tid & 15;
        #pragma unroll
        for (int kq = 0; kq < 16; kq++) {
            float a0 = As[kq][ty * 4 + 0];
            float a1 = As[kq][ty * 4 + 1];
            float a2 = As[kq][ty * 4 + 2];
            float a3 = As[kq][ty * 4 + 3];
            float v0 = Ws[kq][tx * 4 + 0];
            float v1 = Ws[kq][tx * 4 + 1];
            float v2 = Ws[kq][tx * 4 + 2];
            float v3 = Ws[kq][tx * 4 + 3];
            acc[0][0] = fmaf(a0, v0, acc[0][0]); acc[0][1] = fmaf(a0, v1, acc[0][1]);
            acc[0][2] = fmaf(a0, v2, acc[0][2]); acc[0][3] = fmaf(a0, v3, acc[0][3]);
            acc[1][0] = fmaf(a1, v0, acc[1][0]); acc[1][1] = fmaf(a1, v1, acc[1][1]);
            acc[1][2] = fmaf(a1, v2, acc[1][2]); acc[1][3] = fmaf(a1, v3, acc[1][3]);
            acc[2][0] = fmaf(a2, v0, acc[2][0]); acc[2][1] = fmaf(a2, v1, acc[2][1]);
            acc[2][2] = fmaf(a2, v2, acc[2][2]); acc[2][3] = fmaf(a2, v3, acc[2][3]);
            acc[3][0] = fmaf(a3, v0, acc[3][0]); acc[3][1] = fmaf(a3, v1, acc[3][1]);
            acc[3][2] = fmaf(a3, v2, acc[3][2]); acc[3][3] = fmaf(a3, v3, acc[3][3]);
        }
        __syncthreads();
    }
    int ty = tid >> 4;
    int tx = tid & 15;
    #pragma unroll
    for (int i = 0; i < 4; i++) {
        int m = mblk + ty * 4 + i;
        #pragma unroll
        for (int j = 0; j < 4; j++) {
            int n = nblk + tx * 4 + j;
            if (n < N) {
                C[(size_t)m * ldc + n] = softplusf(acc[i][j] + bias[n]);
            }
        }
    }
}

// ---------------- fused scan-input prep, merged branches ----------------
// grid (4096/32, 256/32, 2)
__global__ __launch_bounds__(256) void prep_kernel(const float* __restrict__ dl,
                                                   const float* __restrict__ xs,
                                                   const float* __restrict__ Dvec,
                                                   float* __restrict__ dtT,
                                                   float* __restrict__ duT,
                                                   float* __restrict__ udT) {
    __shared__ float tD[32][33];
    __shared__ float tU[32][33];
    int br = blockIdx.z;
    int m0 = blockIdx.x * 32;   // within-branch row (b*L + t)
    int n0 = blockIdx.y * 32;   // d cols
    int tx = threadIdx.x;
    int ty = threadIdx.y;
    #pragma unroll
    for (int k = 0; k < 4; k++) {
        size_t src = ((size_t)br * NROW + m0 + ty + 8 * k) * 256 + n0 + tx;
        tD[ty + 8 * k][tx] = dl[src];
        tU[ty + 8 * k][tx] = xs[src];
    }
    __syncthreads();
    #pragma unroll
    for (int k = 0; k < 4; k++) {
        int d = n0 + ty + 8 * k;
        size_t dst = ((size_t)br * 256 + d) * 4096 + m0 + tx;
        float dv = tD[tx][ty + 8 * k];
        float uv = tU[tx][ty + 8 * k];
        dtT[dst] = dv * LOG2E;
        duT[dst] = dv * uv;
        udT[dst] = uv * Dvec[d];
    }
}

// ---------------- global signed-max over Bc/Cc, merged: grid (128, 2) ----------------
__global__ __launch_bounds__(256) void redmax_kernel(const float* __restrict__ xdbl,
                                                     float* __restrict__ part) {
    __shared__ float sbuf[8];
    int br = blockIdx.y;
    const float* xd = xdbl + (size_t)br * NROW * 288;
    float mb = -INFINITY, mc = -INFINITY;
    const size_t total = (size_t)NROW * 128;
    for (size_t i = (size_t)blockIdx.x * 256 + threadIdx.x; i < total;
         i += (size_t)gridDim.x * 256) {
        size_t row = i >> 7;
        int n = (int)(i & 127);
        const float* p = xd + row * 288;
        mb = fmaxf(mb, p[32 + n]);
        mc = fmaxf(mc, p[160 + n]);
    }
    mb = blockMaxAll(mb, sbuf);
    mc = blockMaxAll(mc, sbuf);
    if (threadIdx.x == 0) {
        part[br * 128 + blockIdx.x] = mb;
        part[256 + br * 128 + blockIdx.x] = mc;
    }
}

// one block, 128 threads: wave w handles branch w
__global__ __launch_bounds__(128) void finmax_kernel(const float* __restrict__ part,
                                                     float* __restrict__ thr) {
    int tid = threadIdx.x;
    int br = tid >> 6;
    int l = tid & 63;
    float vb = fmaxf(part[br * 128 + l], part[br * 128 + 64 + l]);
    float vc = fmaxf(part[256 + br * 128 + l], part[256 + br * 128 + 64 + l]);
    #pragma unroll
    for (int off = 32; off > 0; off >>= 1) {
        vb = fmaxf(vb, __shfl_xor(vb, off));
        vc = fmaxf(vc, __shfl_xor(vc, off));
    }
    if (l == 0) {
        thr[2 * br]     = 0.1f * vb;
        thr[2 * br + 1] = 0.1f * vc;
    }
}

// ---------------- shrink + pack Bc/Cc, merged ----------------
__global__ __launch_bounds__(256) void shrinkpack_kernel(const float* __restrict__ xdbl,
                                                         const float* __restrict__ thr,
                                                         float* __restrict__ Bs,
                                                         float* __restrict__ Cs) {
    int idx = blockIdx.x * 256 + threadIdx.x;   // over MROW*128
    int row = idx >> 7;          // global row 0..8191
    int br  = row >> 12;
    int n = idx & 127;
    float tB = thr[2 * br], tC = thr[2 * br + 1];
    const float* p = xdbl + (size_t)row * 288;
    Bs[idx] = shrinkf(p[32 + n], tB);
    Cs[idx] = shrinkf(p[160 + n], tC);
}

// ---------------- selective scan (v3 structure) ----------------
__global__ __launch_bounds__(128) void scan3_kernel(float* __restrict__ ws) {
    int blk  = blockIdx.x;
    int xcd  = blk & 7;
    int slot = blk >> 3;
    int combo = xcd >> 1;
    int d  = (xcd & 1) * 128 + slot;
    int br = combo >> 1;
    int b  = combo & 1;
    int tid = threadIdx.x;
    int lt  = tid & 63;

    const float* A   = ws + (br ? OFF_A2 : OFF_A1);
    size_t dchain = ((size_t)br * 256 + d) * 4096 + (size_t)b * L_;
    const float* dtT = ws + OFF_DTT + dchain;
    const float* duT = ws + OFF_DUT + dchain;
    const float* udT = ws + OFF_UDT + dchain;
    const float* Bp  = ws + OFF_BS + ((size_t)br * NROW + (size_t)b * L_) * 128 + tid;
    const float* Cp  = ws + OFF_CS + ((size_t)br * NROW + (size_t)b * L_) * 128 + tid;
    float*       yTp = ws + OFF_YT + dchain;

    __shared__ float red[64 * 132];
    __shared__ float comb[64];

    float a = A[d * 128 + tid];
    float h = 0.0f;

    float Bb[2][8], Cb[2][8];
    float dt_c = dtT[lt];
    float du_c = duT[lt];
    float ud_c = udT[lt];
    float dt_n = 0.f, du_n = 0.f, ud_n = 0.f;
    #pragma unroll
    for (int j = 0; j < 8; j++) { Bb[0][j] = Bp[(size_t)j * 128];       Cb[0][j] = Cp[(size_t)j * 128]; }
    #pragma unroll
    for (int j = 0; j < 8; j++) { Bb[1][j] = Bp[(size_t)(8 + j) * 128]; Cb[1][j] = Cp[(size_t)(8 + j) * 128]; }

    for (int c = 0; c < 32; c++) {
        if (c < 31) {
            dt_n = dtT[(c + 1) * 64 + lt];
            du_n = duT[(c + 1) * 64 + lt];
            ud_n = udT[(c + 1) * 64 + lt];
        }
        #pragma unroll
        for (int m = 0; m < 8; m++) {
            const int cur = m & 1;
            #pragma unroll
            for (int j = 0; j < 8; j++) {
                const int tl = m * 8 + j;
                float dt2 = rlanef(dt_c, tl);
                float du  = rlanef(du_c, tl);
                float e = __builtin_amdgcn_exp2f(dt2 * a);
                h = fmaf(e, h, du * Bb[cur][j]);
                red[tl * 132 + tid] = h * Cb[cur][j];
            }
            int nb = c * 8 + m + 2;
            if (nb < 256) {
                #pragma unroll
                for (int j = 0; j < 8; j++) {
                    Bb[cur][j] = Bp[((size_t)nb * 8 + j) * 128];
                    Cb[cur][j] = Cp[((size_t)nb * 8 + j) * 128];
                }
            }
        }
        __syncthreads();
        {
            const float* rp = &red[(tid & 63) * 132 + (tid >> 6) * 64];
            float s0 = 0.f, s1 = 0.f, s2 = 0.f, s3 = 0.f;
            #pragma unroll
            for (int i = 0; i < 64; i += 4) {
                float4 v = *(const float4*)(rp + i);
                s0 += v.x; s1 += v.y; s2 += v.z; s3 += v.w;
            }
            float part = (s0 + s1) + (s2 + s3);
            if (tid >= 64) comb[tid - 64] = part;
            __syncthreads();
            if (tid < 64) yTp[c * 64 + tid] = part + comb[tid] + ud_c;
        }
        __syncthreads();
        dt_c = dt_n;
        du_c = du_n;
        ud_c = ud_n;
    }
}

// ---------------- yT -> yz bf16 split (y half), merged: grid (8, 128, 2) ----------------
__global__ __launch_bounds__(256) void transpose_yz_kernel(const float* __restrict__ yT,
                                                           unsigned short* __restrict__ yzh,
                                                           unsigned short* __restrict__ yzl) {
    __shared__ float tile[32][33];
    int br = blockIdx.z;
    int m0 = blockIdx.x * 32;   // d rows
    int n0 = blockIdx.y * 32;   // within-branch t cols
    int tx = threadIdx.x;
    int ty = threadIdx.y;
    #pragma unroll
    for (int k = 0; k < 4; k++) {
        tile[ty + 8 * k][tx] = yT[((size_t)br * 256 + m0 + ty + 8 * k) * 4096 + n0 + tx];
    }
    __syncthreads();
    #pragma unroll
    for (int k = 0; k < 4; k++) {
        size_t dst = ((size_t)br * NROW + n0 + ty + 8 * k) * 512 + m0 + tx;
        unsigned short h, l;
        split2(tile[tx][ty + 8 * k], h, l);
        yzh[dst] = h; yzl[dst] = l;
    }
}

// ---------------- host-side launch ----------------
extern "C" void kernel_launch(void* const* d_in, const int* in_sizes, int n_in,
                              void* d_out, int out_size, void* d_ws, size_t ws_size,
                              hipStream_t stream) {
    const float* inp   = (const float*)d_in[0];
    const float* in_w[2]  = {(const float*)d_in[1],  (const float*)d_in[8]};
    const float* cxw[2]   = {(const float*)d_in[2],  (const float*)d_in[9]};
    const float* czw[2]   = {(const float*)d_in[3],  (const float*)d_in[10]};
    const float* xw[2]    = {(const float*)d_in[4],  (const float*)d_in[11]};
    const float* dtw[2]   = {(const float*)d_in[5],  (const float*)d_in[12]};
    const float* dtb[2]   = {(const float*)d_in[6],  (const float*)d_in[13]};
    const float* outw[2]  = {(const float*)d_in[7],  (const float*)d_in[14]};
    const float* A_log = (const float*)d_in[15];
    const float* Dvec  = (const float*)d_in[16];
    const float* eps   = (const float*)d_in[17];
    float* out = (float*)d_out;
    float* ws  = (float*)d_ws;
    unsigned short* hb = (unsigned short*)(ws + FLOAT_END);

    computeA_kernel<<<1, 256, 0, stream>>>(A_log, eps, ws);

    wsplit_all<<<(1196032 + 255) / 256, 256, 0, stream>>>(
        in_w[0], in_w[1], outw[0], outw[1], xw[0], xw[1], hb);

    transpose_in_kernel<<<dim3(L_ / 32, 512 / 32, 4), dim3(32, 8), 0, stream>>>(
        inp, hb + HOFF_XINH, hb + HOFF_XINL);

    // in_proj (merged M=8192): xz = xin * in_w^T
    gemm_mfma<0><<<dim3(512 / 64, MROW / 128), 256, 0, stream>>>(
        hb + HOFF_XINH, hb + HOFF_XINL, 512,
        hb + HOFF_INWH, hb + HOFF_INWL, WST_IN,
        ws + OFF_XZ, 512, 512, 512);

    conv_silu_kernel<<<(MROW * HALF_) / 256, 256, 0, stream>>>(
        ws + OFF_XZ, ws + OFF_XS, hb + HOFF_XSH, hb + HOFF_XSL,
        hb + HOFF_YZH, hb + HOFF_YZL, cxw[0], cxw[1], czw[0], czw[1]);

    // x_proj (merged): xdbl = xs * xw^T
    gemm_mfma<1><<<dim3((288 + 63) / 64, MROW / 128), 256, 0, stream>>>(
        hb + HOFF_XSH, hb + HOFF_XSL, 256,
        hb + HOFF_XWH, hb + HOFF_XWL, WST_X,
        ws + OFF_XDBL, 288, 288, 256);

    // dt_proj (merged, vector fp32, K=32) + softplus
    gemm_dt<<<dim3(256 / 64, MROW / 64), 256, 0, stream>>>(
        ws + OFF_XDBL, 288, dtw[0], dtw[1], dtb[0], dtb[1],
        ws + OFF_DLT, 256, 256, 32);

    prep_kernel<<<dim3(NROW / 32, 256 / 32, 2), dim3(32, 8), 0, stream>>>(
        ws + OFF_DLT, ws + OFF_XS, Dvec,
        ws + OFF_DTT, ws + OFF_DUT, ws + OFF_UDT);

    redmax_kernel<<<dim3(128, 2), 256, 0, stream>>>(ws + OFF_XDBL, ws + OFF_PART);
    finmax_kernel<<<1, 128, 0, stream>>>(ws + OFF_PART, ws + OFF_THR);

    shrinkpack_kernel<<<(MROW * 128) / 256, 256, 0, stream>>>(
        ws + OFF_XDBL, ws + OFF_THR, ws + OFF_BS, ws + OFF_CS);

    scan3_kernel<<<dim3(1024), 128, 0, stream>>>(ws);

    transpose_yz_kernel<<<dim3(256 / 32, NROW / 32, 2), dim3(32, 8), 0, stream>>>(
        ws + OFF_YT, hb + HOFF_YZH, hb + HOFF_YZL);

    // out_proj (merged): d_out = yz * out_w^T  (out1 || out2 is exactly M=8192 row-major)
    gemm_mfma<0><<<dim3(512 / 64, MROW / 128), 256, 0, stream>>>(
        hb + HOFF_YZH, hb + HOFF_YZL, 512,
        hb + HOFF_OUTWH, hb + HOFF_OUTWL, WST_IN,
        out, 512, 512, 512);
}

// Round 7
// 350.702 us; speedup vs baseline: 2.6424x; 1.2629x over previous
//
#include <hip/hip_runtime.h>
#include <math.h>

// ---------------- problem constants ----------------
constexpr int B_    = 2;
constexpr int L_    = 2048;
constexpr int NROW  = B_ * L_;     // 4096 rows per branch
constexpr int MROW  = 2 * NROW;    // 8192 merged rows (branch-major)
constexpr int HALF_ = 256;
constexpr int DS_   = 128;

constexpr float LOG2E = 1.4426950408889634f;

// ---------------- ws layout ----------------
// fp32 region (float element offsets)
constexpr size_t OFF_MINP = 0;                                    // 32 (minA partials)
constexpr size_t OFF_BCMX = 32;                                   // 4 (uint atomics: brB,brC x2)
constexpr size_t OFF_XZ   = 64;                                   // 8192x512 (transient)
constexpr size_t OFF_YT   = OFF_XZ + (size_t)MROW * 256;          // alias: 2x256x4096 (after conv)
constexpr size_t OFF_XDBL = OFF_XZ + (size_t)MROW * 512;          // 8192x288
constexpr size_t OFF_XS   = OFF_XDBL + (size_t)MROW * 288;        // 8192x256
constexpr size_t OFF_BS   = OFF_XS  + (size_t)MROW * 256;         // 2 x 4096x128
constexpr size_t OFF_CS   = OFF_BS  + (size_t)2 * NROW * 128;     // 2 x 4096x128
constexpr size_t OFF_DTT  = OFF_CS  + (size_t)2 * NROW * 128;     // 2 x 256x4096
constexpr size_t OFF_DUT  = OFF_DTT + (size_t)2 * 256 * 4096;
constexpr size_t OFF_UDT  = OFF_DUT + (size_t)2 * 256 * 4096;
constexpr size_t FLOAT_END = OFF_UDT + (size_t)2 * 256 * 4096;

// bf16 region (ushort element offsets, based at ws + FLOAT_END floats)
constexpr size_t HOFF_XINH = 0;                                   // 8192x512
constexpr size_t HOFF_XINL = HOFF_XINH + (size_t)MROW * 512;
constexpr size_t HOFF_YZH  = HOFF_XINH;                           // alias (xin dead after in_proj)
constexpr size_t HOFF_YZL  = HOFF_XINL;
constexpr size_t HOFF_XSH  = HOFF_XINL + (size_t)MROW * 512;      // 8192x256
constexpr size_t HOFF_XSL  = HOFF_XSH  + (size_t)MROW * 256;
constexpr size_t HOFF_INWH = HOFF_XSL  + (size_t)MROW * 256;      // 2 x 512x512
constexpr size_t HOFF_INWL = HOFF_INWH + 524288;
constexpr size_t HOFF_XWH  = HOFF_INWL + 524288;                  // 2 x 288x256
constexpr size_t HOFF_XWL  = HOFF_XWH  + 147456;
constexpr size_t HOFF_OUTWH= HOFF_XWL  + 147456;                  // 2 x 512x512
constexpr size_t HOFF_OUTWL= HOFF_OUTWH+ 524288;

constexpr size_t WST_IN = 262144;   // per-branch in/out weight elems
constexpr size_t WST_X  = 73728;    // per-branch x_proj weight elems

// ---------------- types / helpers ----------------
typedef __bf16 bf16x8 __attribute__((ext_vector_type(8)));
typedef float  f32x4  __attribute__((ext_vector_type(4)));

__device__ __forceinline__ unsigned short bf16rn(float x) {
    unsigned u = __float_as_uint(x);
    unsigned r = (u + 0x7FFFu + ((u >> 16) & 1u)) >> 16;
    return (unsigned short)r;
}
__device__ __forceinline__ void split2(float x, unsigned short& h, unsigned short& l) {
    h = bf16rn(x);
    float hf = __uint_as_float(((unsigned)h) << 16);
    l = bf16rn(x - hf);
}

__device__ __forceinline__ float shrinkf(float v, float thr) {
    float a = fabsf(v) - thr;
    a = fmaxf(a, 0.0f);
    float r = copysignf(a, v);
    return (v == 0.0f) ? 0.0f : r;
}
__device__ __forceinline__ float siluf(float v) { return v / (1.0f + __expf(-v)); }
__device__ __forceinline__ float softplusf(float v) {
    return fmaxf(v, 0.0f) + log1pf(__expf(-fabsf(v)));
}
__device__ __forceinline__ float rlanef(float v, int l) {
    return __int_as_float(__builtin_amdgcn_readlane(__float_as_int(v), l));
}
// monotone float<->uint key for atomicMax on signed floats
__device__ __forceinline__ unsigned fkey(float f) {
    unsigned u = __float_as_uint(f);
    return (u >> 31) ? ~u : (u | 0x80000000u);
}
__device__ __forceinline__ float funkey(unsigned k) {
    unsigned u = (k >> 31) ? (k & 0x7FFFFFFFu) : ~k;
    return __uint_as_float(u);
}

// ---------------- minA: block-min of A_log + atomic-slot init ----------------
// grid 32 x 256 thr x 4 elems = 32768
__global__ __launch_bounds__(256) void minA_kernel(const float* __restrict__ A_log,
                                                   float* __restrict__ ws,
                                                   unsigned* __restrict__ bcmax) {
    __shared__ float sbuf[8];
    int i = blockIdx.x * 1024 + threadIdx.x * 4;
    float4 v = *(const float4*)(A_log + i);
    float mv = fminf(fminf(v.x, v.y), fminf(v.z, v.w));
    #pragma unroll
    for (int off = 32; off > 0; off >>= 1) mv = fminf(mv, __shfl_xor(mv, off));
    if ((threadIdx.x & 63) == 0) sbuf[threadIdx.x >> 6] = mv;
    __syncthreads();
    if (threadIdx.x == 0) {
        float r = fminf(fminf(sbuf[0], sbuf[1]), fminf(sbuf[2], sbuf[3]));
        ws[OFF_MINP + blockIdx.x] = r;
    }
    if (blockIdx.x == 0 && threadIdx.x < 4) bcmax[threadIdx.x] = 0u;
}

// ---------------- ALL weight splits in one dispatch ----------------
__global__ __launch_bounds__(256) void wsplit_all(const float* __restrict__ in_w0,
                                                  const float* __restrict__ in_w1,
                                                  const float* __restrict__ outw0,
                                                  const float* __restrict__ outw1,
                                                  const float* __restrict__ xw0,
                                                  const float* __restrict__ xw1,
                                                  unsigned short* __restrict__ hb) {
    int i = blockIdx.x * 256 + threadIdx.x;
    if (i >= 1196032) return;   // 4*262144 + 2*73728
    const float* src;
    size_t hbase, lbase;
    int off;
    if (i < 1048576) {
        int t = i >> 18;
        off = i & 262143;
        src = (t == 0) ? in_w0 : (t == 1) ? in_w1 : (t == 2) ? outw0 : outw1;
        if (t < 2) { hbase = HOFF_INWH + (size_t)t * WST_IN;  lbase = HOFF_INWL + (size_t)t * WST_IN; }
        else       { hbase = HOFF_OUTWH + (size_t)(t - 2) * WST_IN; lbase = HOFF_OUTWL + (size_t)(t - 2) * WST_IN; }
    } else {
        int j = i - 1048576;
        int t = (j < (int)WST_X) ? 0 : 1;
        off = j - t * (int)WST_X;
        src = t ? xw1 : xw0;
        hbase = HOFF_XWH + (size_t)t * WST_X;
        lbase = HOFF_XWL + (size_t)t * WST_X;
    }
    unsigned short h, l;
    split2(src[off], h, l);
    hb[hbase + off] = h;
    hb[lbase + off] = l;
}

// ---------------- input transpose + split (both branches, both b) ----------------
__global__ __launch_bounds__(256) void transpose_in_kernel(const float* __restrict__ inp,
                                                           unsigned short* __restrict__ xh,
                                                           unsigned short* __restrict__ xl) {
    __shared__ float tile[32][33];
    int z  = blockIdx.z;
    int br = z >> 1;
    int b  = z & 1;
    int t0 = blockIdx.x * 32;
    int m0 = blockIdx.y * 32;
    int tx = threadIdx.x;
    int ty = threadIdx.y;
    #pragma unroll
    for (int k = 0; k < 4; k++) {
        tile[ty + 8 * k][tx] =
            inp[((size_t)b * 1024 + br * 512 + m0 + ty + 8 * k) * L_ + t0 + tx];
    }
    __syncthreads();
    #pragma unroll
    for (int k = 0; k < 4; k++) {
        size_t dst = ((size_t)br * NROW + (size_t)b * L_ + t0 + ty + 8 * k) * 512 + m0 + tx;
        unsigned short h, l;
        split2(tile[tx][ty + 8 * k], h, l);
        xh[dst] = h; xl[dst] = l;
    }
}

// ---------------- MFMA GEMM (bf16x3): C[M,N] = A * W_br^T, merged M=8192 ----------------
// 128x64 tile, BK=32, 256 thr. DOMAX: fused signed-max of B/C col-ranges via atomicMax.
template <int NGUARD, int DOMAX>
__global__ __launch_bounds__(256) void gemm_mfma(const unsigned short* __restrict__ Ah,
                                                 const unsigned short* __restrict__ Al, int lda,
                                                 const unsigned short* __restrict__ WhB,
                                                 const unsigned short* __restrict__ WlB,
                                                 size_t wstride,
                                                 float* __restrict__ C, int ldc,
                                                 int N, int K,
                                                 unsigned* __restrict__ bcmax) {
    __shared__ __align__(16) unsigned short sAh[128 * 40];
    __shared__ __align__(16) unsigned short sAl[128 * 40];
    __shared__ __align__(16) unsigned short sBh[64 * 40];
    __shared__ __align__(16) unsigned short sBl[64 * 40];
    int tid  = threadIdx.x;
    int wid  = tid >> 6;
    int lane = tid & 63;
    int fr   = lane & 15;
    int kg   = lane >> 4;
    int mblk = blockIdx.y * 128;
    int nblk = blockIdx.x * 64;
    int br   = (mblk >= NROW) ? 1 : 0;
    const unsigned short* Wh = WhB + (size_t)br * wstride;
    const unsigned short* Wl = WlB + (size_t)br * wstride;
    int srow = tid >> 2;            // 0..63
    int skp  = (tid & 3) * 8;       // k-chunk of 8

    f32x4 acc[2][4] = {};

    for (int k0 = 0; k0 < K; k0 += 32) {
        uint4 vah0 = *(const uint4*)(Ah + (size_t)(mblk + srow) * lda + k0 + skp);
        uint4 vah1 = *(const uint4*)(Ah + (size_t)(mblk + 64 + srow) * lda + k0 + skp);
        uint4 val0 = *(const uint4*)(Al + (size_t)(mblk + srow) * lda + k0 + skp);
        uint4 val1 = *(const uint4*)(Al + (size_t)(mblk + 64 + srow) * lda + k0 + skp);
        uint4 vbh = {0, 0, 0, 0}, vbl = {0, 0, 0, 0};
        if (!NGUARD || (nblk + srow) < N) {
            vbh = *(const uint4*)(Wh + (size_t)(nblk + srow) * K + k0 + skp);
            vbl = *(const uint4*)(Wl + (size_t)(nblk + srow) * K + k0 + skp);
        }
        __syncthreads();   // WAR vs previous iter's ds_reads
        *(uint4*)(sAh + srow * 40 + skp) = vah0;
        *(uint4*)(sAh + (64 + srow) * 40 + skp) = vah1;
        *(uint4*)(sAl + srow * 40 + skp) = val0;
        *(uint4*)(sAl + (64 + srow) * 40 + skp) = val1;
        *(uint4*)(sBh + srow * 40 + skp) = vbh;
        *(uint4*)(sBl + srow * 40 + skp) = vbl;
        __syncthreads();

        bf16x8 ah0 = *(const bf16x8*)(sAh + (wid * 32 + fr) * 40 + kg * 8);
        bf16x8 ah1 = *(const bf16x8*)(sAh + (wid * 32 + 16 + fr) * 40 + kg * 8);
        bf16x8 al0 = *(const bf16x8*)(sAl + (wid * 32 + fr) * 40 + kg * 8);
        bf16x8 al1 = *(const bf16x8*)(sAl + (wid * 32 + 16 + fr) * 40 + kg * 8);
        #pragma unroll
        for (int nt = 0; nt < 4; nt++) {
            bf16x8 bh = *(const bf16x8*)(sBh + (nt * 16 + fr) * 40 + kg * 8);
            bf16x8 bl = *(const bf16x8*)(sBl + (nt * 16 + fr) * 40 + kg * 8);
            acc[0][nt] = __builtin_amdgcn_mfma_f32_16x16x32_bf16(ah0, bh, acc[0][nt], 0, 0, 0);
            acc[0][nt] = __builtin_amdgcn_mfma_f32_16x16x32_bf16(ah0, bl, acc[0][nt], 0, 0, 0);
            acc[0][nt] = __builtin_amdgcn_mfma_f32_16x16x32_bf16(al0, bh, acc[0][nt], 0, 0, 0);
            acc[1][nt] = __builtin_amdgcn_mfma_f32_16x16x32_bf16(ah1, bh, acc[1][nt], 0, 0, 0);
            acc[1][nt] = __builtin_amdgcn_mfma_f32_16x16x32_bf16(ah1, bl, acc[1][nt], 0, 0, 0);
            acc[1][nt] = __builtin_amdgcn_mfma_f32_16x16x32_bf16(al1, bh, acc[1][nt], 0, 0, 0);
        }
    }
    // C/D layout: col = lane&15, row = (lane>>4)*4 + reg
    #pragma unroll
    for (int mt = 0; mt < 2; mt++) {
        #pragma unroll
        for (int nt = 0; nt < 4; nt++) {
            int col = nblk + nt * 16 + fr;
            if (NGUARD && col >= N) continue;
            #pragma unroll
            for (int r = 0; r < 4; r++) {
                int row = mblk + wid * 32 + mt * 16 + kg * 4 + r;
                C[(size_t)row * ldc + col] = acc[mt][nt][r];
            }
        }
    }
    if (DOMAX) {
        // fused signed max of Bc (cols 32..159) and Cc (cols 160..287)
        float mb = -INFINITY, mc = -INFINITY;
        #pragma unroll
        for (int nt = 0; nt < 4; nt++) {
            int c16 = nblk + nt * 16;         // 16-col subtile never straddles 32/160/288
            if (c16 >= 32 && c16 < 160) {
                #pragma unroll
                for (int mt = 0; mt < 2; mt++)
                    #pragma unroll
                    for (int r = 0; r < 4; r++) mb = fmaxf(mb, acc[mt][nt][r]);
            } else if (c16 >= 160 && c16 < 288) {
                #pragma unroll
                for (int mt = 0; mt < 2; mt++)
                    #pragma unroll
                    for (int r = 0; r < 4; r++) mc = fmaxf(mc, acc[mt][nt][r]);
            }
        }
        #pragma unroll
        for (int off = 32; off > 0; off >>= 1) {
            mb = fmaxf(mb, __shfl_xor(mb, off));
            mc = fmaxf(mc, __shfl_xor(mc, off));
        }
        if (lane == 0) {
            if (mb > -INFINITY) atomicMax(bcmax + 2 * br,     fkey(mb));
            if (mc > -INFINITY) atomicMax(bcmax + 2 * br + 1, fkey(mc));
        }
    }
}

// ---------------- depthwise conv (k=4) + SiLU, merged branches ----------------
__global__ __launch_bounds__(256) void conv_silu_kernel(const float* __restrict__ xz,
                                                        float* __restrict__ xs,
                                                        unsigned short* __restrict__ xsh,
                                                        unsigned short* __restrict__ xsl,
                                                        unsigned short* __restrict__ yzh,
                                                        unsigned short* __restrict__ yzl,
                                                        const float* __restrict__ wx0,
                                                        const float* __restrict__ wx1,
                                                        const float* __restrict__ wz0,
                                                        const float* __restrict__ wz1) {
    int idx = blockIdx.x * 256 + threadIdx.x;   // over MROW*256
    int c   = idx & 255;
    int row = idx >> 8;          // global row 0..8191
    int br  = row >> 12;
    int t   = row & (L_ - 1);
    const float* wx = br ? wx1 : wx0;
    const float* wz = br ? wz1 : wz0;
    float ax = 0.0f, az = 0.0f;
    #pragma unroll
    for (int j = 0; j < 4; j++) {
        int tt = t + j - 1;
        if (tt >= 0 && tt < L_) {
            const float* p = xz + (size_t)(row + j - 1) * 512;
            ax = fmaf(p[c], wx[c * 4 + j], ax);
            az = fmaf(p[c + 256], wz[c * 4 + j], az);
        }
    }
    float sx = siluf(ax);
    float sz = siluf(az);
    xs[(size_t)row * 256 + c] = sx;
    unsigned short h, l;
    split2(sx, h, l);
    xsh[(size_t)row * 256 + c] = h;
    xsl[(size_t)row * 256 + c] = l;
    split2(sz, h, l);
    yzh[(size_t)row * 512 + 256 + c] = h;
    yzl[(size_t)row * 512 + 256 + c] = l;
}

// ---------------- fused dt_proj (K=32) + softplus + scan-input prep ----------------
// grid (256/64, MROW/64). Writes dtT/duT/udT directly (d-major); delta never hits memory.
__global__ __launch_bounds__(256) void dtprep_kernel(const float* __restrict__ A, int lda,
                                                     const float* __restrict__ W0,
                                                     const float* __restrict__ W1,
                                                     const float* __restrict__ b0,
                                                     const float* __restrict__ b1,
                                                     const float* __restrict__ xs,
                                                     const float* __restrict__ Dvec,
                                                     float* __restrict__ dtT,
                                                     float* __restrict__ duT,
                                                     float* __restrict__ udT) {
    __shared__ float As[16][68];
    __shared__ float Ws[16][68];
    int tid = threadIdx.x;
    int kk = tid & 15;
    int rr = tid >> 4;
    int mblk = blockIdx.y * 64;
    int nblk = blockIdx.x * 64;
    int br = (mblk >= NROW) ? 1 : 0;
    const float* W    = br ? W1 : W0;
    const float* bias = br ? b1 : b0;
    float acc[4][4] = {};
    for (int k0 = 0; k0 < 32; k0 += 16) {
        #pragma unroll
        for (int j = 0; j < 4; j++) {
            As[kk][rr + 16 * j] = A[(size_t)(mblk + rr + 16 * j) * lda + k0 + kk];
        }
        #pragma unroll
        for (int j = 0; j < 4; j++) {
            Ws[kk][rr + 16 * j] = W[(size_t)(nblk + rr + 16 * j) * 32 + k0 + kk];
        }
        __syncthreads();
        int ty = tid >> 4;
        int tx = tid & 15;
        #pragma unroll
        for (int kq = 0; kq < 16; kq++) {
            float a0 = As[kq][ty * 4 + 0];
            float a1 = As[kq][ty * 4 + 1];
            float a2 = As[kq][ty * 4 + 2];
            float a3 = As[kq][ty * 4 + 3];
            float v0 = Ws[kq][tx * 4 + 0];
            float v1 = Ws[kq][tx * 4 + 1];
            float v2 = Ws[kq][tx * 4 + 2];
            float v3 = Ws[kq][tx * 4 + 3];
            acc[0][0] = fmaf(a0, v0, acc[0][0]); acc[0][1] = fmaf(a0, v1, acc[0][1]);
            acc[0][2] = fmaf(a0, v2, acc[0][2]); acc[0][3] = fmaf(a0, v3, acc[0][3]);
            acc[1][0] = fmaf(a1, v0, acc[1][0]); acc[1][1] = fmaf(a1, v1, acc[1][1]);
            acc[1][2] = fmaf(a1, v2, acc[1][2]); acc[1][3] = fmaf(a1, v3, acc[1][3]);
            acc[2][0] = fmaf(a2, v0, acc[2][0]); acc[2][1] = fmaf(a2, v1, acc[2][1]);
            acc[2][2] = fmaf(a2, v2, acc[2][2]); acc[2][3] = fmaf(a2, v3, acc[2][3]);
            acc[3][0] = fmaf(a3, v0, acc[3][0]); acc[3][1] = fmaf(a3, v1, acc[3][1]);
            acc[3][2] = fmaf(a3, v2, acc[3][2]); acc[3][3] = fmaf(a3, v3, acc[3][3]);
        }
        __syncthreads();
    }
    int ty = tid >> 4;
    int tx = tid & 15;
    #pragma unroll
    for (int i = 0; i < 4; i++) {
        int m = mblk + ty * 4 + i;           // global row
        int mloc = m & (NROW - 1);           // within-branch row
        #pragma unroll
        for (int j = 0; j < 4; j++) {
            int n = nblk + tx * 4 + j;       // d
            float delta = softplusf(acc[i][j] + bias[n]);
            float u = xs[(size_t)m * 256 + n];
            size_t dst = ((size_t)br * 256 + n) * 4096 + mloc;
            dtT[dst] = delta * LOG2E;
            duT[dst] = delta * u;
            udT[dst] = u * Dvec[n];
        }
    }
}

// ---------------- shrink + pack Bc/Cc, merged; decodes atomic maxima ----------------
__global__ __launch_bounds__(256) void shrinkpack_kernel(const float* __restrict__ xdbl,
                                                         const unsigned* __restrict__ bcmax,
                                                         float* __restrict__ Bs,
                                                         float* __restrict__ Cs) {
    int idx = blockIdx.x * 256 + threadIdx.x;   // over MROW*128
    int row = idx >> 7;          // global row 0..8191
    int br  = row >> 12;
    int n = idx & 127;
    float tB = 0.1f * funkey(bcmax[2 * br]);
    float tC = 0.1f * funkey(bcmax[2 * br + 1]);
    const float* p = xdbl + (size_t)row * 288;
    Bs[idx] = shrinkf(p[32 + n], tB);
    Cs[idx] = shrinkf(p[160 + n], tC);
}

// ---------------- selective scan (v3 structure; computes A on the fly) ----------------
__global__ __launch_bounds__(128) void scan3_kernel(float* __restrict__ ws,
                                                    const float* __restrict__ A_log,
                                                    const float* __restrict__ eps) {
    int blk  = blockIdx.x;
    int xcd  = blk & 7;
    int slot = blk >> 3;
    int combo = xcd >> 1;
    int d  = (xcd & 1) * 128 + slot;
    int br = combo >> 1;
    int b  = combo & 1;
    int tid = threadIdx.x;
    int lt  = tid & 63;

    // A on the fly: thr1 = 0.1*max(base), max(base) = -e*exp(min A_log) (monotone);
    // thr2 = 0.1*shrink(max(base),thr1) (shrink is monotone).
    float pv = ws[OFF_MINP + (tid & 31)];
    #pragma unroll
    for (int off = 16; off > 0; off >>= 1) pv = fminf(pv, __shfl_xor(pv, off));
    float e  = 1.0f + eps[0];
    float m1 = -e * __expf(pv);
    float t1 = 0.1f * m1;
    float t2 = 0.1f * shrinkf(m1, t1);
    float base = -e * __expf(A_log[d * 128 + tid]);
    float a = shrinkf(base, t1);
    if (br) a = shrinkf(a, t2);

    size_t dchain = ((size_t)br * 256 + d) * 4096 + (size_t)b * L_;
    const float* dtT = ws + OFF_DTT + dchain;
    const float* duT = ws + OFF_DUT + dchain;
    const float* udT = ws + OFF_UDT + dchain;
    const float* Bp  = ws + OFF_BS + ((size_t)br * NROW + (size_t)b * L_) * 128 + tid;
    const float* Cp  = ws + OFF_CS + ((size_t)br * NROW + (size_t)b * L_) * 128 + tid;
    float*       yTp = ws + OFF_YT + dchain;

    __shared__ float red[64 * 132];
    __shared__ float comb[64];

    float h = 0.0f;

    float Bb[2][8], Cb[2][8];
    float dt_c = dtT[lt];
    float du_c = duT[lt];
    float ud_c = udT[lt];
    float dt_n = 0.f, du_n = 0.f, ud_n = 0.f;
    #pragma unroll
    for (int j = 0; j < 8; j++) { Bb[0][j] = Bp[(size_t)j * 128];       Cb[0][j] = Cp[(size_t)j * 128]; }
    #pragma unroll
    for (int j = 0; j < 8; j++) { Bb[1][j] = Bp[(size_t)(8 + j) * 128]; Cb[1][j] = Cp[(size_t)(8 + j) * 128]; }

    for (int c = 0; c < 32; c++) {
        if (c < 31) {
            dt_n = dtT[(c + 1) * 64 + lt];
            du_n = duT[(c + 1) * 64 + lt];
            ud_n = udT[(c + 1) * 64 + lt];
        }
        #pragma unroll
        for (int m = 0; m < 8; m++) {
            const int cur = m & 1;
            #pragma unroll
            for (int j = 0; j < 8; j++) {
                const int tl = m * 8 + j;
                float dt2 = rlanef(dt_c, tl);
                float du  = rlanef(du_c, tl);
                float ev = __builtin_amdgcn_exp2f(dt2 * a);
                h = fmaf(ev, h, du * Bb[cur][j]);
                red[tl * 132 + tid] = h * Cb[cur][j];
            }
            int nb = c * 8 + m + 2;
            if (nb < 256) {
                #pragma unroll
                for (int j = 0; j < 8; j++) {
                    Bb[cur][j] = Bp[((size_t)nb * 8 + j) * 128];
                    Cb[cur][j] = Cp[((size_t)nb * 8 + j) * 128];
                }
            }
        }
        __syncthreads();
        {
            const float* rp = &red[(tid & 63) * 132 + (tid >> 6) * 64];
            float s0 = 0.f, s1 = 0.f, s2 = 0.f, s3 = 0.f;
            #pragma unroll
            for (int i = 0; i < 64; i += 4) {
                float4 v = *(const float4*)(rp + i);
                s0 += v.x; s1 += v.y; s2 += v.z; s3 += v.w;
            }
            float part = (s0 + s1) + (s2 + s3);
            if (tid >= 64) comb[tid - 64] = part;
            __syncthreads();
            if (tid < 64) yTp[c * 64 + tid] = part + comb[tid] + ud_c;
        }
        __syncthreads();
        dt_c = dt_n;
        du_c = du_n;
        ud_c = ud_n;
    }
}

// ---------------- yT -> yz bf16 split (y half), merged: grid (8, 128, 2) ----------------
__global__ __launch_bounds__(256) void transpose_yz_kernel(const float* __restrict__ yT,
                                                           unsigned short* __restrict__ yzh,
                                                           unsigned short* __restrict__ yzl) {
    __shared__ float tile[32][33];
    int br = blockIdx.z;
    int m0 = blockIdx.x * 32;   // d rows
    int n0 = blockIdx.y * 32;   // within-branch t cols
    int tx = threadIdx.x;
    int ty = threadIdx.y;
    #pragma unroll
    for (int k = 0; k < 4; k++) {
        tile[ty + 8 * k][tx] = yT[((size_t)br * 256 + m0 + ty + 8 * k) * 4096 + n0 + tx];
    }
    __syncthreads();
    #pragma unroll
    for (int k = 0; k < 4; k++) {
        size_t dst = ((size_t)br * NROW + n0 + ty + 8 * k) * 512 + m0 + tx;
        unsigned short h, l;
        split2(tile[tx][ty + 8 * k], h, l);
        yzh[dst] = h; yzl[dst] = l;
    }
}

// ---------------- host-side launch ----------------
extern "C" void kernel_launch(void* const* d_in, const int* in_sizes, int n_in,
                              void* d_out, int out_size, void* d_ws, size_t ws_size,
                              hipStream_t stream) {
    const float* inp   = (const float*)d_in[0];
    const float* in_w[2]  = {(const float*)d_in[1],  (const float*)d_in[8]};
    const float* cxw[2]   = {(const float*)d_in[2],  (const float*)d_in[9]};
    const float* czw[2]   = {(const float*)d_in[3],  (const float*)d_in[10]};
    const float* xw[2]    = {(const float*)d_in[4],  (const float*)d_in[11]};
    const float* dtw[2]   = {(const float*)d_in[5],  (const float*)d_in[12]};
    const float* dtb[2]   = {(const float*)d_in[6],  (const float*)d_in[13]};
    const float* outw[2]  = {(const float*)d_in[7],  (const float*)d_in[14]};
    const float* A_log = (const float*)d_in[15];
    const float* Dvec  = (const float*)d_in[16];
    const float* eps   = (const float*)d_in[17];
    float* out = (float*)d_out;
    float* ws  = (float*)d_ws;
    unsigned short* hb = (unsigned short*)(ws + FLOAT_END);
    unsigned* bcmax = (unsigned*)(ws + OFF_BCMX);

    // min(A_log) partials + atomic-slot init
    minA_kernel<<<32, 256, 0, stream>>>(A_log, ws, bcmax);

    wsplit_all<<<(1196032 + 255) / 256, 256, 0, stream>>>(
        in_w[0], in_w[1], outw[0], outw[1], xw[0], xw[1], hb);

    transpose_in_kernel<<<dim3(L_ / 32, 512 / 32, 4), dim3(32, 8), 0, stream>>>(
        inp, hb + HOFF_XINH, hb + HOFF_XINL);

    // in_proj (merged M=8192): xz = xin * in_w^T
    gemm_mfma<0, 0><<<dim3(512 / 64, MROW / 128), 256, 0, stream>>>(
        hb + HOFF_XINH, hb + HOFF_XINL, 512,
        hb + HOFF_INWH, hb + HOFF_INWL, WST_IN,
        ws + OFF_XZ, 512, 512, 512, nullptr);

    conv_silu_kernel<<<(MROW * HALF_) / 256, 256, 0, stream>>>(
        ws + OFF_XZ, ws + OFF_XS, hb + HOFF_XSH, hb + HOFF_XSL,
        hb + HOFF_YZH, hb + HOFF_YZL, cxw[0], cxw[1], czw[0], czw[1]);

    // x_proj (merged): xdbl = xs * xw^T, with fused B/C signed-max atomics
    gemm_mfma<1, 1><<<dim3((288 + 63) / 64, MROW / 128), 256, 0, stream>>>(
        hb + HOFF_XSH, hb + HOFF_XSL, 256,
        hb + HOFF_XWH, hb + HOFF_XWL, WST_X,
        ws + OFF_XDBL, 288, 288, 256, bcmax);

    // dt_proj + softplus + prep (fused): writes dtT/duT/udT directly
    dtprep_kernel<<<dim3(256 / 64, MROW / 64), 256, 0, stream>>>(
        ws + OFF_XDBL, 288, dtw[0], dtw[1], dtb[0], dtb[1],
        ws + OFF_XS, Dvec,
        ws + OFF_DTT, ws + OFF_DUT, ws + OFF_UDT);

    shrinkpack_kernel<<<(MROW * 128) / 256, 256, 0, stream>>>(
        ws + OFF_XDBL, bcmax, ws + OFF_BS, ws + OFF_CS);

    scan3_kernel<<<dim3(1024), 128, 0, stream>>>(ws, A_log, eps);

    transpose_yz_kernel<<<dim3(256 / 32, NROW / 32, 2), dim3(32, 8), 0, stream>>>(
        ws + OFF_YT, hb + HOFF_YZH, hb + HOFF_YZL);

    // out_proj (merged): d_out = yz * out_w^T
    gemm_mfma<0, 0><<<dim3(512 / 64, MROW / 128), 256, 0, stream>>>(
        hb + HOFF_YZH, hb + HOFF_YZL, 512,
        hb + HOFF_OUTWH, hb + HOFF_OUTWL, WST_IN,
        out, 512, 512, 512, nullptr);
}

// Round 8
// 341.108 us; speedup vs baseline: 2.7167x; 1.0281x over previous
//
#include <hip/hip_runtime.h>
#include <math.h>

// ---------------- problem constants ----------------
constexpr int B_    = 2;
constexpr int L_    = 2048;
constexpr int NROW  = B_ * L_;     // 4096 rows per branch
constexpr int MROW  = 2 * NROW;    // 8192 merged rows (branch-major)
constexpr int HALF_ = 256;
constexpr int DS_   = 128;

constexpr float LOG2E = 1.4426950408889634f;

// ---------------- ws layout ----------------
// fp32 region (float element offsets)
constexpr size_t OFF_MINP = 0;                                    // 32 (minA partials)
constexpr size_t OFF_BCMX = 32;                                   // 4 (uint atomics: brB,brC x2)
constexpr size_t OFF_XZ   = 64;                                   // 8192x512 (transient)
constexpr size_t OFF_YT   = OFF_XZ + (size_t)MROW * 256;          // alias: 2x256x4096 (after conv)
constexpr size_t OFF_XDBL = OFF_XZ + (size_t)MROW * 512;          // 8192x288
constexpr size_t OFF_XS   = OFF_XDBL + (size_t)MROW * 288;        // 8192x256
constexpr size_t OFF_BS   = OFF_XS  + (size_t)MROW * 256;         // 2 x 4096x128
constexpr size_t OFF_CS   = OFF_BS  + (size_t)2 * NROW * 128;     // 2 x 4096x128
constexpr size_t OFF_DTT  = OFF_CS  + (size_t)2 * NROW * 128;     // 2 x 256x4096
constexpr size_t OFF_DUT  = OFF_DTT + (size_t)2 * 256 * 4096;
constexpr size_t OFF_UDT  = OFF_DUT + (size_t)2 * 256 * 4096;
constexpr size_t FLOAT_END = OFF_UDT + (size_t)2 * 256 * 4096;

// bf16 region (ushort element offsets, based at ws + FLOAT_END floats)
constexpr size_t HOFF_XINH = 0;                                   // 8192x512
constexpr size_t HOFF_XINL = HOFF_XINH + (size_t)MROW * 512;
constexpr size_t HOFF_YZH  = HOFF_XINH;                           // alias (xin dead after in_proj)
constexpr size_t HOFF_YZL  = HOFF_XINL;
constexpr size_t HOFF_XSH  = HOFF_XINL + (size_t)MROW * 512;      // 8192x256
constexpr size_t HOFF_XSL  = HOFF_XSH  + (size_t)MROW * 256;
constexpr size_t HOFF_INWH = HOFF_XSL  + (size_t)MROW * 256;      // 2 x 512x512
constexpr size_t HOFF_INWL = HOFF_INWH + 524288;
constexpr size_t HOFF_XWH  = HOFF_INWL + 524288;                  // 2 x 288x256
constexpr size_t HOFF_XWL  = HOFF_XWH  + 147456;
constexpr size_t HOFF_OUTWH= HOFF_XWL  + 147456;                  // 2 x 512x512
constexpr size_t HOFF_OUTWL= HOFF_OUTWH+ 524288;

constexpr size_t WST_IN = 262144;   // per-branch in/out weight elems
constexpr size_t WST_X  = 73728;    // per-branch x_proj weight elems

// pre_all block ranges
constexpr int PRE_MINA = 32;
constexpr int PRE_WSPL = (1196032 + 255) / 256;   // 4672
constexpr int PRE_TIN  = 64 * 16 * 4;             // 4096
constexpr int PRE_BLOCKS = PRE_MINA + PRE_WSPL + PRE_TIN;

// ---------------- types / helpers ----------------
typedef __bf16 bf16x8 __attribute__((ext_vector_type(8)));
typedef float  f32x4  __attribute__((ext_vector_type(4)));

__device__ __forceinline__ unsigned short bf16rn(float x) {
    unsigned u = __float_as_uint(x);
    unsigned r = (u + 0x7FFFu + ((u >> 16) & 1u)) >> 16;
    return (unsigned short)r;
}
__device__ __forceinline__ void split2(float x, unsigned short& h, unsigned short& l) {
    h = bf16rn(x);
    float hf = __uint_as_float(((unsigned)h) << 16);
    l = bf16rn(x - hf);
}

__device__ __forceinline__ float shrinkf(float v, float thr) {
    float a = fabsf(v) - thr;
    a = fmaxf(a, 0.0f);
    float r = copysignf(a, v);
    return (v == 0.0f) ? 0.0f : r;
}
__device__ __forceinline__ float siluf(float v) { return v / (1.0f + __expf(-v)); }
__device__ __forceinline__ float softplusf(float v) {
    return fmaxf(v, 0.0f) + log1pf(__expf(-fabsf(v)));
}
__device__ __forceinline__ float rlanef(float v, int l) {
    return __int_as_float(__builtin_amdgcn_readlane(__float_as_int(v), l));
}
// monotone float<->uint key for atomicMax on signed floats
__device__ __forceinline__ unsigned fkey(float f) {
    unsigned u = __float_as_uint(f);
    return (u >> 31) ? ~u : (u | 0x80000000u);
}
__device__ __forceinline__ float funkey(unsigned k) {
    unsigned u = (k >> 31) ? (k & 0x7FFFFFFFu) : ~k;
    return __uint_as_float(u);
}

// ---------------- pre_all: minA + weight splits + input transpose, one dispatch ----------------
__global__ __launch_bounds__(256) void pre_all(const float* __restrict__ A_log,
                                               const float* __restrict__ inp,
                                               const float* __restrict__ in_w0,
                                               const float* __restrict__ in_w1,
                                               const float* __restrict__ outw0,
                                               const float* __restrict__ outw1,
                                               const float* __restrict__ xw0,
                                               const float* __restrict__ xw1,
                                               float* __restrict__ ws,
                                               unsigned* __restrict__ bcmax,
                                               unsigned short* __restrict__ hb) {
    int bid = blockIdx.x;
    int tid = threadIdx.x;
    if (bid < PRE_MINA) {
        // ---- minA role ----
        __shared__ float sbuf[8];
        int i = bid * 1024 + tid * 4;
        float4 v = *(const float4*)(A_log + i);
        float mv = fminf(fminf(v.x, v.y), fminf(v.z, v.w));
        #pragma unroll
        for (int off = 32; off > 0; off >>= 1) mv = fminf(mv, __shfl_xor(mv, off));
        if ((tid & 63) == 0) sbuf[tid >> 6] = mv;
        __syncthreads();
        if (tid == 0) {
            float r = fminf(fminf(sbuf[0], sbuf[1]), fminf(sbuf[2], sbuf[3]));
            ws[OFF_MINP + bid] = r;
        }
        if (bid == 0 && tid < 4) bcmax[tid] = 0u;
    } else if (bid < PRE_MINA + PRE_WSPL) {
        // ---- wsplit role ----
        int i = (bid - PRE_MINA) * 256 + tid;
        if (i >= 1196032) return;
        const float* src;
        size_t hbase, lbase;
        int off;
        if (i < 1048576) {
            int t = i >> 18;
            off = i & 262143;
            src = (t == 0) ? in_w0 : (t == 1) ? in_w1 : (t == 2) ? outw0 : outw1;
            if (t < 2) { hbase = HOFF_INWH + (size_t)t * WST_IN;  lbase = HOFF_INWL + (size_t)t * WST_IN; }
            else       { hbase = HOFF_OUTWH + (size_t)(t - 2) * WST_IN; lbase = HOFF_OUTWL + (size_t)(t - 2) * WST_IN; }
        } else {
            int j = i - 1048576;
            int t = (j < (int)WST_X) ? 0 : 1;
            off = j - t * (int)WST_X;
            src = t ? xw1 : xw0;
            hbase = HOFF_XWH + (size_t)t * WST_X;
            lbase = HOFF_XWL + (size_t)t * WST_X;
        }
        unsigned short h, l;
        split2(src[off], h, l);
        hb[hbase + off] = h;
        hb[lbase + off] = l;
    } else {
        // ---- transpose_in role ----
        __shared__ float tile[32][33];
        int idx = bid - PRE_MINA - PRE_WSPL;    // 0..4095
        int bx = idx & 63;          // t block (64)
        int by = (idx >> 6) & 15;   // ch block (16)
        int z  = idx >> 10;         // 0..3
        int br = z >> 1;
        int b  = z & 1;
        int t0 = bx * 32;
        int m0 = by * 32;
        int tx = tid & 31;
        int ty = tid >> 5;
        #pragma unroll
        for (int k = 0; k < 4; k++) {
            tile[ty + 8 * k][tx] =
                inp[((size_t)b * 1024 + br * 512 + m0 + ty + 8 * k) * L_ + t0 + tx];
        }
        __syncthreads();
        #pragma unroll
        for (int k = 0; k < 4; k++) {
            size_t dst = ((size_t)br * NROW + (size_t)b * L_ + t0 + ty + 8 * k) * 512 + m0 + tx;
            unsigned short h, l;
            split2(tile[tx][ty + 8 * k], h, l);
            hb[HOFF_XINH + dst] = h;
            hb[HOFF_XINL + dst] = l;
        }
    }
}

// ---------------- MFMA GEMM (bf16x3): C[M,N] = A * W_br^T, merged M=8192 ----------------
// 128x64 tile, BK=32, 256 thr. DOMAX: fused signed-max of B/C col-ranges via atomicMax.
template <int NGUARD, int DOMAX>
__global__ __launch_bounds__(256) void gemm_mfma(const unsigned short* __restrict__ Ah,
                                                 const unsigned short* __restrict__ Al, int lda,
                                                 const unsigned short* __restrict__ WhB,
                                                 const unsigned short* __restrict__ WlB,
                                                 size_t wstride,
                                                 float* __restrict__ C, int ldc,
                                                 int N, int K,
                                                 unsigned* __restrict__ bcmax) {
    __shared__ __align__(16) unsigned short sAh[128 * 40];
    __shared__ __align__(16) unsigned short sAl[128 * 40];
    __shared__ __align__(16) unsigned short sBh[64 * 40];
    __shared__ __align__(16) unsigned short sBl[64 * 40];
    int tid  = threadIdx.x;
    int wid  = tid >> 6;
    int lane = tid & 63;
    int fr   = lane & 15;
    int kg   = lane >> 4;
    int mblk = blockIdx.y * 128;
    int nblk = blockIdx.x * 64;
    int br   = (mblk >= NROW) ? 1 : 0;
    const unsigned short* Wh = WhB + (size_t)br * wstride;
    const unsigned short* Wl = WlB + (size_t)br * wstride;
    int srow = tid >> 2;            // 0..63
    int skp  = (tid & 3) * 8;       // k-chunk of 8

    f32x4 acc[2][4] = {};

    for (int k0 = 0; k0 < K; k0 += 32) {
        uint4 vah0 = *(const uint4*)(Ah + (size_t)(mblk + srow) * lda + k0 + skp);
        uint4 vah1 = *(const uint4*)(Ah + (size_t)(mblk + 64 + srow) * lda + k0 + skp);
        uint4 val0 = *(const uint4*)(Al + (size_t)(mblk + srow) * lda + k0 + skp);
        uint4 val1 = *(const uint4*)(Al + (size_t)(mblk + 64 + srow) * lda + k0 + skp);
        uint4 vbh = {0, 0, 0, 0}, vbl = {0, 0, 0, 0};
        if (!NGUARD || (nblk + srow) < N) {
            vbh = *(const uint4*)(Wh + (size_t)(nblk + srow) * K + k0 + skp);
            vbl = *(const uint4*)(Wl + (size_t)(nblk + srow) * K + k0 + skp);
        }
        __syncthreads();   // WAR vs previous iter's ds_reads
        *(uint4*)(sAh + srow * 40 + skp) = vah0;
        *(uint4*)(sAh + (64 + srow) * 40 + skp) = vah1;
        *(uint4*)(sAl + srow * 40 + skp) = val0;
        *(uint4*)(sAl + (64 + srow) * 40 + skp) = val1;
        *(uint4*)(sBh + srow * 40 + skp) = vbh;
        *(uint4*)(sBl + srow * 40 + skp) = vbl;
        __syncthreads();

        bf16x8 ah0 = *(const bf16x8*)(sAh + (wid * 32 + fr) * 40 + kg * 8);
        bf16x8 ah1 = *(const bf16x8*)(sAh + (wid * 32 + 16 + fr) * 40 + kg * 8);
        bf16x8 al0 = *(const bf16x8*)(sAl + (wid * 32 + fr) * 40 + kg * 8);
        bf16x8 al1 = *(const bf16x8*)(sAl + (wid * 32 + 16 + fr) * 40 + kg * 8);
        #pragma unroll
        for (int nt = 0; nt < 4; nt++) {
            bf16x8 bh = *(const bf16x8*)(sBh + (nt * 16 + fr) * 40 + kg * 8);
            bf16x8 bl = *(const bf16x8*)(sBl + (nt * 16 + fr) * 40 + kg * 8);
            acc[0][nt] = __builtin_amdgcn_mfma_f32_16x16x32_bf16(ah0, bh, acc[0][nt], 0, 0, 0);
            acc[0][nt] = __builtin_amdgcn_mfma_f32_16x16x32_bf16(ah0, bl, acc[0][nt], 0, 0, 0);
            acc[0][nt] = __builtin_amdgcn_mfma_f32_16x16x32_bf16(al0, bh, acc[0][nt], 0, 0, 0);
            acc[1][nt] = __builtin_amdgcn_mfma_f32_16x16x32_bf16(ah1, bh, acc[1][nt], 0, 0, 0);
            acc[1][nt] = __builtin_amdgcn_mfma_f32_16x16x32_bf16(ah1, bl, acc[1][nt], 0, 0, 0);
            acc[1][nt] = __builtin_amdgcn_mfma_f32_16x16x32_bf16(al1, bh, acc[1][nt], 0, 0, 0);
        }
    }
    // C/D layout: col = lane&15, row = (lane>>4)*4 + reg
    #pragma unroll
    for (int mt = 0; mt < 2; mt++) {
        #pragma unroll
        for (int nt = 0; nt < 4; nt++) {
            int col = nblk + nt * 16 + fr;
            if (NGUARD && col >= N) continue;
            #pragma unroll
            for (int r = 0; r < 4; r++) {
                int row = mblk + wid * 32 + mt * 16 + kg * 4 + r;
                C[(size_t)row * ldc + col] = acc[mt][nt][r];
            }
        }
    }
    if (DOMAX) {
        // fused signed max of Bc (cols 32..159) and Cc (cols 160..287)
        float mb = -INFINITY, mc = -INFINITY;
        #pragma unroll
        for (int nt = 0; nt < 4; nt++) {
            int c16 = nblk + nt * 16;         // 16-col subtile never straddles 32/160/288
            if (c16 >= 32 && c16 < 160) {
                #pragma unroll
                for (int mt = 0; mt < 2; mt++)
                    #pragma unroll
                    for (int r = 0; r < 4; r++) mb = fmaxf(mb, acc[mt][nt][r]);
            } else if (c16 >= 160 && c16 < 288) {
                #pragma unroll
                for (int mt = 0; mt < 2; mt++)
                    #pragma unroll
                    for (int r = 0; r < 4; r++) mc = fmaxf(mc, acc[mt][nt][r]);
            }
        }
        #pragma unroll
        for (int off = 32; off > 0; off >>= 1) {
            mb = fmaxf(mb, __shfl_xor(mb, off));
            mc = fmaxf(mc, __shfl_xor(mc, off));
        }
        if (lane == 0) {
            if (mb > -INFINITY) atomicMax(bcmax + 2 * br,     fkey(mb));
            if (mc > -INFINITY) atomicMax(bcmax + 2 * br + 1, fkey(mc));
        }
    }
}

// ---------------- depthwise conv (k=4) + SiLU, merged branches ----------------
__global__ __launch_bounds__(256) void conv_silu_kernel(const float* __restrict__ xz,
                                                        float* __restrict__ xs,
                                                        unsigned short* __restrict__ xsh,
                                                        unsigned short* __restrict__ xsl,
                                                        unsigned short* __restrict__ yzh,
                                                        unsigned short* __restrict__ yzl,
                                                        const float* __restrict__ wx0,
                                                        const float* __restrict__ wx1,
                                                        const float* __restrict__ wz0,
                                                        const float* __restrict__ wz1) {
    int idx = blockIdx.x * 256 + threadIdx.x;   // over MROW*256
    int c   = idx & 255;
    int row = idx >> 8;          // global row 0..8191
    int br  = row >> 12;
    int t   = row & (L_ - 1);
    const float* wx = br ? wx1 : wx0;
    const float* wz = br ? wz1 : wz0;
    float ax = 0.0f, az = 0.0f;
    #pragma unroll
    for (int j = 0; j < 4; j++) {
        int tt = t + j - 1;
        if (tt >= 0 && tt < L_) {
            const float* p = xz + (size_t)(row + j - 1) * 512;
            ax = fmaf(p[c], wx[c * 4 + j], ax);
            az = fmaf(p[c + 256], wz[c * 4 + j], az);
        }
    }
    float sx = siluf(ax);
    float sz = siluf(az);
    xs[(size_t)row * 256 + c] = sx;
    unsigned short h, l;
    split2(sx, h, l);
    xsh[(size_t)row * 256 + c] = h;
    xsl[(size_t)row * 256 + c] = l;
    split2(sz, h, l);
    yzh[(size_t)row * 512 + 256 + c] = h;
    yzl[(size_t)row * 512 + 256 + c] = l;
}

// ---------------- fused dt_proj(K=32)+softplus+prep + shrinkpack, one dispatch ----------------
// grid (4, MROW/64). GEMM part: 64 rows x 64 d. Shrink part: same 64 rows x 64-col slice
// of Bc (nb<2) or Cc (nb>=2). bcmax final at kernel entry (previous dispatch's atomics).
__global__ __launch_bounds__(256) void dtprep_shrink(const float* __restrict__ A, int lda,
                                                     const float* __restrict__ W0,
                                                     const float* __restrict__ W1,
                                                     const float* __restrict__ b0,
                                                     const float* __restrict__ b1,
                                                     const float* __restrict__ xs,
                                                     const float* __restrict__ Dvec,
                                                     float* __restrict__ dtT,
                                                     float* __restrict__ duT,
                                                     float* __restrict__ udT,
                                                     const unsigned* __restrict__ bcmax,
                                                     float* __restrict__ Bs,
                                                     float* __restrict__ Cs) {
    __shared__ float As[16][68];
    __shared__ float Ws[16][68];
    int tid = threadIdx.x;
    int kk = tid & 15;
    int rr = tid >> 4;
    int mblk = blockIdx.y * 64;
    int nblk = blockIdx.x * 64;
    int br = (mblk >= NROW) ? 1 : 0;
    const float* W    = br ? W1 : W0;
    const float* bias = br ? b1 : b0;
    float acc[4][4] = {};
    for (int k0 = 0; k0 < 32; k0 += 16) {
        #pragma unroll
        for (int j = 0; j < 4; j++) {
            As[kk][rr + 16 * j] = A[(size_t)(mblk + rr + 16 * j) * lda + k0 + kk];
        }
        #pragma unroll
        for (int j = 0; j < 4; j++) {
            Ws[kk][rr + 16 * j] = W[(size_t)(nblk + rr + 16 * j) * 32 + k0 + kk];
        }
        __syncthreads();
        int ty = tid >> 4;
        int tx = tid & 15;
        #pragma unroll
        for (int kq = 0; kq < 16; kq++) {
            float a0 = As[kq][ty * 4 + 0];
            float a1 = As[kq][ty * 4 + 1];
            float a2 = As[kq][ty * 4 + 2];
            float a3 = As[kq][ty * 4 + 3];
            float v0 = Ws[kq][tx * 4 + 0];
            float v1 = Ws[kq][tx * 4 + 1];
            float v2 = Ws[kq][tx * 4 + 2];
            float v3 = Ws[kq][tx * 4 + 3];
            acc[0][0] = fmaf(a0, v0, acc[0][0]); acc[0][1] = fmaf(a0, v1, acc[0][1]);
            acc[0][2] = fmaf(a0, v2, acc[0][2]); acc[0][3] = fmaf(a0, v3, acc[0][3]);
            acc[1][0] = fmaf(a1, v0, acc[1][0]); acc[1][1] = fmaf(a1, v1, acc[1][1]);
            acc[1][2] = fmaf(a1, v2, acc[1][2]); acc[1][3] = fmaf(a1, v3, acc[1][3]);
            acc[2][0] = fmaf(a2, v0, acc[2][0]); acc[2][1] = fmaf(a2, v1, acc[2][1]);
            acc[2][2] = fmaf(a2, v2, acc[2][2]); acc[2][3] = fmaf(a2, v3, acc[2][3]);
            acc[3][0] = fmaf(a3, v0, acc[3][0]); acc[3][1] = fmaf(a3, v1, acc[3][1]);
            acc[3][2] = fmaf(a3, v2, acc[3][2]); acc[3][3] = fmaf(a3, v3, acc[3][3]);
        }
        __syncthreads();
    }
    {
        int ty = tid >> 4;
        int tx = tid & 15;
        #pragma unroll
        for (int i = 0; i < 4; i++) {
            int m = mblk + ty * 4 + i;           // global row
            int mloc = m & (NROW - 1);           // within-branch row
            #pragma unroll
            for (int j = 0; j < 4; j++) {
                int n = nblk + tx * 4 + j;       // d
                float delta = softplusf(acc[i][j] + bias[n]);
                float u = xs[(size_t)m * 256 + n];
                size_t dst = ((size_t)br * 256 + n) * 4096 + mloc;
                dtT[dst] = delta * LOG2E;
                duT[dst] = delta * u;
                udT[dst] = u * Dvec[n];
            }
        }
    }
    // ---- shrink slice: 64 rows x 64 cols of Bc or Cc ----
    {
        int q = blockIdx.x;                      // 0..3
        int isC = q >> 1;
        int cbase = (q & 1) * 64;                // col offset within 128
        int xoff = isC ? (160 + cbase) : (32 + cbase);
        float thr = 0.1f * funkey(bcmax[2 * br + isC]);
        float* dstArr = isC ? Cs : Bs;
        int r = tid >> 2;                        // 0..63
        int c0 = (tid & 3) * 16;                 // 0,16,32,48
        const float* src = A + (size_t)(mblk + r) * lda + xoff + c0;
        float* dp = dstArr + (size_t)(mblk + r) * 128 + cbase + c0;
        #pragma unroll
        for (int i = 0; i < 16; i += 4) {
            float4 v = *(const float4*)(src + i);
            float4 o;
            o.x = shrinkf(v.x, thr);
            o.y = shrinkf(v.y, thr);
            o.z = shrinkf(v.z, thr);
            o.w = shrinkf(v.w, thr);
            *(float4*)(dp + i) = o;
        }
    }
}

// ---------------- selective scan (v3 structure; computes A on the fly) ----------------
__global__ __launch_bounds__(128) void scan3_kernel(float* __restrict__ ws,
                                                    const float* __restrict__ A_log,
                                                    const float* __restrict__ eps) {
    int blk  = blockIdx.x;
    int xcd  = blk & 7;
    int slot = blk >> 3;
    int combo = xcd >> 1;
    int d  = (xcd & 1) * 128 + slot;
    int br = combo >> 1;
    int b  = combo & 1;
    int tid = threadIdx.x;
    int lt  = tid & 63;

    float pv = ws[OFF_MINP + (tid & 31)];
    #pragma unroll
    for (int off = 16; off > 0; off >>= 1) pv = fminf(pv, __shfl_xor(pv, off));
    float e  = 1.0f + eps[0];
    float m1 = -e * __expf(pv);
    float t1 = 0.1f * m1;
    float t2 = 0.1f * shrinkf(m1, t1);
    float base = -e * __expf(A_log[d * 128 + tid]);
    float a = shrinkf(base, t1);
    if (br) a = shrinkf(a, t2);

    size_t dchain = ((size_t)br * 256 + d) * 4096 + (size_t)b * L_;
    const float* dtT = ws + OFF_DTT + dchain;
    const float* duT = ws + OFF_DUT + dchain;
    const float* udT = ws + OFF_UDT + dchain;
    const float* Bp  = ws + OFF_BS + ((size_t)br * NROW + (size_t)b * L_) * 128 + tid;
    const float* Cp  = ws + OFF_CS + ((size_t)br * NROW + (size_t)b * L_) * 128 + tid;
    float*       yTp = ws + OFF_YT + dchain;

    __shared__ float red[64 * 132];
    __shared__ float comb[64];

    float h = 0.0f;

    float Bb[2][8], Cb[2][8];
    float dt_c = dtT[lt];
    float du_c = duT[lt];
    float ud_c = udT[lt];
    float dt_n = 0.f, du_n = 0.f, ud_n = 0.f;
    #pragma unroll
    for (int j = 0; j < 8; j++) { Bb[0][j] = Bp[(size_t)j * 128];       Cb[0][j] = Cp[(size_t)j * 128]; }
    #pragma unroll
    for (int j = 0; j < 8; j++) { Bb[1][j] = Bp[(size_t)(8 + j) * 128]; Cb[1][j] = Cp[(size_t)(8 + j) * 128]; }

    for (int c = 0; c < 32; c++) {
        if (c < 31) {
            dt_n = dtT[(c + 1) * 64 + lt];
            du_n = duT[(c + 1) * 64 + lt];
            ud_n = udT[(c + 1) * 64 + lt];
        }
        #pragma unroll
        for (int m = 0; m < 8; m++) {
            const int cur = m & 1;
            #pragma unroll
            for (int j = 0; j < 8; j++) {
                const int tl = m * 8 + j;
                float dt2 = rlanef(dt_c, tl);
                float du  = rlanef(du_c, tl);
                float ev = __builtin_amdgcn_exp2f(dt2 * a);
                h = fmaf(ev, h, du * Bb[cur][j]);
                red[tl * 132 + tid] = h * Cb[cur][j];
            }
            int nb = c * 8 + m + 2;
            if (nb < 256) {
                #pragma unroll
                for (int j = 0; j < 8; j++) {
                    Bb[cur][j] = Bp[((size_t)nb * 8 + j) * 128];
                    Cb[cur][j] = Cp[((size_t)nb * 8 + j) * 128];
                }
            }
        }
        __syncthreads();
        {
            const float* rp = &red[(tid & 63) * 132 + (tid >> 6) * 64];
            float s0 = 0.f, s1 = 0.f, s2 = 0.f, s3 = 0.f;
            #pragma unroll
            for (int i = 0; i < 64; i += 4) {
                float4 v = *(const float4*)(rp + i);
                s0 += v.x; s1 += v.y; s2 += v.z; s3 += v.w;
            }
            float part = (s0 + s1) + (s2 + s3);
            if (tid >= 64) comb[tid - 64] = part;
            __syncthreads();
            if (tid < 64) yTp[c * 64 + tid] = part + comb[tid] + ud_c;
        }
        __syncthreads();
        dt_c = dt_n;
        du_c = du_n;
        ud_c = ud_n;
    }
}

// ---------------- yT -> yz bf16 split (y half), merged: grid (8, 128, 2) ----------------
__global__ __launch_bounds__(256) void transpose_yz_kernel(const float* __restrict__ yT,
                                                           unsigned short* __restrict__ yzh,
                                                           unsigned short* __restrict__ yzl) {
    __shared__ float tile[32][33];
    int br = blockIdx.z;
    int m0 = blockIdx.x * 32;   // d rows
    int n0 = blockIdx.y * 32;   // within-branch t cols
    int tx = threadIdx.x;
    int ty = threadIdx.y;
    #pragma unroll
    for (int k = 0; k < 4; k++) {
        tile[ty + 8 * k][tx] = yT[((size_t)br * 256 + m0 + ty + 8 * k) * 4096 + n0 + tx];
    }
    __syncthreads();
    #pragma unroll
    for (int k = 0; k < 4; k++) {
        size_t dst = ((size_t)br * NROW + n0 + ty + 8 * k) * 512 + m0 + tx;
        unsigned short h, l;
        split2(tile[tx][ty + 8 * k], h, l);
        yzh[dst] = h; yzl[dst] = l;
    }
}

// ---------------- host-side launch ----------------
extern "C" void kernel_launch(void* const* d_in, const int* in_sizes, int n_in,
                              void* d_out, int out_size, void* d_ws, size_t ws_size,
                              hipStream_t stream) {
    const float* inp   = (const float*)d_in[0];
    const float* in_w[2]  = {(const float*)d_in[1],  (const float*)d_in[8]};
    const float* cxw[2]   = {(const float*)d_in[2],  (const float*)d_in[9]};
    const float* czw[2]   = {(const float*)d_in[3],  (const float*)d_in[10]};
    const float* xw[2]    = {(const float*)d_in[4],  (const float*)d_in[11]};
    const float* dtw[2]   = {(const float*)d_in[5],  (const float*)d_in[12]};
    const float* dtb[2]   = {(const float*)d_in[6],  (const float*)d_in[13]};
    const float* outw[2]  = {(const float*)d_in[7],  (const float*)d_in[14]};
    const float* A_log = (const float*)d_in[15];
    const float* Dvec  = (const float*)d_in[16];
    const float* eps   = (const float*)d_in[17];
    float* out = (float*)d_out;
    float* ws  = (float*)d_ws;
    unsigned short* hb = (unsigned short*)(ws + FLOAT_END);
    unsigned* bcmax = (unsigned*)(ws + OFF_BCMX);

    // 1) minA + weight splits + input transpose, one dispatch
    pre_all<<<PRE_BLOCKS, 256, 0, stream>>>(
        A_log, inp, in_w[0], in_w[1], outw[0], outw[1], xw[0], xw[1],
        ws, bcmax, hb);

    // 2) in_proj (merged M=8192): xz = xin * in_w^T
    gemm_mfma<0, 0><<<dim3(512 / 64, MROW / 128), 256, 0, stream>>>(
        hb + HOFF_XINH, hb + HOFF_XINL, 512,
        hb + HOFF_INWH, hb + HOFF_INWL, WST_IN,
        ws + OFF_XZ, 512, 512, 512, nullptr);

    // 3) conv + silu (+ bf16 splits for x_proj / out_proj z-half)
    conv_silu_kernel<<<(MROW * HALF_) / 256, 256, 0, stream>>>(
        ws + OFF_XZ, ws + OFF_XS, hb + HOFF_XSH, hb + HOFF_XSL,
        hb + HOFF_YZH, hb + HOFF_YZL, cxw[0], cxw[1], czw[0], czw[1]);

    // 4) x_proj (merged): xdbl = xs * xw^T, with fused B/C signed-max atomics
    gemm_mfma<1, 1><<<dim3((288 + 63) / 64, MROW / 128), 256, 0, stream>>>(
        hb + HOFF_XSH, hb + HOFF_XSL, 256,
        hb + HOFF_XWH, hb + HOFF_XWL, WST_X,
        ws + OFF_XDBL, 288, 288, 256, bcmax);

    // 5) dt_proj + softplus + prep + shrinkpack (one dispatch)
    dtprep_shrink<<<dim3(4, MROW / 64), 256, 0, stream>>>(
        ws + OFF_XDBL, 288, dtw[0], dtw[1], dtb[0], dtb[1],
        ws + OFF_XS, Dvec,
        ws + OFF_DTT, ws + OFF_DUT, ws + OFF_UDT,
        bcmax, ws + OFF_BS, ws + OFF_CS);

    // 6) scan
    scan3_kernel<<<dim3(1024), 128, 0, stream>>>(ws, A_log, eps);

    // 7) yT -> yz bf16 split
    transpose_yz_kernel<<<dim3(256 / 32, NROW / 32, 2), dim3(32, 8), 0, stream>>>(
        ws + OFF_YT, hb + HOFF_YZH, hb + HOFF_YZL);

    // 8) out_proj (merged): d_out = yz * out_w^T
    gemm_mfma<0, 0><<<dim3(512 / 64, MROW / 128), 256, 0, stream>>>(
        hb + HOFF_YZH, hb + HOFF_YZL, 512,
        hb + HOFF_OUTWH, hb + HOFF_OUTWL, WST_IN,
        out, 512, 512, 512, nullptr);
}

// Round 9
// 325.951 us; speedup vs baseline: 2.8430x; 1.0465x over previous
//
#include <hip/hip_runtime.h>
#include <math.h>

// ---------------- problem constants ----------------
constexpr int B_    = 2;
constexpr int L_    = 2048;
constexpr int NROW  = B_ * L_;     // 4096 rows per branch
constexpr int MROW  = 2 * NROW;    // 8192 merged rows (branch-major)
constexpr int HALF_ = 256;
constexpr int DS_   = 128;

constexpr float LOG2E = 1.4426950408889634f;

// ---------------- ws layout ----------------
// fp32 region (float element offsets)
constexpr size_t OFF_MINP = 0;                                    // 32 (minA partials)
constexpr size_t OFF_BCMX = 32;                                   // 4 (uint atomics: brB,brC x2)
constexpr size_t OFF_XZ   = 64;                                   // 8192x512 (transient)
constexpr size_t OFF_YT   = OFF_XZ + (size_t)MROW * 256;          // alias: 2x256x4096 (after conv)
constexpr size_t OFF_XDBL = OFF_XZ + (size_t)MROW * 512;          // 8192x288
constexpr size_t OFF_XS   = OFF_XDBL + (size_t)MROW * 288;        // 8192x256
constexpr size_t OFF_BS   = OFF_XS  + (size_t)MROW * 256;         // 2 x 4096x128
constexpr size_t OFF_CS   = OFF_BS  + (size_t)2 * NROW * 128;     // 2 x 4096x128
constexpr size_t OFF_DTT  = OFF_CS  + (size_t)2 * NROW * 128;     // 2 x 256x4096
constexpr size_t OFF_DUT  = OFF_DTT + (size_t)2 * 256 * 4096;
constexpr size_t OFF_UDT  = OFF_DUT + (size_t)2 * 256 * 4096;
constexpr size_t FLOAT_END = OFF_UDT + (size_t)2 * 256 * 4096;

// bf16 region (ushort element offsets, based at ws + FLOAT_END floats)
constexpr size_t HOFF_XINH = 0;                                   // 8192x512
constexpr size_t HOFF_XINL = HOFF_XINH + (size_t)MROW * 512;
constexpr size_t HOFF_YZH  = HOFF_XINH;                           // alias (xin dead after in_proj)
constexpr size_t HOFF_YZL  = HOFF_XINL;
constexpr size_t HOFF_XSH  = HOFF_XINL + (size_t)MROW * 512;      // 8192x256
constexpr size_t HOFF_XSL  = HOFF_XSH  + (size_t)MROW * 256;
constexpr size_t HOFF_INWH = HOFF_XSL  + (size_t)MROW * 256;      // 2 x 512x512
constexpr size_t HOFF_INWL = HOFF_INWH + 524288;
constexpr size_t HOFF_XWH  = HOFF_INWL + 524288;                  // 2 x 288x256
constexpr size_t HOFF_XWL  = HOFF_XWH  + 147456;
constexpr size_t HOFF_OUTWH= HOFF_XWL  + 147456;                  // 2 x 512x512
constexpr size_t HOFF_OUTWL= HOFF_OUTWH+ 524288;

constexpr size_t WST_IN = 262144;   // per-branch in/out weight elems
constexpr size_t WST_X  = 73728;    // per-branch x_proj weight elems

// pre_all block ranges
constexpr int PRE_MINA = 32;
constexpr int PRE_WSPL = (1196032 + 255) / 256;   // 4672
constexpr int PRE_TIN  = 64 * 16 * 4;             // 4096
constexpr int PRE_BLOCKS = PRE_MINA + PRE_WSPL + PRE_TIN;

// ---------------- types / helpers ----------------
typedef __bf16 bf16x8 __attribute__((ext_vector_type(8)));
typedef float  f32x4  __attribute__((ext_vector_type(4)));

__device__ __forceinline__ unsigned short bf16rn(float x) {
    unsigned u = __float_as_uint(x);
    unsigned r = (u + 0x7FFFu + ((u >> 16) & 1u)) >> 16;
    return (unsigned short)r;
}
__device__ __forceinline__ void split2(float x, unsigned short& h, unsigned short& l) {
    h = bf16rn(x);
    float hf = __uint_as_float(((unsigned)h) << 16);
    l = bf16rn(x - hf);
}

__device__ __forceinline__ float shrinkf(float v, float thr) {
    float a = fabsf(v) - thr;
    a = fmaxf(a, 0.0f);
    float r = copysignf(a, v);
    return (v == 0.0f) ? 0.0f : r;
}
__device__ __forceinline__ float siluf(float v) { return v / (1.0f + __expf(-v)); }
__device__ __forceinline__ float softplusf(float v) {
    return fmaxf(v, 0.0f) + log1pf(__expf(-fabsf(v)));
}
__device__ __forceinline__ float rlanef(float v, int l) {
    return __int_as_float(__builtin_amdgcn_readlane(__float_as_int(v), l));
}
// monotone float<->uint key for atomicMax on signed floats
__device__ __forceinline__ unsigned fkey(float f) {
    unsigned u = __float_as_uint(f);
    return (u >> 31) ? ~u : (u | 0x80000000u);
}
__device__ __forceinline__ float funkey(unsigned k) {
    unsigned u = (k >> 31) ? (k & 0x7FFFFFFFu) : ~k;
    return __uint_as_float(u);
}

// ---------------- pre_all: minA + weight splits + input transpose, one dispatch ----------------
__global__ __launch_bounds__(256) void pre_all(const float* __restrict__ A_log,
                                               const float* __restrict__ inp,
                                               const float* __restrict__ in_w0,
                                               const float* __restrict__ in_w1,
                                               const float* __restrict__ outw0,
                                               const float* __restrict__ outw1,
                                               const float* __restrict__ xw0,
                                               const float* __restrict__ xw1,
                                               float* __restrict__ ws,
                                               unsigned* __restrict__ bcmax,
                                               unsigned short* __restrict__ hb) {
    int bid = blockIdx.x;
    int tid = threadIdx.x;
    if (bid < PRE_MINA) {
        // ---- minA role ----
        __shared__ float sbuf[8];
        int i = bid * 1024 + tid * 4;
        float4 v = *(const float4*)(A_log + i);
        float mv = fminf(fminf(v.x, v.y), fminf(v.z, v.w));
        #pragma unroll
        for (int off = 32; off > 0; off >>= 1) mv = fminf(mv, __shfl_xor(mv, off));
        if ((tid & 63) == 0) sbuf[tid >> 6] = mv;
        __syncthreads();
        if (tid == 0) {
            float r = fminf(fminf(sbuf[0], sbuf[1]), fminf(sbuf[2], sbuf[3]));
            ws[OFF_MINP + bid] = r;
        }
        if (bid == 0 && tid < 4) bcmax[tid] = 0u;
    } else if (bid < PRE_MINA + PRE_WSPL) {
        // ---- wsplit role ----
        int i = (bid - PRE_MINA) * 256 + tid;
        if (i >= 1196032) return;
        const float* src;
        size_t hbase, lbase;
        int off;
        if (i < 1048576) {
            int t = i >> 18;
            off = i & 262143;
            src = (t == 0) ? in_w0 : (t == 1) ? in_w1 : (t == 2) ? outw0 : outw1;
            if (t < 2) { hbase = HOFF_INWH + (size_t)t * WST_IN;  lbase = HOFF_INWL + (size_t)t * WST_IN; }
            else       { hbase = HOFF_OUTWH + (size_t)(t - 2) * WST_IN; lbase = HOFF_OUTWL + (size_t)(t - 2) * WST_IN; }
        } else {
            int j = i - 1048576;
            int t = (j < (int)WST_X) ? 0 : 1;
            off = j - t * (int)WST_X;
            src = t ? xw1 : xw0;
            hbase = HOFF_XWH + (size_t)t * WST_X;
            lbase = HOFF_XWL + (size_t)t * WST_X;
        }
        unsigned short h, l;
        split2(src[off], h, l);
        hb[hbase + off] = h;
        hb[lbase + off] = l;
    } else {
        // ---- transpose_in role ----
        __shared__ float tile[32][33];
        int idx = bid - PRE_MINA - PRE_WSPL;    // 0..4095
        int bx = idx & 63;          // t block (64)
        int by = (idx >> 6) & 15;   // ch block (16)
        int z  = idx >> 10;         // 0..3
        int br = z >> 1;
        int b  = z & 1;
        int t0 = bx * 32;
        int m0 = by * 32;
        int tx = tid & 31;
        int ty = tid >> 5;
        #pragma unroll
        for (int k = 0; k < 4; k++) {
            tile[ty + 8 * k][tx] =
                inp[((size_t)b * 1024 + br * 512 + m0 + ty + 8 * k) * L_ + t0 + tx];
        }
        __syncthreads();
        #pragma unroll
        for (int k = 0; k < 4; k++) {
            size_t dst = ((size_t)br * NROW + (size_t)b * L_ + t0 + ty + 8 * k) * 512 + m0 + tx;
            unsigned short h, l;
            split2(tile[tx][ty + 8 * k], h, l);
            hb[HOFF_XINH + dst] = h;
            hb[HOFF_XINL + dst] = l;
        }
    }
}

// ---------------- MFMA GEMM (bf16x3) with register prefetch ----------------
// 128x64 tile, BK=32, 256 thr. Next K-chunk preloaded into registers right after
// the second barrier -> global latency overlaps the 24-MFMA compute phase.
template <int NGUARD, int DOMAX>
__global__ __launch_bounds__(256) void gemm_mfma(const unsigned short* __restrict__ Ah,
                                                 const unsigned short* __restrict__ Al, int lda,
                                                 const unsigned short* __restrict__ WhB,
                                                 const unsigned short* __restrict__ WlB,
                                                 size_t wstride,
                                                 float* __restrict__ C, int ldc,
                                                 int N, int K,
                                                 unsigned* __restrict__ bcmax) {
    __shared__ __align__(16) unsigned short sAh[128 * 40];
    __shared__ __align__(16) unsigned short sAl[128 * 40];
    __shared__ __align__(16) unsigned short sBh[64 * 40];
    __shared__ __align__(16) unsigned short sBl[64 * 40];
    int tid  = threadIdx.x;
    int wid  = tid >> 6;
    int lane = tid & 63;
    int fr   = lane & 15;
    int kg   = lane >> 4;
    int mblk = blockIdx.y * 128;
    int nblk = blockIdx.x * 64;
    int br   = (mblk >= NROW) ? 1 : 0;
    const unsigned short* Wh = WhB + (size_t)br * wstride;
    const unsigned short* Wl = WlB + (size_t)br * wstride;
    int srow = tid >> 2;            // 0..63
    int skp  = (tid & 3) * 8;       // k-chunk of 8
    bool brow_ok = (!NGUARD) || ((nblk + srow) < N);

    const unsigned short* pA0 = Ah + (size_t)(mblk + srow) * lda + skp;
    const unsigned short* pA1 = Ah + (size_t)(mblk + 64 + srow) * lda + skp;
    const unsigned short* pL0 = Al + (size_t)(mblk + srow) * lda + skp;
    const unsigned short* pL1 = Al + (size_t)(mblk + 64 + srow) * lda + skp;
    const unsigned short* pBh = Wh + (size_t)(nblk + srow) * K + skp;
    const unsigned short* pBl = Wl + (size_t)(nblk + srow) * K + skp;

    f32x4 acc[2][4] = {};

    uint4 rah0 = *(const uint4*)(pA0);
    uint4 rah1 = *(const uint4*)(pA1);
    uint4 ral0 = *(const uint4*)(pL0);
    uint4 ral1 = *(const uint4*)(pL1);
    uint4 rbh = {0, 0, 0, 0}, rbl = {0, 0, 0, 0};
    if (brow_ok) {
        rbh = *(const uint4*)(pBh);
        rbl = *(const uint4*)(pBl);
    }

    for (int k0 = 0; k0 < K; k0 += 32) {
        __syncthreads();   // WAR vs previous iter's ds_reads
        *(uint4*)(sAh + srow * 40 + skp) = rah0;
        *(uint4*)(sAh + (64 + srow) * 40 + skp) = rah1;
        *(uint4*)(sAl + srow * 40 + skp) = ral0;
        *(uint4*)(sAl + (64 + srow) * 40 + skp) = ral1;
        *(uint4*)(sBh + srow * 40 + skp) = rbh;
        *(uint4*)(sBl + srow * 40 + skp) = rbl;
        __syncthreads();

        int kn = k0 + 32;
        if (kn < K) {      // prefetch next chunk; latency hides under MFMAs below
            rah0 = *(const uint4*)(pA0 + kn);
            rah1 = *(const uint4*)(pA1 + kn);
            ral0 = *(const uint4*)(pL0 + kn);
            ral1 = *(const uint4*)(pL1 + kn);
            if (brow_ok) {
                rbh = *(const uint4*)(pBh + kn);
                rbl = *(const uint4*)(pBl + kn);
            }
        }

        bf16x8 ah0 = *(const bf16x8*)(sAh + (wid * 32 + fr) * 40 + kg * 8);
        bf16x8 ah1 = *(const bf16x8*)(sAh + (wid * 32 + 16 + fr) * 40 + kg * 8);
        bf16x8 al0 = *(const bf16x8*)(sAl + (wid * 32 + fr) * 40 + kg * 8);
        bf16x8 al1 = *(const bf16x8*)(sAl + (wid * 32 + 16 + fr) * 40 + kg * 8);
        #pragma unroll
        for (int nt = 0; nt < 4; nt++) {
            bf16x8 bh = *(const bf16x8*)(sBh + (nt * 16 + fr) * 40 + kg * 8);
            bf16x8 bl = *(const bf16x8*)(sBl + (nt * 16 + fr) * 40 + kg * 8);
            acc[0][nt] = __builtin_amdgcn_mfma_f32_16x16x32_bf16(ah0, bh, acc[0][nt], 0, 0, 0);
            acc[0][nt] = __builtin_amdgcn_mfma_f32_16x16x32_bf16(ah0, bl, acc[0][nt], 0, 0, 0);
            acc[0][nt] = __builtin_amdgcn_mfma_f32_16x16x32_bf16(al0, bh, acc[0][nt], 0, 0, 0);
            acc[1][nt] = __builtin_amdgcn_mfma_f32_16x16x32_bf16(ah1, bh, acc[1][nt], 0, 0, 0);
            acc[1][nt] = __builtin_amdgcn_mfma_f32_16x16x32_bf16(ah1, bl, acc[1][nt], 0, 0, 0);
            acc[1][nt] = __builtin_amdgcn_mfma_f32_16x16x32_bf16(al1, bh, acc[1][nt], 0, 0, 0);
        }
    }
    // C/D layout: col = lane&15, row = (lane>>4)*4 + reg
    #pragma unroll
    for (int mt = 0; mt < 2; mt++) {
        #pragma unroll
        for (int nt = 0; nt < 4; nt++) {
            int col = nblk + nt * 16 + fr;
            if (NGUARD && col >= N) continue;
            #pragma unroll
            for (int r = 0; r < 4; r++) {
                int row = mblk + wid * 32 + mt * 16 + kg * 4 + r;
                C[(size_t)row * ldc + col] = acc[mt][nt][r];
            }
        }
    }
    if (DOMAX) {
        float mb = -INFINITY, mc = -INFINITY;
        #pragma unroll
        for (int nt = 0; nt < 4; nt++) {
            int c16 = nblk + nt * 16;
            if (c16 >= 32 && c16 < 160) {
                #pragma unroll
                for (int mt = 0; mt < 2; mt++)
                    #pragma unroll
                    for (int r = 0; r < 4; r++) mb = fmaxf(mb, acc[mt][nt][r]);
            } else if (c16 >= 160 && c16 < 288) {
                #pragma unroll
                for (int mt = 0; mt < 2; mt++)
                    #pragma unroll
                    for (int r = 0; r < 4; r++) mc = fmaxf(mc, acc[mt][nt][r]);
            }
        }
        #pragma unroll
        for (int off = 32; off > 0; off >>= 1) {
            mb = fmaxf(mb, __shfl_xor(mb, off));
            mc = fmaxf(mc, __shfl_xor(mc, off));
        }
        if (lane == 0) {
            if (mb > -INFINITY) atomicMax(bcmax + 2 * br,     fkey(mb));
            if (mc > -INFINITY) atomicMax(bcmax + 2 * br + 1, fkey(mc));
        }
    }
}

// ---------------- depthwise conv (k=4) + SiLU, vectorized 4 channels/thread ----------------
__global__ __launch_bounds__(256) void conv_silu_kernel(const float* __restrict__ xz,
                                                        float* __restrict__ xs,
                                                        unsigned short* __restrict__ xsh,
                                                        unsigned short* __restrict__ xsl,
                                                        unsigned short* __restrict__ yzh,
                                                        unsigned short* __restrict__ yzl,
                                                        const float* __restrict__ wx0,
                                                        const float* __restrict__ wx1,
                                                        const float* __restrict__ wz0,
                                                        const float* __restrict__ wz1) {
    int gid = blockIdx.x * 256 + threadIdx.x;   // over MROW*64
    int c4  = (gid & 63) << 2;                  // channel quad
    int row = gid >> 6;                         // global row 0..8191
    int br  = row >> 12;
    int t   = row & (L_ - 1);
    const float* wx = br ? wx1 : wx0;
    const float* wz = br ? wz1 : wz0;
    // per-channel taps (w[c][0..3] is exactly a float4)
    float4 wxv[4], wzv[4];
    #pragma unroll
    for (int k = 0; k < 4; k++) {
        wxv[k] = *(const float4*)(wx + (c4 + k) * 4);
        wzv[k] = *(const float4*)(wz + (c4 + k) * 4);
    }
    float4 ax = {0, 0, 0, 0}, az = {0, 0, 0, 0};
    #pragma unroll
    for (int j = 0; j < 4; j++) {
        int tt = t + j - 1;
        if (tt >= 0 && tt < L_) {
            const float* p = xz + (size_t)(row + j - 1) * 512;
            float4 vx = *(const float4*)(p + c4);
            float4 vz = *(const float4*)(p + 256 + c4);
            ax.x = fmaf(vx.x, ((const float*)&wxv[0])[j], ax.x);
            ax.y = fmaf(vx.y, ((const float*)&wxv[1])[j], ax.y);
            ax.z = fmaf(vx.z, ((const float*)&wxv[2])[j], ax.z);
            ax.w = fmaf(vx.w, ((const float*)&wxv[3])[j], ax.w);
            az.x = fmaf(vz.x, ((const float*)&wzv[0])[j], az.x);
            az.y = fmaf(vz.y, ((const float*)&wzv[1])[j], az.y);
            az.z = fmaf(vz.z, ((const float*)&wzv[2])[j], az.z);
            az.w = fmaf(vz.w, ((const float*)&wzv[3])[j], az.w);
        }
    }
    float4 sx, sz;
    sx.x = siluf(ax.x); sx.y = siluf(ax.y); sx.z = siluf(ax.z); sx.w = siluf(ax.w);
    sz.x = siluf(az.x); sz.y = siluf(az.y); sz.z = siluf(az.z); sz.w = siluf(az.w);
    *(float4*)(xs + (size_t)row * 256 + c4) = sx;
    ushort4 hx, lx, hz, lz;
    split2(sx.x, hx.x, lx.x); split2(sx.y, hx.y, lx.y);
    split2(sx.z, hx.z, lx.z); split2(sx.w, hx.w, lx.w);
    split2(sz.x, hz.x, lz.x); split2(sz.y, hz.y, lz.y);
    split2(sz.z, hz.z, lz.z); split2(sz.w, hz.w, lz.w);
    *(ushort4*)(xsh + (size_t)row * 256 + c4) = hx;
    *(ushort4*)(xsl + (size_t)row * 256 + c4) = lx;
    *(ushort4*)(yzh + (size_t)row * 512 + 256 + c4) = hz;
    *(ushort4*)(yzl + (size_t)row * 512 + 256 + c4) = lz;
}

// ---------------- fused dt_proj(K=32)+softplus+prep + shrinkpack ----------------
// grid (4, MROW/64). d-major outputs staged through LDS -> coalesced float4 stores.
__global__ __launch_bounds__(256) void dtprep_shrink(const float* __restrict__ A, int lda,
                                                     const float* __restrict__ W0,
                                                     const float* __restrict__ W1,
                                                     const float* __restrict__ b0,
                                                     const float* __restrict__ b1,
                                                     const float* __restrict__ xs,
                                                     const float* __restrict__ Dvec,
                                                     float* __restrict__ dtT,
                                                     float* __restrict__ duT,
                                                     float* __restrict__ udT,
                                                     const unsigned* __restrict__ bcmax,
                                                     float* __restrict__ Bs,
                                                     float* __restrict__ Cs) {
    __shared__ float As[16][68];
    __shared__ float Ws[16][68];
    __shared__ float tb[64 * 68];   // transpose buffer [n][m], stride 68 (16B-aligned rows)
    int tid = threadIdx.x;
    int kk = tid & 15;
    int rr = tid >> 4;
    int mblk = blockIdx.y * 64;
    int nblk = blockIdx.x * 64;
    int br = (mblk >= NROW) ? 1 : 0;
    const float* W    = br ? W1 : W0;
    const float* bias = br ? b1 : b0;
    float acc[4][4] = {};
    for (int k0 = 0; k0 < 32; k0 += 16) {
        #pragma unroll
        for (int j = 0; j < 4; j++) {
            As[kk][rr + 16 * j] = A[(size_t)(mblk + rr + 16 * j) * lda + k0 + kk];
        }
        #pragma unroll
        for (int j = 0; j < 4; j++) {
            Ws[kk][rr + 16 * j] = W[(size_t)(nblk + rr + 16 * j) * 32 + k0 + kk];
        }
        __syncthreads();
        int ty = tid >> 4;
        int tx = tid & 15;
        #pragma unroll
        for (int kq = 0; kq < 16; kq++) {
            float a0 = As[kq][ty * 4 + 0];
            float a1 = As[kq][ty * 4 + 1];
            float a2 = As[kq][ty * 4 + 2];
            float a3 = As[kq][ty * 4 + 3];
            float v0 = Ws[kq][tx * 4 + 0];
            float v1 = Ws[kq][tx * 4 + 1];
            float v2 = Ws[kq][tx * 4 + 2];
            float v3 = Ws[kq][tx * 4 + 3];
            acc[0][0] = fmaf(a0, v0, acc[0][0]); acc[0][1] = fmaf(a0, v1, acc[0][1]);
            acc[0][2] = fmaf(a0, v2, acc[0][2]); acc[0][3] = fmaf(a0, v3, acc[0][3]);
            acc[1][0] = fmaf(a1, v0, acc[1][0]); acc[1][1] = fmaf(a1, v1, acc[1][1]);
            acc[1][2] = fmaf(a1, v2, acc[1][2]); acc[1][3] = fmaf(a1, v3, acc[1][3]);
            acc[2][0] = fmaf(a2, v0, acc[2][0]); acc[2][1] = fmaf(a2, v1, acc[2][1]);
            acc[2][2] = fmaf(a2, v2, acc[2][2]); acc[2][3] = fmaf(a2, v3, acc[2][3]);
            acc[3][0] = fmaf(a3, v0, acc[3][0]); acc[3][1] = fmaf(a3, v1, acc[3][1]);
            acc[3][2] = fmaf(a3, v2, acc[3][2]); acc[3][3] = fmaf(a3, v3, acc[3][3]);
        }
        __syncthreads();
    }
    // epilogue: delta/u per (i,j); three d-major tensors via LDS transpose
    int ty = tid >> 4;
    int tx = tid & 15;
    float dlt[4][4], uu[4][4];
    #pragma unroll
    for (int i = 0; i < 4; i++) {
        int m = mblk + ty * 4 + i;
        #pragma unroll
        for (int j = 0; j < 4; j++) {
            int n = nblk + tx * 4 + j;
            dlt[i][j] = softplusf(acc[i][j] + bias[n]);
            uu[i][j]  = xs[(size_t)m * 256 + n];
        }
    }
    float Dv[4];
    #pragma unroll
    for (int j = 0; j < 4; j++) Dv[j] = Dvec[nblk + tx * 4 + j];

    int mlocbase = mblk & (NROW - 1);
    int nrd  = tid >> 2;              // 0..63: n-row to read
    int mc   = (tid & 3) * 4;         // starting float4 chunk
    size_t obase = ((size_t)br * 256 + nblk + nrd) * 4096 + mlocbase;
    #pragma unroll
    for (int pass = 0; pass < 3; pass++) {
        __syncthreads();   // WAR vs previous pass reads
        #pragma unroll
        for (int i = 0; i < 4; i++) {
            #pragma unroll
            for (int j = 0; j < 4; j++) {
                float v = (pass == 0) ? dlt[i][j] * LOG2E
                        : (pass == 1) ? dlt[i][j] * uu[i][j]
                                      : uu[i][j] * Dv[j];
                tb[(tx * 4 + j) * 68 + ty * 4 + i] = v;
            }
        }
        __syncthreads();
        float* dst = (pass == 0) ? dtT : (pass == 1) ? duT : udT;
        #pragma unroll
        for (int it = 0; it < 4; it++) {
            int cc = mc + it * 16;    // wait: cover 16 float4 chunks per n-row
            float4 v = *(const float4*)(tb + nrd * 68 + cc);
            *(float4*)(dst + obase + cc) = v;
        }
    }
    // ---- shrink slice: 64 rows x 64 cols of Bc or Cc ----
    {
        int q = blockIdx.x;
        int isC = q >> 1;
        int cbase = (q & 1) * 64;
        int xoff = isC ? (160 + cbase) : (32 + cbase);
        float thr = 0.1f * funkey(bcmax[2 * br + isC]);
        float* dstArr = isC ? Cs : Bs;
        int r = tid >> 2;
        int c0 = (tid & 3) * 16;
        const float* src = A + (size_t)(mblk + r) * lda + xoff + c0;
        float* dp = dstArr + (size_t)(mblk + r) * 128 + cbase + c0;
        #pragma unroll
        for (int i = 0; i < 16; i += 4) {
            float4 v = *(const float4*)(src + i);
            float4 o;
            o.x = shrinkf(v.x, thr);
            o.y = shrinkf(v.y, thr);
            o.z = shrinkf(v.z, thr);
            o.w = shrinkf(v.w, thr);
            *(float4*)(dp + i) = o;
        }
    }
}

// ---------------- selective scan (v3 structure; computes A on the fly) ----------------
__global__ __launch_bounds__(128) void scan3_kernel(float* __restrict__ ws,
                                                    const float* __restrict__ A_log,
                                                    const float* __restrict__ eps) {
    int blk  = blockIdx.x;
    int xcd  = blk & 7;
    int slot = blk >> 3;
    int combo = xcd >> 1;
    int d  = (xcd & 1) * 128 + slot;
    int br = combo >> 1;
    int b  = combo & 1;
    int tid = threadIdx.x;
    int lt  = tid & 63;

    float pv = ws[OFF_MINP + (tid & 31)];
    #pragma unroll
    for (int off = 16; off > 0; off >>= 1) pv = fminf(pv, __shfl_xor(pv, off));
    float e  = 1.0f + eps[0];
    float m1 = -e * __expf(pv);
    float t1 = 0.1f * m1;
    float t2 = 0.1f * shrinkf(m1, t1);
    float base = -e * __expf(A_log[d * 128 + tid]);
    float a = shrinkf(base, t1);
    if (br) a = shrinkf(a, t2);

    size_t dchain = ((size_t)br * 256 + d) * 4096 + (size_t)b * L_;
    const float* dtT = ws + OFF_DTT + dchain;
    const float* duT = ws + OFF_DUT + dchain;
    const float* udT = ws + OFF_UDT + dchain;
    const float* Bp  = ws + OFF_BS + ((size_t)br * NROW + (size_t)b * L_) * 128 + tid;
    const float* Cp  = ws + OFF_CS + ((size_t)br * NROW + (size_t)b * L_) * 128 + tid;
    float*       yTp = ws + OFF_YT + dchain;

    __shared__ float red[64 * 132];
    __shared__ float comb[64];

    float h = 0.0f;

    float Bb[2][8], Cb[2][8];
    float dt_c = dtT[lt];
    float du_c = duT[lt];
    float ud_c = udT[lt];
    float dt_n = 0.f, du_n = 0.f, ud_n = 0.f;
    #pragma unroll
    for (int j = 0; j < 8; j++) { Bb[0][j] = Bp[(size_t)j * 128];       Cb[0][j] = Cp[(size_t)j * 128]; }
    #pragma unroll
    for (int j = 0; j < 8; j++) { Bb[1][j] = Bp[(size_t)(8 + j) * 128]; Cb[1][j] = Cp[(size_t)(8 + j) * 128]; }

    for (int c = 0; c < 32; c++) {
        if (c < 31) {
            dt_n = dtT[(c + 1) * 64 + lt];
            du_n = duT[(c + 1) * 64 + lt];
            ud_n = udT[(c + 1) * 64 + lt];
        }
        #pragma unroll
        for (int m = 0; m < 8; m++) {
            const int cur = m & 1;
            #pragma unroll
            for (int j = 0; j < 8; j++) {
                const int tl = m * 8 + j;
                float dt2 = rlanef(dt_c, tl);
                float du  = rlanef(du_c, tl);
                float ev = __builtin_amdgcn_exp2f(dt2 * a);
                h = fmaf(ev, h, du * Bb[cur][j]);
                red[tl * 132 + tid] = h * Cb[cur][j];
            }
            int nb = c * 8 + m + 2;
            if (nb < 256) {
                #pragma unroll
                for (int j = 0; j < 8; j++) {
                    Bb[cur][j] = Bp[((size_t)nb * 8 + j) * 128];
                    Cb[cur][j] = Cp[((size_t)nb * 8 + j) * 128];
                }
            }
        }
        __syncthreads();
        {
            const float* rp = &red[(tid & 63) * 132 + (tid >> 6) * 64];
            float s0 = 0.f, s1 = 0.f, s2 = 0.f, s3 = 0.f;
            #pragma unroll
            for (int i = 0; i < 64; i += 4) {
                float4 v = *(const float4*)(rp + i);
                s0 += v.x; s1 += v.y; s2 += v.z; s3 += v.w;
            }
            float part = (s0 + s1) + (s2 + s3);
            if (tid >= 64) comb[tid - 64] = part;
            __syncthreads();
            if (tid < 64) yTp[c * 64 + tid] = part + comb[tid] + ud_c;
        }
        __syncthreads();
        dt_c = dt_n;
        du_c = du_n;
        ud_c = ud_n;
    }
}

// ---------------- yT -> yz bf16 split (y half), merged: grid (8, 128, 2) ----------------
__global__ __launch_bounds__(256) void transpose_yz_kernel(const float* __restrict__ yT,
                                                           unsigned short* __restrict__ yzh,
                                                           unsigned short* __restrict__ yzl) {
    __shared__ float tile[32][33];
    int br = blockIdx.z;
    int m0 = blockIdx.x * 32;   // d rows
    int n0 = blockIdx.y * 32;   // within-branch t cols
    int tx = threadIdx.x;
    int ty = threadIdx.y;
    #pragma unroll
    for (int k = 0; k < 4; k++) {
        tile[ty + 8 * k][tx] = yT[((size_t)br * 256 + m0 + ty + 8 * k) * 4096 + n0 + tx];
    }
    __syncthreads();
    #pragma unroll
    for (int k = 0; k < 4; k++) {
        size_t dst = ((size_t)br * NROW + n0 + ty + 8 * k) * 512 + m0 + tx;
        unsigned short h, l;
        split2(tile[tx][ty + 8 * k], h, l);
        yzh[dst] = h; yzl[dst] = l;
    }
}

// ---------------- host-side launch ----------------
extern "C" void kernel_launch(void* const* d_in, const int* in_sizes, int n_in,
                              void* d_out, int out_size, void* d_ws, size_t ws_size,
                              hipStream_t stream) {
    const float* inp   = (const float*)d_in[0];
    const float* in_w[2]  = {(const float*)d_in[1],  (const float*)d_in[8]};
    const float* cxw[2]   = {(const float*)d_in[2],  (const float*)d_in[9]};
    const float* czw[2]   = {(const float*)d_in[3],  (const float*)d_in[10]};
    const float* xw[2]    = {(const float*)d_in[4],  (const float*)d_in[11]};
    const float* dtw[2]   = {(const float*)d_in[5],  (const float*)d_in[12]};
    const float* dtb[2]   = {(const float*)d_in[6],  (const float*)d_in[13]};
    const float* outw[2]  = {(const float*)d_in[7],  (const float*)d_in[14]};
    const float* A_log = (const float*)d_in[15];
    const float* Dvec  = (const float*)d_in[16];
    const float* eps   = (const float*)d_in[17];
    float* out = (float*)d_out;
    float* ws  = (float*)d_ws;
    unsigned short* hb = (unsigned short*)(ws + FLOAT_END);
    unsigned* bcmax = (unsigned*)(ws + OFF_BCMX);

    pre_all<<<PRE_BLOCKS, 256, 0, stream>>>(
        A_log, inp, in_w[0], in_w[1], outw[0], outw[1], xw[0], xw[1],
        ws, bcmax, hb);

    gemm_mfma<0, 0><<<dim3(512 / 64, MROW / 128), 256, 0, stream>>>(
        hb + HOFF_XINH, hb + HOFF_XINL, 512,
        hb + HOFF_INWH, hb + HOFF_INWL, WST_IN,
        ws + OFF_XZ, 512, 512, 512, nullptr);

    conv_silu_kernel<<<(MROW * 64) / 256, 256, 0, stream>>>(
        ws + OFF_XZ, ws + OFF_XS, hb + HOFF_XSH, hb + HOFF_XSL,
        hb + HOFF_YZH, hb + HOFF_YZL, cxw[0], cxw[1], czw[0], czw[1]);

    gemm_mfma<1, 1><<<dim3((288 + 63) / 64, MROW / 128), 256, 0, stream>>>(
        hb + HOFF_XSH, hb + HOFF_XSL, 256,
        hb + HOFF_XWH, hb + HOFF_XWL, WST_X,
        ws + OFF_XDBL, 288, 288, 256, bcmax);

    dtprep_shrink<<<dim3(4, MROW / 64), 256, 0, stream>>>(
        ws + OFF_XDBL, 288, dtw[0], dtw[1], dtb[0], dtb[1],
        ws + OFF_XS, Dvec,
        ws + OFF_DTT, ws + OFF_DUT, ws + OFF_UDT,
        bcmax, ws + OFF_BS, ws + OFF_CS);

    scan3_kernel<<<dim3(1024), 128, 0, stream>>>(ws, A_log, eps);

    transpose_yz_kernel<<<dim3(256 / 32, NROW / 32, 2), dim3(32, 8), 0, stream>>>(
        ws + OFF_YT, hb + HOFF_YZH, hb + HOFF_YZL);

    gemm_mfma<0, 0><<<dim3(512 / 64, MROW / 128), 256, 0, stream>>>(
        hb + HOFF_YZH, hb + HOFF_YZL, 512,
        hb + HOFF_OUTWH, hb + HOFF_OUTWL, WST_IN,
        out, 512, 512, 512, nullptr);
}